// Round 6
// baseline (21918.280 us; speedup 1.0000x reference)
//
#include <hip/hip_runtime.h>
#include <hip/hip_bf16.h>

typedef unsigned short u16;
typedef __bf16 bf16x8 __attribute__((ext_vector_type(8)));
typedef float f32x4 __attribute__((ext_vector_type(4)));
typedef u16 u16x8 __attribute__((ext_vector_type(8)));
typedef u16 u16x4 __attribute__((ext_vector_type(4)));

#define B_ 32
#define N_ 196
#define D_ 768
#define H_ 12
#define L_ 12
#define FF_ 3072
#define CLS_ 1000
#define HD_ 64
#define BH_ 384
#define NTOK_ 6272
#define ATTN_PER_B_ 460992   /* H*N*N */
#define NN_ 38416            /* N*N */

__device__ inline u16 f2bf(float f){
    __bf16 h = (__bf16)f;
    return __builtin_bit_cast(u16, h);
}
__device__ inline float bf2f(u16 u){
    __bf16 h = __builtin_bit_cast(__bf16, u);
    return (float)h;
}
// 3-way split: v ~= s0 + s1 + s2 (each bf16), ~24 mantissa bits
__device__ inline void split3(float v, u16& s0, u16& s1, u16& s2){
    s0 = f2bf(v);
    float r = v - bf2f(s0);
    s1 = f2bf(r);
    r = r - bf2f(s1);
    s2 = f2bf(r);
}

// ---------------- elementwise / conversion ----------------

__global__ __launch_bounds__(256)
void addpos_kernel(const float* __restrict__ x, const float* __restrict__ pos,
                   float* __restrict__ src){
    size_t gid = (size_t)blockIdx.x * 256 + threadIdx.x;
    size_t e = gid * 4;
    size_t tok = e / D_;
    size_t d = e % D_;
    size_t pe = (tok % N_) * D_ + d;
    float4 a = *(const float4*)(x + e);
    float4 p = *(const float4*)(pos + pe);
    float4 o = make_float4(a.x + p.x, a.y + p.y, a.z + p.z, a.w + p.w);
    *(float4*)(src + e) = o;
}

// f32 -> 3-way bf16 split
__global__ __launch_bounds__(256)
void cvt_split3(const float* __restrict__ in, u16* __restrict__ o0,
                u16* __restrict__ o1, u16* __restrict__ o2){
    size_t e = ((size_t)blockIdx.x * 256 + threadIdx.x) * 4;
    float4 v = *(const float4*)(in + e);
    u16x4 p0, p1, p2;
    float vv[4] = {v.x, v.y, v.z, v.w};
#pragma unroll
    for (int t = 0; t < 4; ++t){
        u16 a, b, c;
        split3(vv[t], a, b, c);
        p0[t] = a; p1[t] = b; p2[t] = c;
    }
    *(u16x4*)(o0 + e) = p0;
    *(u16x4*)(o1 + e) = p1;
    *(u16x4*)(o2 + e) = p2;
}

// weight transpose + 3-way split: in (K, Nn) f32 -> out (Nn, K) bf16 triple
__global__ __launch_bounds__(256)
void wtrans_kernel(const float* __restrict__ in, u16* __restrict__ o0,
                   u16* __restrict__ o1, u16* __restrict__ o2, int K, int Nn){
    __shared__ float t[32][33];
    int n0 = blockIdx.x * 32, k0 = blockIdx.y * 32;
    int tx = threadIdx.x & 31, ty = threadIdx.x >> 5;   // ty in [0,8)
#pragma unroll
    for (int r = 0; r < 4; ++r)
        t[ty + 8*r][tx] = in[(size_t)(k0 + ty + 8*r) * Nn + n0 + tx];
    __syncthreads();
#pragma unroll
    for (int r = 0; r < 4; ++r){
        float v = t[tx][ty + 8*r];
        size_t oi = (size_t)(n0 + ty + 8*r) * K + k0 + tx;
        u16 a, b, c;
        split3(v, a, b, c);
        o0[oi] = a; o1[oi] = b; o2[oi] = c;
    }
}

// ---------------- row LayerNorm (768 cols), optional 3-way split out ----------------

__global__ __launch_bounds__(256)
void ln_row(const float* __restrict__ in, const float* __restrict__ w,
            const float* __restrict__ bb, float* __restrict__ outF,
            u16* __restrict__ o0, u16* __restrict__ o1, u16* __restrict__ o2){
    int row = blockIdx.x, tid = threadIdx.x;
    const float* base = in + (size_t)row * D_;
    float x0 = base[tid], x1 = base[tid + 256], x2 = base[tid + 512];
    float s = x0 + x1 + x2;
    float q = x0*x0 + x1*x1 + x2*x2;
    __shared__ float red[8];
    for (int o = 32; o > 0; o >>= 1){ s += __shfl_down(s, o); q += __shfl_down(q, o); }
    if ((tid & 63) == 0){ red[tid >> 6] = s; red[4 + (tid >> 6)] = q; }
    __syncthreads();
    s = red[0] + red[1] + red[2] + red[3];
    q = red[4] + red[5] + red[6] + red[7];
    float mu = s * (1.f / D_);
    float rv = rsqrtf(q * (1.f / D_) - mu * mu + 1e-5f);
#pragma unroll
    for (int t = 0; t < 3; ++t){
        int c = tid + t * 256;
        float x = (t == 0 ? x0 : (t == 1 ? x1 : x2));
        float val = (x - mu) * rv * w[c] + bb[c];
        size_t oi = (size_t)row * D_ + c;
        if (outF) outF[oi] = val;
        if (o0){
            u16 a, b, cc;
            split3(val, a, b, cc);
            o0[oi] = a; o1[oi] = b; o2[oi] = cc;
        }
    }
}

// ---------------- split-3 GEMM: C = (A0+A1+A2)(B0+B1+B2)^T, 6-term ----------------
// EPI 0: outF = acc + bias
// EPI 1: split3 out = gelu(acc + bias)
// EPI 2: outF = acc + bias + res

template<int EPI>
__global__ __launch_bounds__(256)
void gemm_split3(const u16* __restrict__ A0, const u16* __restrict__ A1,
                 const u16* __restrict__ A2,
                 const u16* __restrict__ B0, const u16* __restrict__ B1,
                 const u16* __restrict__ B2,
                 const float* __restrict__ bias, const float* __restrict__ res,
                 float* __restrict__ outF, u16* __restrict__ oH,
                 u16* __restrict__ oM, u16* __restrict__ oL,
                 int M, int Nn, int K){
    __shared__ u16 LA0[128][40];
    __shared__ u16 LA1[128][40];
    __shared__ u16 LA2[128][40];
    __shared__ u16 LB0[128][40];
    __shared__ u16 LB1[128][40];
    __shared__ u16 LB2[128][40];
    const int tid = threadIdx.x;
    const int w = tid >> 6, l = tid & 63;
    const int wr = w >> 1, wc = w & 1;
    const int m0 = blockIdx.y * 128, n0 = blockIdx.x * 128;
    f32x4 acc[4][4] = {};
    const int row = tid >> 2, quad = tid & 3;
    const size_t aoff = (size_t)(m0 + row) * K + quad * 8;
    const size_t boff = (size_t)(n0 + row) * K + quad * 8;
    const size_t K64 = (size_t)64 * K;
    const int arow = l & 15, kg = (l >> 4) * 8;
    for (int k0 = 0; k0 < K; k0 += 32){
        u16x8 ra[6], rb[6];
        ra[0] = *(const u16x8*)(A0 + aoff + k0);
        ra[1] = *(const u16x8*)(A0 + aoff + K64 + k0);
        ra[2] = *(const u16x8*)(A1 + aoff + k0);
        ra[3] = *(const u16x8*)(A1 + aoff + K64 + k0);
        ra[4] = *(const u16x8*)(A2 + aoff + k0);
        ra[5] = *(const u16x8*)(A2 + aoff + K64 + k0);
        rb[0] = *(const u16x8*)(B0 + boff + k0);
        rb[1] = *(const u16x8*)(B0 + boff + K64 + k0);
        rb[2] = *(const u16x8*)(B1 + boff + k0);
        rb[3] = *(const u16x8*)(B1 + boff + K64 + k0);
        rb[4] = *(const u16x8*)(B2 + boff + k0);
        rb[5] = *(const u16x8*)(B2 + boff + K64 + k0);
        __syncthreads();
        *(u16x8*)&LA0[row][quad * 8] = ra[0];
        *(u16x8*)&LA0[row + 64][quad * 8] = ra[1];
        *(u16x8*)&LA1[row][quad * 8] = ra[2];
        *(u16x8*)&LA1[row + 64][quad * 8] = ra[3];
        *(u16x8*)&LA2[row][quad * 8] = ra[4];
        *(u16x8*)&LA2[row + 64][quad * 8] = ra[5];
        *(u16x8*)&LB0[row][quad * 8] = rb[0];
        *(u16x8*)&LB0[row + 64][quad * 8] = rb[1];
        *(u16x8*)&LB1[row][quad * 8] = rb[2];
        *(u16x8*)&LB1[row + 64][quad * 8] = rb[3];
        *(u16x8*)&LB2[row][quad * 8] = rb[4];
        *(u16x8*)&LB2[row + 64][quad * 8] = rb[5];
        __syncthreads();
        bf16x8 a0[4], a1[4], a2[4], b0[4], b1[4], b2[4];
#pragma unroll
        for (int m = 0; m < 4; ++m){
            a0[m] = __builtin_bit_cast(bf16x8, *(const u16x8*)&LA0[wr*64 + m*16 + arow][kg]);
            a1[m] = __builtin_bit_cast(bf16x8, *(const u16x8*)&LA1[wr*64 + m*16 + arow][kg]);
            a2[m] = __builtin_bit_cast(bf16x8, *(const u16x8*)&LA2[wr*64 + m*16 + arow][kg]);
        }
#pragma unroll
        for (int n = 0; n < 4; ++n){
            b0[n] = __builtin_bit_cast(bf16x8, *(const u16x8*)&LB0[wc*64 + n*16 + arow][kg]);
            b1[n] = __builtin_bit_cast(bf16x8, *(const u16x8*)&LB1[wc*64 + n*16 + arow][kg]);
            b2[n] = __builtin_bit_cast(bf16x8, *(const u16x8*)&LB2[wc*64 + n*16 + arow][kg]);
        }
        // accumulate smallest-order terms first
#pragma unroll
        for (int m = 0; m < 4; ++m)
#pragma unroll
            for (int n = 0; n < 4; ++n){
                acc[m][n] = __builtin_amdgcn_mfma_f32_16x16x32_bf16(a2[m], b0[n], acc[m][n], 0, 0, 0);
                acc[m][n] = __builtin_amdgcn_mfma_f32_16x16x32_bf16(a1[m], b1[n], acc[m][n], 0, 0, 0);
                acc[m][n] = __builtin_amdgcn_mfma_f32_16x16x32_bf16(a0[m], b2[n], acc[m][n], 0, 0, 0);
                acc[m][n] = __builtin_amdgcn_mfma_f32_16x16x32_bf16(a1[m], b0[n], acc[m][n], 0, 0, 0);
                acc[m][n] = __builtin_amdgcn_mfma_f32_16x16x32_bf16(a0[m], b1[n], acc[m][n], 0, 0, 0);
                acc[m][n] = __builtin_amdgcn_mfma_f32_16x16x32_bf16(a0[m], b0[n], acc[m][n], 0, 0, 0);
            }
    }
    const int r4 = (l >> 4) * 4, c16 = l & 15;
#pragma unroll
    for (int m = 0; m < 4; ++m){
#pragma unroll
        for (int n = 0; n < 4; ++n){
            int colg = n0 + wc*64 + n*16 + c16;
            float bv = bias[colg];
#pragma unroll
            for (int r = 0; r < 4; ++r){
                int rowg = m0 + wr*64 + m*16 + r4 + r;
                size_t oi = (size_t)rowg * Nn + colg;
                float v = acc[m][n][r] + bv;
                if (EPI == 0){
                    outF[oi] = v;
                } else if (EPI == 1){
                    v = 0.5f * v * (1.0f + erff(v * 0.70710678118654752f));
                    u16 a, b, c;
                    split3(v, a, b, c);
                    oH[oi] = a; oM[oi] = b; oL[oi] = c;
                } else {
                    outF[oi] = v + res[oi];
                }
            }
        }
    }
}

// ---------------- q/k normalize+square (double sums), V copy ----------------

__global__ __launch_bounds__(256)
void qkprep_kernel(const float* __restrict__ QKV, float* __restrict__ Q2f,
                   float* __restrict__ K2f, float* __restrict__ Vf){
    int bh = blockIdx.x;
    int b = bh / H_, h = bh % H_;
    int w = threadIdx.x >> 6, l = threadIdx.x & 63;
    for (int n = w; n < N_; n += 4){
        const float* row = QKV + (size_t)(b * N_ + n) * (3 * D_) + h * HD_;
        float qv = row[l], kv = row[D_ + l], vv = row[2 * D_ + l];
        double qs = (double)qv * (double)qv, ks = (double)kv * (double)kv;
        double qr = qs, kr = ks;
        for (int o = 32; o > 0; o >>= 1){ qr += __shfl_xor(qr, o); kr += __shfl_xor(kr, o); }
        size_t oi = ((size_t)bh * N_ + n) * HD_ + l;
        Q2f[oi] = (float)(qs / qr);
        K2f[oi] = (float)(ks / kr);
        Vf[oi] = vv;
    }
}

// ---------------- score (double accum, direct global) ----------------

__global__ __launch_bounds__(256)
void score_dbl(const float* __restrict__ Q2f, const float* __restrict__ K2f,
               float* __restrict__ S){
    int bh = blockIdx.y;
    int idx = blockIdx.x * 256 + threadIdx.x;
    if (idx >= NN_) return;
    int i = idx / N_, j = idx % N_;
    const float* Qr = Q2f + ((size_t)bh * N_ + i) * HD_;
    const float* Kr = K2f + ((size_t)bh * N_ + j) * HD_;
    double s = 0.0;
#pragma unroll
    for (int d = 0; d < HD_; ++d)
        s += (double)Qr[d] * (double)Kr[d];
    S[(size_t)bh * NN_ + idx] = (float)s;
}

// ---------------- batch-LN stats, two-pass, double ----------------

__global__ __launch_bounds__(256)
void statsA_kernel(const float* __restrict__ S, double* __restrict__ part1){
    int b = blockIdx.y, c = blockIdx.x;
    const float* base = S + (size_t)b * ATTN_PER_B_ + (size_t)c * 7203;
    double s = 0.0;
    for (int i = threadIdx.x; i < 7203; i += 256)
        s += (double)base[i];
    __shared__ double red[4];
    for (int o = 32; o > 0; o >>= 1) s += __shfl_down(s, o);
    if ((threadIdx.x & 63) == 0) red[threadIdx.x >> 6] = s;
    __syncthreads();
    if (threadIdx.x == 0) part1[b * 64 + c] = red[0] + red[1] + red[2] + red[3];
}

__global__ __launch_bounds__(64)
void reduceMu_kernel(const double* __restrict__ part1, double* __restrict__ MU){
    int b = blockIdx.x;
    double s = part1[b * 64 + threadIdx.x];
    for (int o = 32; o > 0; o >>= 1) s += __shfl_down(s, o);
    if (threadIdx.x == 0) MU[b] = s / (double)ATTN_PER_B_;
}

__global__ __launch_bounds__(256)
void statsB_kernel(const float* __restrict__ S, const double* __restrict__ MU,
                   double* __restrict__ part2){
    int b = blockIdx.y, c = blockIdx.x;
    double mu = MU[b];
    const float* base = S + (size_t)b * ATTN_PER_B_ + (size_t)c * 7203;
    double q = 0.0;
    for (int i = threadIdx.x; i < 7203; i += 256){
        double d = (double)base[i] - mu;
        q += d * d;
    }
    __shared__ double red[4];
    for (int o = 32; o > 0; o >>= 1) q += __shfl_down(q, o);
    if ((threadIdx.x & 63) == 0) red[threadIdx.x >> 6] = q;
    __syncthreads();
    if (threadIdx.x == 0) part2[b * 64 + c] = red[0] + red[1] + red[2] + red[3];
}

__global__ __launch_bounds__(64)
void reduceR_kernel(const double* __restrict__ part2, const double* __restrict__ MU,
                    float2* __restrict__ musig){
    int b = blockIdx.x;
    double q = part2[b * 64 + threadIdx.x];
    for (int o = 32; o > 0; o >>= 1) q += __shfl_down(q, o);
    if (threadIdx.x == 0){
        double var = q / (double)ATTN_PER_B_;
        musig[b] = make_float2((float)MU[b], (float)(1.0 / sqrt(var + 1e-5)));
    }
}

// ---------------- attn normalize in place (fp32) ----------------

__global__ __launch_bounds__(256)
void attnnorm_f32(float* __restrict__ S, const float* __restrict__ wv,
                  const float* __restrict__ bv, const float2* __restrict__ musig){
    size_t gid = (size_t)blockIdx.x * 256 + threadIdx.x;
    int b = (int)(gid / ATTN_PER_B_);
    int wi = (int)(gid % ATTN_PER_B_);
    float2 ms = musig[b];
    S[gid] = (S[gid] - ms.x) * ms.y * wv[wi] + bv[wi];
}

// ---------------- PV (fp32): Y[b,i,h*64+d] = sum_j S[bh][i][j]*Vf[bh][j][d] ----------------

__global__ __launch_bounds__(256)
void pv_f32(const float* __restrict__ S, const float* __restrict__ Vf,
            float* __restrict__ Y){
    __shared__ float Vl[N_][64];
    int bh = blockIdx.x, tid = threadIdx.x;
    int b = bh / H_, h = bh % H_;
    const float* Vb = Vf + (size_t)bh * N_ * HD_;
    for (int idx = tid; idx < N_ * HD_; idx += 256)
        ((float*)Vl)[idx] = Vb[idx];
    __syncthreads();
    int ii = tid >> 6, d = tid & 63;
    for (int i0 = 0; i0 < N_; i0 += 4){
        int i = i0 + ii;
        const float* Pr = S + ((size_t)bh * N_ + i) * N_;
        float acc = 0.f;
#pragma unroll 4
        for (int j = 0; j < N_; ++j)
            acc += Pr[j] * Vl[j][d];
        Y[((size_t)b * N_ + i) * D_ + h * HD_ + d] = acc;
    }
}

// ---------------- final pooling ----------------

__global__ __launch_bounds__(256)
void rowdot_kernel(const float* __restrict__ xf, const float* __restrict__ pw,
                   const float* __restrict__ pb, float* __restrict__ sraw){
    int row = blockIdx.x, tid = threadIdx.x;
    const float* base = xf + (size_t)row * D_;
    float s = base[tid] * pw[tid] + base[tid + 256] * pw[tid + 256] + base[tid + 512] * pw[tid + 512];
    __shared__ float red[4];
    for (int o = 32; o > 0; o >>= 1) s += __shfl_xor(s, o);
    if ((tid & 63) == 0) red[tid >> 6] = s;
    __syncthreads();
    if (tid == 0) sraw[row] = red[0] + red[1] + red[2] + red[3] + pb[0];
}

__global__ __launch_bounds__(256)
void softmax196_kernel(const float* __restrict__ sraw, float* __restrict__ aw){
    int b = blockIdx.x, tid = threadIdx.x;
    __shared__ float red[8];
    float v = (tid < N_) ? sraw[b * N_ + tid] : -3.0e38f;
    float m = v;
    for (int o = 32; o > 0; o >>= 1) m = fmaxf(m, __shfl_xor(m, o));
    if ((tid & 63) == 0) red[tid >> 6] = m;
    __syncthreads();
    float M = fmaxf(fmaxf(red[0], red[1]), fmaxf(red[2], red[3]));
    float e = (tid < N_) ? expf(v - M) : 0.f;
    float s = e;
    for (int o = 32; o > 0; o >>= 1) s += __shfl_xor(s, o);
    if ((tid & 63) == 0) red[4 + (tid >> 6)] = s;
    __syncthreads();
    float S = red[4] + red[5] + red[6] + red[7];
    if (tid < N_) aw[b * N_ + tid] = e / S;
}

__global__ __launch_bounds__(256)
void poolmat_kernel(const float* __restrict__ aw, const float* __restrict__ xf,
                    float* __restrict__ pooled){
    int b = blockIdx.y;
    int d = blockIdx.x * 256 + threadIdx.x;
    float acc = 0.f;
    for (int n = 0; n < N_; ++n)
        acc += aw[b * N_ + n] * xf[((size_t)b * N_ + n) * D_ + d];
    pooled[b * D_ + d] = acc;
}

__global__ __launch_bounds__(256)
void fc_kernel(const float* __restrict__ pooled, const float* __restrict__ fw,
               const float* __restrict__ fb, float* __restrict__ out){
    int b = blockIdx.y;
    int c = blockIdx.x * 256 + threadIdx.x;
    if (c >= CLS_) return;
    float acc = fb[c];
    for (int d = 0; d < D_; ++d)
        acc += pooled[b * D_ + d] * fw[(size_t)d * CLS_ + c];
    out[b * CLS_ + c] = acc;
}

__global__ __launch_bounds__(256)
void zero_logits(float* __restrict__ out){
    out[blockIdx.x * 256 + threadIdx.x] = 0.f;
}

// ---------------- launcher ----------------

extern "C" void kernel_launch(void* const* d_in, const int* in_sizes, int n_in,
                              void* d_out, int out_size, void* d_ws, size_t ws_size,
                              hipStream_t stream){
    const float* x        = (const float*)d_in[0];
    const float* pos_emb  = (const float*)d_in[1];
    const float* qkv_w    = (const float*)d_in[2];
    const float* qkv_b    = (const float*)d_in[3];
    const float* proj_w   = (const float*)d_in[4];
    const float* proj_b   = (const float*)d_in[5];
    const float* lin1_w   = (const float*)d_in[6];
    const float* lin1_b   = (const float*)d_in[7];
    const float* lin2_w   = (const float*)d_in[8];
    const float* lin2_b   = (const float*)d_in[9];
    const float* pre_ln_w = (const float*)d_in[10];
    const float* pre_ln_b = (const float*)d_in[11];
    const float* norm1_w  = (const float*)d_in[12];
    const float* norm1_b  = (const float*)d_in[13];
    const float* attn_ln_w= (const float*)d_in[14];
    const float* attn_ln_b= (const float*)d_in[15];
    const float* fln_w    = (const float*)d_in[16];
    const float* fln_b    = (const float*)d_in[17];
    const float* pool_w   = (const float*)d_in[18];
    const float* pool_b   = (const float*)d_in[19];
    const float* fc_w     = (const float*)d_in[20];
    const float* fc_b     = (const float*)d_in[21];

    float* dout = (float*)d_out;
    float* S = dout + (size_t)B_ * CLS_;   // attn region (B,H,196,196) f32

    char* ws = (char*)d_ws;
    size_t off = 0;
    auto alloc = [&](size_t bytes)->char*{
        char* p = ws + off;
        off += (bytes + 255) & ~(size_t)255;
        return p;
    };
    float* SRC   = (float*)alloc((size_t)NTOK_ * D_ * 4);
    float* Yb    = (float*)alloc((size_t)NTOK_ * D_ * 4);
    float* TMP   = (float*)alloc((size_t)NTOK_ * D_ * 4);
    float* QKV   = (float*)alloc((size_t)NTOK_ * 3 * D_ * 4);
    u16*   A0    = (u16*)  alloc((size_t)NTOK_ * D_ * 2);
    u16*   A1    = (u16*)  alloc((size_t)NTOK_ * D_ * 2);
    u16*   A2    = (u16*)  alloc((size_t)NTOK_ * D_ * 2);
    u16*   W0    = (u16*)  alloc((size_t)FF_ * D_ * 2);
    u16*   W1    = (u16*)  alloc((size_t)FF_ * D_ * 2);
    u16*   W2    = (u16*)  alloc((size_t)FF_ * D_ * 2);
    u16*   F0    = (u16*)  alloc((size_t)NTOK_ * FF_ * 2);
    u16*   F1    = (u16*)  alloc((size_t)NTOK_ * FF_ * 2);
    u16*   F2    = (u16*)  alloc((size_t)NTOK_ * FF_ * 2);
    float* Q2f   = (float*)alloc((size_t)BH_ * N_ * HD_ * 4);
    float* K2f   = (float*)alloc((size_t)BH_ * N_ * HD_ * 4);
    float* Vf    = (float*)alloc((size_t)BH_ * N_ * HD_ * 4);
    double* P1   = (double*)alloc((size_t)B_ * 64 * 8);
    double* P2   = (double*)alloc((size_t)B_ * 64 * 8);
    double* MU   = (double*)alloc((size_t)B_ * 8);
    float2* MUSIG= (float2*)alloc((size_t)B_ * 8);
    float* SRAW  = (float*)alloc((size_t)NTOK_ * 4);
    float* AW    = (float*)alloc((size_t)NTOK_ * 4);
    float* POOLED= (float*)alloc((size_t)B_ * D_ * 4);

    if (ws_size < off){
        zero_logits<<<(B_ * CLS_) / 256, 256, 0, stream>>>(dout);
        return;
    }

    const int cvt_blocks = NTOK_ * D_ / (256 * 4);  // 4704
    const int score_blocks = (NN_ + 255) / 256;     // 151

    addpos_kernel<<<cvt_blocks, 256, 0, stream>>>(x, pos_emb, SRC);

    for (int l = 0; l < L_; ++l){
        const float* qw  = qkv_w  + (size_t)l * D_ * 3 * D_;
        const float* qb  = qkv_b  + (size_t)l * 3 * D_;
        const float* pw  = proj_w + (size_t)l * D_ * D_;
        const float* pb  = proj_b + (size_t)l * D_;
        const float* l1w = lin1_w + (size_t)l * D_ * FF_;
        const float* l1b = lin1_b + (size_t)l * FF_;
        const float* l2w = lin2_w + (size_t)l * FF_ * D_;
        const float* l2b = lin2_b + (size_t)l * D_;
        const float* prw = pre_ln_w + (size_t)l * D_;
        const float* prb = pre_ln_b + (size_t)l * D_;
        const float* n1w = norm1_w + (size_t)l * D_;
        const float* n1b = norm1_b + (size_t)l * D_;
        const float* awl = attn_ln_w + (size_t)l * H_ * N_ * N_;
        const float* abl = attn_ln_b + (size_t)l * H_ * N_ * N_;

        // pre-LN -> split3 A operand
        ln_row<<<NTOK_, 256, 0, stream>>>(SRC, prw, prb, nullptr, A0, A1, A2);
        // qkv
        wtrans_kernel<<<dim3(3 * D_ / 32, D_ / 32), 256, 0, stream>>>(qw, W0, W1, W2, D_, 3 * D_);
        gemm_split3<0><<<dim3(3 * D_ / 128, NTOK_ / 128), 256, 0, stream>>>(
            A0, A1, A2, W0, W1, W2, qb, nullptr, QKV, nullptr, nullptr, nullptr,
            NTOK_, 3 * D_, D_);
        // q/k normalize+square (double sums), v copy
        qkprep_kernel<<<BH_, 256, 0, stream>>>(QKV, Q2f, K2f, Vf);
        // scores (double accum)
        score_dbl<<<dim3(score_blocks, BH_), 256, 0, stream>>>(Q2f, K2f, S);
        // batch LN over (H,N,N): two-pass double stats
        statsA_kernel<<<dim3(64, B_), 256, 0, stream>>>(S, P1);
        reduceMu_kernel<<<B_, 64, 0, stream>>>(P1, MU);
        statsB_kernel<<<dim3(64, B_), 256, 0, stream>>>(S, MU, P2);
        reduceR_kernel<<<B_, 64, 0, stream>>>(P2, MU, MUSIG);
        attnnorm_f32<<<(int)((size_t)B_ * ATTN_PER_B_ / 256), 256, 0, stream>>>(
            S, awl, abl, MUSIG);
        // attn @ V (fp32) -> Yb (B,N,D)
        pv_f32<<<BH_, 256, 0, stream>>>(S, Vf, Yb);
        // proj + residual
        cvt_split3<<<cvt_blocks, 256, 0, stream>>>(Yb, A0, A1, A2);
        wtrans_kernel<<<dim3(D_ / 32, D_ / 32), 256, 0, stream>>>(pw, W0, W1, W2, D_, D_);
        gemm_split3<2><<<dim3(D_ / 128, NTOK_ / 128), 256, 0, stream>>>(
            A0, A1, A2, W0, W1, W2, pb, SRC, TMP, nullptr, nullptr, nullptr,
            NTOK_, D_, D_);
        // norm1 -> SRC f32 + split3
        ln_row<<<NTOK_, 256, 0, stream>>>(TMP, n1w, n1b, SRC, A0, A1, A2);
        // MLP
        wtrans_kernel<<<dim3(FF_ / 32, D_ / 32), 256, 0, stream>>>(l1w, W0, W1, W2, D_, FF_);
        gemm_split3<1><<<dim3(FF_ / 128, NTOK_ / 128), 256, 0, stream>>>(
            A0, A1, A2, W0, W1, W2, l1b, nullptr, nullptr, F0, F1, F2,
            NTOK_, FF_, D_);
        wtrans_kernel<<<dim3(D_ / 32, FF_ / 32), 256, 0, stream>>>(l2w, W0, W1, W2, FF_, D_);
        gemm_split3<2><<<dim3(D_ / 128, NTOK_ / 128), 256, 0, stream>>>(
            F0, F1, F2, W0, W1, W2, l2b, SRC, SRC, nullptr, nullptr, nullptr,
            NTOK_, D_, FF_);
    }

    // final LN -> Yb (xf)
    ln_row<<<NTOK_, 256, 0, stream>>>(SRC, fln_w, fln_b, Yb, nullptr, nullptr, nullptr);
    // sequence pooling
    rowdot_kernel<<<NTOK_, 256, 0, stream>>>(Yb, pool_w, pool_b, SRAW);
    softmax196_kernel<<<B_, 256, 0, stream>>>(SRAW, AW);
    poolmat_kernel<<<dim3(D_ / 256, B_), 256, 0, stream>>>(AW, Yb, POOLED);
    fc_kernel<<<dim3((CLS_ + 255) / 256, B_), 256, 0, stream>>>(POOLED, fc_w, fc_b, dout);
}

// Round 8
// 15616.246 us; speedup vs baseline: 1.4036x; 1.4036x over previous
//
#include <hip/hip_runtime.h>
#include <hip/hip_bf16.h>

typedef unsigned short u16;
typedef __bf16 bf16x8 __attribute__((ext_vector_type(8)));
typedef float f32x4 __attribute__((ext_vector_type(4)));
typedef u16 u16x8 __attribute__((ext_vector_type(8)));
typedef u16 u16x4 __attribute__((ext_vector_type(4)));

#define B_ 32
#define N_ 196
#define D_ 768
#define H_ 12
#define L_ 12
#define FF_ 3072
#define CLS_ 1000
#define HD_ 64
#define BH_ 384
#define NTOK_ 6272
#define NP_ 224
#define ATTN_PER_B_ 460992   /* H*N*N */
#define NN_ 38416            /* N*N */

__device__ inline u16 f2bf(float f){
    __bf16 h = (__bf16)f;
    return __builtin_bit_cast(u16, h);
}
__device__ inline float bf2f(u16 u){
    __bf16 h = __builtin_bit_cast(__bf16, u);
    return (float)h;
}
// 3-way split: v ~= s0 + s1 + s2 (each bf16), ~24 mantissa bits
__device__ inline void split3(float v, u16& s0, u16& s1, u16& s2){
    s0 = f2bf(v);
    float r = v - bf2f(s0);
    s1 = f2bf(r);
    r = r - bf2f(s1);
    s2 = f2bf(r);
}

// ---------------- elementwise / conversion ----------------

__global__ __launch_bounds__(256)
void addpos_kernel(const float* __restrict__ x, const float* __restrict__ pos,
                   float* __restrict__ src){
    size_t gid = (size_t)blockIdx.x * 256 + threadIdx.x;
    size_t e = gid * 4;
    size_t tok = e / D_;
    size_t d = e % D_;
    size_t pe = (tok % N_) * D_ + d;
    float4 a = *(const float4*)(x + e);
    float4 p = *(const float4*)(pos + pe);
    float4 o = make_float4(a.x + p.x, a.y + p.y, a.z + p.z, a.w + p.w);
    *(float4*)(src + e) = o;
}

// f32 -> 3-way bf16 split
__global__ __launch_bounds__(256)
void cvt_split3(const float* __restrict__ in, u16* __restrict__ o0,
                u16* __restrict__ o1, u16* __restrict__ o2){
    size_t e = ((size_t)blockIdx.x * 256 + threadIdx.x) * 4;
    float4 v = *(const float4*)(in + e);
    u16x4 p0, p1, p2;
    float vv[4] = {v.x, v.y, v.z, v.w};
#pragma unroll
    for (int t = 0; t < 4; ++t){
        u16 a, b, c;
        split3(vv[t], a, b, c);
        p0[t] = a; p1[t] = b; p2[t] = c;
    }
    *(u16x4*)(o0 + e) = p0;
    *(u16x4*)(o1 + e) = p1;
    *(u16x4*)(o2 + e) = p2;
}

// weight transpose + 3-way split: in (K, Nn) f32 -> out (Nn, K) bf16 triple
__global__ __launch_bounds__(256)
void wtrans_kernel(const float* __restrict__ in, u16* __restrict__ o0,
                   u16* __restrict__ o1, u16* __restrict__ o2, int K, int Nn){
    __shared__ float t[32][33];
    int n0 = blockIdx.x * 32, k0 = blockIdx.y * 32;
    int tx = threadIdx.x & 31, ty = threadIdx.x >> 5;   // ty in [0,8)
#pragma unroll
    for (int r = 0; r < 4; ++r)
        t[ty + 8*r][tx] = in[(size_t)(k0 + ty + 8*r) * Nn + n0 + tx];
    __syncthreads();
#pragma unroll
    for (int r = 0; r < 4; ++r){
        float v = t[tx][ty + 8*r];
        size_t oi = (size_t)(n0 + ty + 8*r) * K + k0 + tx;
        u16 a, b, c;
        split3(v, a, b, c);
        o0[oi] = a; o1[oi] = b; o2[oi] = c;
    }
}

// ---------------- row LayerNorm (768 cols), optional 3-way split out ----------------

__global__ __launch_bounds__(256)
void ln_row(const float* __restrict__ in, const float* __restrict__ w,
            const float* __restrict__ bb, float* __restrict__ outF,
            u16* __restrict__ o0, u16* __restrict__ o1, u16* __restrict__ o2){
    int row = blockIdx.x, tid = threadIdx.x;
    const float* base = in + (size_t)row * D_;
    float x0 = base[tid], x1 = base[tid + 256], x2 = base[tid + 512];
    float s = x0 + x1 + x2;
    float q = x0*x0 + x1*x1 + x2*x2;
    __shared__ float red[8];
    for (int o = 32; o > 0; o >>= 1){ s += __shfl_down(s, o); q += __shfl_down(q, o); }
    if ((tid & 63) == 0){ red[tid >> 6] = s; red[4 + (tid >> 6)] = q; }
    __syncthreads();
    s = red[0] + red[1] + red[2] + red[3];
    q = red[4] + red[5] + red[6] + red[7];
    float mu = s * (1.f / D_);
    float rv = rsqrtf(q * (1.f / D_) - mu * mu + 1e-5f);
#pragma unroll
    for (int t = 0; t < 3; ++t){
        int c = tid + t * 256;
        float x = (t == 0 ? x0 : (t == 1 ? x1 : x2));
        float val = (x - mu) * rv * w[c] + bb[c];
        size_t oi = (size_t)row * D_ + c;
        if (outF) outF[oi] = val;
        if (o0){
            u16 a, b, cc;
            split3(val, a, b, cc);
            o0[oi] = a; o1[oi] = b; o2[oi] = cc;
        }
    }
}

// ---------------- split-3 GEMM: C = (A0+A1+A2)(B0+B1+B2)^T, 6-term ----------------

template<int EPI>
__global__ __launch_bounds__(256)
void gemm_split3(const u16* __restrict__ A0, const u16* __restrict__ A1,
                 const u16* __restrict__ A2,
                 const u16* __restrict__ B0, const u16* __restrict__ B1,
                 const u16* __restrict__ B2,
                 const float* __restrict__ bias, const float* __restrict__ res,
                 float* __restrict__ outF, u16* __restrict__ oH,
                 u16* __restrict__ oM, u16* __restrict__ oL,
                 int M, int Nn, int K){
    __shared__ u16 LA0[128][40];
    __shared__ u16 LA1[128][40];
    __shared__ u16 LA2[128][40];
    __shared__ u16 LB0[128][40];
    __shared__ u16 LB1[128][40];
    __shared__ u16 LB2[128][40];
    const int tid = threadIdx.x;
    const int w = tid >> 6, l = tid & 63;
    const int wr = w >> 1, wc = w & 1;
    const int m0 = blockIdx.y * 128, n0 = blockIdx.x * 128;
    f32x4 acc[4][4] = {};
    const int row = tid >> 2, quad = tid & 3;
    const size_t aoff = (size_t)(m0 + row) * K + quad * 8;
    const size_t boff = (size_t)(n0 + row) * K + quad * 8;
    const size_t K64 = (size_t)64 * K;
    const int arow = l & 15, kg = (l >> 4) * 8;
    for (int k0 = 0; k0 < K; k0 += 32){
        u16x8 ra[6], rb[6];
        ra[0] = *(const u16x8*)(A0 + aoff + k0);
        ra[1] = *(const u16x8*)(A0 + aoff + K64 + k0);
        ra[2] = *(const u16x8*)(A1 + aoff + k0);
        ra[3] = *(const u16x8*)(A1 + aoff + K64 + k0);
        ra[4] = *(const u16x8*)(A2 + aoff + k0);
        ra[5] = *(const u16x8*)(A2 + aoff + K64 + k0);
        rb[0] = *(const u16x8*)(B0 + boff + k0);
        rb[1] = *(const u16x8*)(B0 + boff + K64 + k0);
        rb[2] = *(const u16x8*)(B1 + boff + k0);
        rb[3] = *(const u16x8*)(B1 + boff + K64 + k0);
        rb[4] = *(const u16x8*)(B2 + boff + k0);
        rb[5] = *(const u16x8*)(B2 + boff + K64 + k0);
        __syncthreads();
        *(u16x8*)&LA0[row][quad * 8] = ra[0];
        *(u16x8*)&LA0[row + 64][quad * 8] = ra[1];
        *(u16x8*)&LA1[row][quad * 8] = ra[2];
        *(u16x8*)&LA1[row + 64][quad * 8] = ra[3];
        *(u16x8*)&LA2[row][quad * 8] = ra[4];
        *(u16x8*)&LA2[row + 64][quad * 8] = ra[5];
        *(u16x8*)&LB0[row][quad * 8] = rb[0];
        *(u16x8*)&LB0[row + 64][quad * 8] = rb[1];
        *(u16x8*)&LB1[row][quad * 8] = rb[2];
        *(u16x8*)&LB1[row + 64][quad * 8] = rb[3];
        *(u16x8*)&LB2[row][quad * 8] = rb[4];
        *(u16x8*)&LB2[row + 64][quad * 8] = rb[5];
        __syncthreads();
        bf16x8 a0[4], a1[4], a2[4], b0[4], b1[4], b2[4];
#pragma unroll
        for (int m = 0; m < 4; ++m){
            a0[m] = __builtin_bit_cast(bf16x8, *(const u16x8*)&LA0[wr*64 + m*16 + arow][kg]);
            a1[m] = __builtin_bit_cast(bf16x8, *(const u16x8*)&LA1[wr*64 + m*16 + arow][kg]);
            a2[m] = __builtin_bit_cast(bf16x8, *(const u16x8*)&LA2[wr*64 + m*16 + arow][kg]);
        }
#pragma unroll
        for (int n = 0; n < 4; ++n){
            b0[n] = __builtin_bit_cast(bf16x8, *(const u16x8*)&LB0[wc*64 + n*16 + arow][kg]);
            b1[n] = __builtin_bit_cast(bf16x8, *(const u16x8*)&LB1[wc*64 + n*16 + arow][kg]);
            b2[n] = __builtin_bit_cast(bf16x8, *(const u16x8*)&LB2[wc*64 + n*16 + arow][kg]);
        }
        // accumulate smallest-order terms first
#pragma unroll
        for (int m = 0; m < 4; ++m)
#pragma unroll
            for (int n = 0; n < 4; ++n){
                acc[m][n] = __builtin_amdgcn_mfma_f32_16x16x32_bf16(a2[m], b0[n], acc[m][n], 0, 0, 0);
                acc[m][n] = __builtin_amdgcn_mfma_f32_16x16x32_bf16(a1[m], b1[n], acc[m][n], 0, 0, 0);
                acc[m][n] = __builtin_amdgcn_mfma_f32_16x16x32_bf16(a0[m], b2[n], acc[m][n], 0, 0, 0);
                acc[m][n] = __builtin_amdgcn_mfma_f32_16x16x32_bf16(a1[m], b0[n], acc[m][n], 0, 0, 0);
                acc[m][n] = __builtin_amdgcn_mfma_f32_16x16x32_bf16(a0[m], b1[n], acc[m][n], 0, 0, 0);
                acc[m][n] = __builtin_amdgcn_mfma_f32_16x16x32_bf16(a0[m], b0[n], acc[m][n], 0, 0, 0);
            }
    }
    const int r4 = (l >> 4) * 4, c16 = l & 15;
#pragma unroll
    for (int m = 0; m < 4; ++m){
#pragma unroll
        for (int n = 0; n < 4; ++n){
            int colg = n0 + wc*64 + n*16 + c16;
            float bv = bias[colg];
#pragma unroll
            for (int r = 0; r < 4; ++r){
                int rowg = m0 + wr*64 + m*16 + r4 + r;
                size_t oi = (size_t)rowg * Nn + colg;
                float v = acc[m][n][r] + bv;
                if (EPI == 0){
                    outF[oi] = v;
                } else if (EPI == 1){
                    v = 0.5f * v * (1.0f + erff(v * 0.70710678118654752f));
                    u16 a, b, c;
                    split3(v, a, b, c);
                    oH[oi] = a; oM[oi] = b; oL[oi] = c;
                } else {
                    outF[oi] = v + res[oi];
                }
            }
        }
    }
}

// ---------------- q/k normalize+square -> split-3 bf16 (padded 224 rows), V copy ----------------

__global__ __launch_bounds__(256)
void qkprep_kernel(const float* __restrict__ QKV,
                   u16* __restrict__ Q0, u16* __restrict__ Q1, u16* __restrict__ Q2,
                   u16* __restrict__ K0, u16* __restrict__ K1, u16* __restrict__ K2,
                   float* __restrict__ Vf){
    int bh = blockIdx.x;
    int b = bh / H_, h = bh % H_;
    int w = threadIdx.x >> 6, l = threadIdx.x & 63;
    size_t base = (size_t)bh * (NP_ * HD_);
    for (int n = w; n < NP_; n += 4){
        size_t oi = base + (size_t)n * HD_ + l;
        if (n < N_){
            const float* row = QKV + (size_t)(b * N_ + n) * (3 * D_) + h * HD_;
            float qv = row[l], kv = row[D_ + l], vv = row[2 * D_ + l];
            double qs = (double)qv * (double)qv, ks = (double)kv * (double)kv;
            double qr = qs, kr = ks;
            for (int o = 32; o > 0; o >>= 1){ qr += __shfl_xor(qr, o); kr += __shfl_xor(kr, o); }
            float q2 = (float)(qs / qr), k2 = (float)(ks / kr);
            u16 a, bb, c;
            split3(q2, a, bb, c);
            Q0[oi] = a; Q1[oi] = bb; Q2[oi] = c;
            split3(k2, a, bb, c);
            K0[oi] = a; K1[oi] = bb; K2[oi] = c;
            Vf[((size_t)bh * N_ + n) * HD_ + l] = vv;
        } else {
            Q0[oi] = 0; Q1[oi] = 0; Q2[oi] = 0;
            K0[oi] = 0; K1[oi] = 0; K2[oi] = 0;
        }
    }
}

// ---------------- score via split-3 bf16 MFMA (6-term): S = Q2 @ K2^T ----------------
// One block per (i-tile, bh). 4 waves each compute one 16x16 quadrant of the 32x32 tile.

#define SPAD 72

__global__ __launch_bounds__(256)
void score_mfma3(const u16* __restrict__ Q0, const u16* __restrict__ Q1,
                 const u16* __restrict__ Q2,
                 const u16* __restrict__ K0, const u16* __restrict__ K1,
                 const u16* __restrict__ K2,
                 float* __restrict__ S){
    __shared__ u16 Ql[3][32][SPAD];
    __shared__ u16 Kl[3][32][SPAD];
    int i0 = blockIdx.x * 32;
    int bh = blockIdx.y;
    int tid = threadIdx.x;
    size_t base = (size_t)bh * (NP_ * HD_);
    // stage Q tile: 32*64/8 = 256 chunks per split
    {
        int r = tid >> 3, q = tid & 7;
        size_t src = base + (size_t)(i0 + r) * HD_ + q * 8;
        *(u16x8*)&Ql[0][r][q * 8] = *(const u16x8*)(Q0 + src);
        *(u16x8*)&Ql[1][r][q * 8] = *(const u16x8*)(Q1 + src);
        *(u16x8*)&Ql[2][r][q * 8] = *(const u16x8*)(Q2 + src);
    }
    const int w = tid >> 6, l = tid & 63;
    const int wm = w >> 1, wn = w & 1;        // wave quadrant
    const int arow = l & 15, kg0 = (l >> 4) * 8;
    const int r4 = (l >> 4) * 4, c16 = l & 15;
    for (int jt = 0; jt < 7; ++jt){
        __syncthreads();
        {
            int r = tid >> 3, q = tid & 7;
            size_t src = base + (size_t)(jt * 32 + r) * HD_ + q * 8;
            *(u16x8*)&Kl[0][r][q * 8] = *(const u16x8*)(K0 + src);
            *(u16x8*)&Kl[1][r][q * 8] = *(const u16x8*)(K1 + src);
            *(u16x8*)&Kl[2][r][q * 8] = *(const u16x8*)(K2 + src);
        }
        __syncthreads();
        f32x4 acc = {};
#pragma unroll
        for (int kk = 0; kk < 2; ++kk){
            int kg = kk * 32 + kg0;
            bf16x8 a0 = __builtin_bit_cast(bf16x8, *(const u16x8*)&Ql[0][wm*16 + arow][kg]);
            bf16x8 a1 = __builtin_bit_cast(bf16x8, *(const u16x8*)&Ql[1][wm*16 + arow][kg]);
            bf16x8 a2 = __builtin_bit_cast(bf16x8, *(const u16x8*)&Ql[2][wm*16 + arow][kg]);
            bf16x8 b0 = __builtin_bit_cast(bf16x8, *(const u16x8*)&Kl[0][wn*16 + arow][kg]);
            bf16x8 b1 = __builtin_bit_cast(bf16x8, *(const u16x8*)&Kl[1][wn*16 + arow][kg]);
            bf16x8 b2 = __builtin_bit_cast(bf16x8, *(const u16x8*)&Kl[2][wn*16 + arow][kg]);
            acc = __builtin_amdgcn_mfma_f32_16x16x32_bf16(a2, b0, acc, 0, 0, 0);
            acc = __builtin_amdgcn_mfma_f32_16x16x32_bf16(a1, b1, acc, 0, 0, 0);
            acc = __builtin_amdgcn_mfma_f32_16x16x32_bf16(a0, b2, acc, 0, 0, 0);
            acc = __builtin_amdgcn_mfma_f32_16x16x32_bf16(a1, b0, acc, 0, 0, 0);
            acc = __builtin_amdgcn_mfma_f32_16x16x32_bf16(a0, b1, acc, 0, 0, 0);
            acc = __builtin_amdgcn_mfma_f32_16x16x32_bf16(a0, b0, acc, 0, 0, 0);
        }
#pragma unroll
        for (int r = 0; r < 4; ++r){
            int i = i0 + wm * 16 + r4 + r;
            int j = jt * 32 + wn * 16 + c16;
            if (i < N_ && j < N_)
                S[((size_t)bh * N_ + i) * N_ + j] = acc[r];
        }
    }
}

// ---------------- batch-LN stats, two-pass, double ----------------

__global__ __launch_bounds__(256)
void statsA_kernel(const float* __restrict__ S, double* __restrict__ part1){
    int b = blockIdx.y, c = blockIdx.x;
    const float* base = S + (size_t)b * ATTN_PER_B_ + (size_t)c * 7203;
    double s = 0.0;
    for (int i = threadIdx.x; i < 7203; i += 256)
        s += (double)base[i];
    __shared__ double red[4];
    for (int o = 32; o > 0; o >>= 1) s += __shfl_down(s, o);
    if ((threadIdx.x & 63) == 0) red[threadIdx.x >> 6] = s;
    __syncthreads();
    if (threadIdx.x == 0) part1[b * 64 + c] = red[0] + red[1] + red[2] + red[3];
}

__global__ __launch_bounds__(64)
void reduceMu_kernel(const double* __restrict__ part1, double* __restrict__ MU){
    int b = blockIdx.x;
    double s = part1[b * 64 + threadIdx.x];
    for (int o = 32; o > 0; o >>= 1) s += __shfl_down(s, o);
    if (threadIdx.x == 0) MU[b] = s / (double)ATTN_PER_B_;
}

__global__ __launch_bounds__(256)
void statsB_kernel(const float* __restrict__ S, const double* __restrict__ MU,
                   double* __restrict__ part2){
    int b = blockIdx.y, c = blockIdx.x;
    double mu = MU[b];
    const float* base = S + (size_t)b * ATTN_PER_B_ + (size_t)c * 7203;
    double q = 0.0;
    for (int i = threadIdx.x; i < 7203; i += 256){
        double d = (double)base[i] - mu;
        q += d * d;
    }
    __shared__ double red[4];
    for (int o = 32; o > 0; o >>= 1) q += __shfl_down(q, o);
    if ((threadIdx.x & 63) == 0) red[threadIdx.x >> 6] = q;
    __syncthreads();
    if (threadIdx.x == 0) part2[b * 64 + c] = red[0] + red[1] + red[2] + red[3];
}

__global__ __launch_bounds__(64)
void reduceR_kernel(const double* __restrict__ part2, const double* __restrict__ MU,
                    float2* __restrict__ musig){
    int b = blockIdx.x;
    double q = part2[b * 64 + threadIdx.x];
    for (int o = 32; o > 0; o >>= 1) q += __shfl_down(q, o);
    if (threadIdx.x == 0){
        double var = q / (double)ATTN_PER_B_;
        musig[b] = make_float2((float)MU[b], (float)(1.0 / sqrt(var + 1e-5)));
    }
}

// ---------------- attn normalize in place (fp32) ----------------

__global__ __launch_bounds__(256)
void attnnorm_f32(float* __restrict__ S, const float* __restrict__ wv,
                  const float* __restrict__ bv, const float2* __restrict__ musig){
    size_t gid = (size_t)blockIdx.x * 256 + threadIdx.x;
    int b = (int)(gid / ATTN_PER_B_);
    int wi = (int)(gid % ATTN_PER_B_);
    float2 ms = musig[b];
    S[gid] = (S[gid] - ms.x) * ms.y * wv[wi] + bv[wi];
}

// ---------------- PV (fp32): Y[b,i,h*64+d] = sum_j S[bh][i][j]*Vf[bh][j][d] ----------------

__global__ __launch_bounds__(256)
void pv_f32(const float* __restrict__ S, const float* __restrict__ Vf,
            float* __restrict__ Y){
    __shared__ float Vl[N_][64];
    int bh = blockIdx.x, tid = threadIdx.x;
    int b = bh / H_, h = bh % H_;
    const float* Vb = Vf + (size_t)bh * N_ * HD_;
    for (int idx = tid; idx < N_ * HD_; idx += 256)
        ((float*)Vl)[idx] = Vb[idx];
    __syncthreads();
    int ii = tid >> 6, d = tid & 63;
    for (int i0 = 0; i0 < N_; i0 += 4){
        int i = i0 + ii;
        const float* Pr = S + ((size_t)bh * N_ + i) * N_;
        float acc = 0.f;
#pragma unroll 4
        for (int j = 0; j < N_; ++j)
            acc += Pr[j] * Vl[j][d];
        Y[((size_t)b * N_ + i) * D_ + h * HD_ + d] = acc;
    }
}

// ---------------- final pooling ----------------

__global__ __launch_bounds__(256)
void rowdot_kernel(const float* __restrict__ xf, const float* __restrict__ pw,
                   const float* __restrict__ pb, float* __restrict__ sraw){
    int row = blockIdx.x, tid = threadIdx.x;
    const float* base = xf + (size_t)row * D_;
    float s = base[tid] * pw[tid] + base[tid + 256] * pw[tid + 256] + base[tid + 512] * pw[tid + 512];
    __shared__ float red[4];
    for (int o = 32; o > 0; o >>= 1) s += __shfl_xor(s, o);
    if ((tid & 63) == 0) red[tid >> 6] = s;
    __syncthreads();
    if (tid == 0) sraw[row] = red[0] + red[1] + red[2] + red[3] + pb[0];
}

__global__ __launch_bounds__(256)
void softmax196_kernel(const float* __restrict__ sraw, float* __restrict__ aw){
    int b = blockIdx.x, tid = threadIdx.x;
    __shared__ float red[8];
    float v = (tid < N_) ? sraw[b * N_ + tid] : -3.0e38f;
    float m = v;
    for (int o = 32; o > 0; o >>= 1) m = fmaxf(m, __shfl_xor(m, o));
    if ((tid & 63) == 0) red[tid >> 6] = m;
    __syncthreads();
    float M = fmaxf(fmaxf(red[0], red[1]), fmaxf(red[2], red[3]));
    float e = (tid < N_) ? expf(v - M) : 0.f;
    float s = e;
    for (int o = 32; o > 0; o >>= 1) s += __shfl_xor(s, o);
    if ((tid & 63) == 0) red[4 + (tid >> 6)] = s;
    __syncthreads();
    float S = red[4] + red[5] + red[6] + red[7];
    if (tid < N_) aw[b * N_ + tid] = e / S;
}

__global__ __launch_bounds__(256)
void poolmat_kernel(const float* __restrict__ aw, const float* __restrict__ xf,
                    float* __restrict__ pooled){
    int b = blockIdx.y;
    int d = blockIdx.x * 256 + threadIdx.x;
    float acc = 0.f;
    for (int n = 0; n < N_; ++n)
        acc += aw[b * N_ + n] * xf[((size_t)b * N_ + n) * D_ + d];
    pooled[b * D_ + d] = acc;
}

__global__ __launch_bounds__(256)
void fc_kernel(const float* __restrict__ pooled, const float* __restrict__ fw,
               const float* __restrict__ fb, float* __restrict__ out){
    int b = blockIdx.y;
    int c = blockIdx.x * 256 + threadIdx.x;
    if (c >= CLS_) return;
    float acc = fb[c];
    for (int d = 0; d < D_; ++d)
        acc += pooled[b * D_ + d] * fw[(size_t)d * CLS_ + c];
    out[b * CLS_ + c] = acc;
}

__global__ __launch_bounds__(256)
void zero_logits(float* __restrict__ out){
    out[blockIdx.x * 256 + threadIdx.x] = 0.f;
}

// ---------------- launcher ----------------

extern "C" void kernel_launch(void* const* d_in, const int* in_sizes, int n_in,
                              void* d_out, int out_size, void* d_ws, size_t ws_size,
                              hipStream_t stream){
    const float* x        = (const float*)d_in[0];
    const float* pos_emb  = (const float*)d_in[1];
    const float* qkv_w    = (const float*)d_in[2];
    const float* qkv_b    = (const float*)d_in[3];
    const float* proj_w   = (const float*)d_in[4];
    const float* proj_b   = (const float*)d_in[5];
    const float* lin1_w   = (const float*)d_in[6];
    const float* lin1_b   = (const float*)d_in[7];
    const float* lin2_w   = (const float*)d_in[8];
    const float* lin2_b   = (const float*)d_in[9];
    const float* pre_ln_w = (const float*)d_in[10];
    const float* pre_ln_b = (const float*)d_in[11];
    const float* norm1_w  = (const float*)d_in[12];
    const float* norm1_b  = (const float*)d_in[13];
    const float* attn_ln_w= (const float*)d_in[14];
    const float* attn_ln_b= (const float*)d_in[15];
    const float* fln_w    = (const float*)d_in[16];
    const float* fln_b    = (const float*)d_in[17];
    const float* pool_w   = (const float*)d_in[18];
    const float* pool_b   = (const float*)d_in[19];
    const float* fc_w     = (const float*)d_in[20];
    const float* fc_b     = (const float*)d_in[21];

    float* dout = (float*)d_out;
    float* S = dout + (size_t)B_ * CLS_;   // attn region (B,H,196,196) f32

    char* ws = (char*)d_ws;
    size_t off = 0;
    auto alloc = [&](size_t bytes)->char*{
        char* p = ws + off;
        off += (bytes + 255) & ~(size_t)255;
        return p;
    };
    float* SRC   = (float*)alloc((size_t)NTOK_ * D_ * 4);
    float* Yb    = (float*)alloc((size_t)NTOK_ * D_ * 4);
    float* TMP   = (float*)alloc((size_t)NTOK_ * D_ * 4);
    float* QKV   = (float*)alloc((size_t)NTOK_ * 3 * D_ * 4);
    u16*   A0    = (u16*)  alloc((size_t)NTOK_ * D_ * 2);
    u16*   A1    = (u16*)  alloc((size_t)NTOK_ * D_ * 2);
    u16*   A2    = (u16*)  alloc((size_t)NTOK_ * D_ * 2);
    u16*   W0    = (u16*)  alloc((size_t)FF_ * D_ * 2);
    u16*   W1    = (u16*)  alloc((size_t)FF_ * D_ * 2);
    u16*   W2    = (u16*)  alloc((size_t)FF_ * D_ * 2);
    u16*   F0    = (u16*)  alloc((size_t)NTOK_ * FF_ * 2);
    u16*   F1    = (u16*)  alloc((size_t)NTOK_ * FF_ * 2);
    u16*   F2    = (u16*)  alloc((size_t)NTOK_ * FF_ * 2);
    u16*   Q0b   = (u16*)  alloc((size_t)BH_ * NP_ * HD_ * 2);
    u16*   Q1b   = (u16*)  alloc((size_t)BH_ * NP_ * HD_ * 2);
    u16*   Q2b   = (u16*)  alloc((size_t)BH_ * NP_ * HD_ * 2);
    u16*   K0b   = (u16*)  alloc((size_t)BH_ * NP_ * HD_ * 2);
    u16*   K1b   = (u16*)  alloc((size_t)BH_ * NP_ * HD_ * 2);
    u16*   K2b   = (u16*)  alloc((size_t)BH_ * NP_ * HD_ * 2);
    float* Vf    = (float*)alloc((size_t)BH_ * N_ * HD_ * 4);
    double* P1   = (double*)alloc((size_t)B_ * 64 * 8);
    double* P2   = (double*)alloc((size_t)B_ * 64 * 8);
    double* MU   = (double*)alloc((size_t)B_ * 8);
    float2* MUSIG= (float2*)alloc((size_t)B_ * 8);
    float* SRAW  = (float*)alloc((size_t)NTOK_ * 4);
    float* AW    = (float*)alloc((size_t)NTOK_ * 4);
    float* POOLED= (float*)alloc((size_t)B_ * D_ * 4);

    if (ws_size < off){
        zero_logits<<<(B_ * CLS_) / 256, 256, 0, stream>>>(dout);
        return;
    }

    const int cvt_blocks = NTOK_ * D_ / (256 * 4);  // 4704

    addpos_kernel<<<cvt_blocks, 256, 0, stream>>>(x, pos_emb, SRC);

    for (int l = 0; l < L_; ++l){
        const float* qw  = qkv_w  + (size_t)l * D_ * 3 * D_;
        const float* qb  = qkv_b  + (size_t)l * 3 * D_;
        const float* pw  = proj_w + (size_t)l * D_ * D_;
        const float* pb  = proj_b + (size_t)l * D_;
        const float* l1w = lin1_w + (size_t)l * D_ * FF_;
        const float* l1b = lin1_b + (size_t)l * FF_;
        const float* l2w = lin2_w + (size_t)l * FF_ * D_;
        const float* l2b = lin2_b + (size_t)l * D_;
        const float* prw = pre_ln_w + (size_t)l * D_;
        const float* prb = pre_ln_b + (size_t)l * D_;
        const float* n1w = norm1_w + (size_t)l * D_;
        const float* n1b = norm1_b + (size_t)l * D_;
        const float* awl = attn_ln_w + (size_t)l * H_ * N_ * N_;
        const float* abl = attn_ln_b + (size_t)l * H_ * N_ * N_;

        // pre-LN -> split3 A operand
        ln_row<<<NTOK_, 256, 0, stream>>>(SRC, prw, prb, nullptr, A0, A1, A2);
        // qkv
        wtrans_kernel<<<dim3(3 * D_ / 32, D_ / 32), 256, 0, stream>>>(qw, W0, W1, W2, D_, 3 * D_);
        gemm_split3<0><<<dim3(3 * D_ / 128, NTOK_ / 128), 256, 0, stream>>>(
            A0, A1, A2, W0, W1, W2, qb, nullptr, QKV, nullptr, nullptr, nullptr,
            NTOK_, 3 * D_, D_);
        // q/k normalize+square -> split3 bf16 (padded), v copy
        qkprep_kernel<<<BH_, 256, 0, stream>>>(QKV, Q0b, Q1b, Q2b, K0b, K1b, K2b, Vf);
        // scores via split-3 MFMA (6-term)
        score_mfma3<<<dim3(7, BH_), 256, 0, stream>>>(Q0b, Q1b, Q2b, K0b, K1b, K2b, S);
        // batch LN over (H,N,N): two-pass double stats
        statsA_kernel<<<dim3(64, B_), 256, 0, stream>>>(S, P1);
        reduceMu_kernel<<<B_, 64, 0, stream>>>(P1, MU);
        statsB_kernel<<<dim3(64, B_), 256, 0, stream>>>(S, MU, P2);
        reduceR_kernel<<<B_, 64, 0, stream>>>(P2, MU, MUSIG);
        attnnorm_f32<<<(int)((size_t)B_ * ATTN_PER_B_ / 256), 256, 0, stream>>>(
            S, awl, abl, MUSIG);
        // attn @ V (fp32) -> Yb (B,N,D)
        pv_f32<<<BH_, 256, 0, stream>>>(S, Vf, Yb);
        // proj + residual
        cvt_split3<<<cvt_blocks, 256, 0, stream>>>(Yb, A0, A1, A2);
        wtrans_kernel<<<dim3(D_ / 32, D_ / 32), 256, 0, stream>>>(pw, W0, W1, W2, D_, D_);
        gemm_split3<2><<<dim3(D_ / 128, NTOK_ / 128), 256, 0, stream>>>(
            A0, A1, A2, W0, W1, W2, pb, SRC, TMP, nullptr, nullptr, nullptr,
            NTOK_, D_, D_);
        // norm1 -> SRC f32 + split3
        ln_row<<<NTOK_, 256, 0, stream>>>(TMP, n1w, n1b, SRC, A0, A1, A2);
        // MLP
        wtrans_kernel<<<dim3(FF_ / 32, D_ / 32), 256, 0, stream>>>(l1w, W0, W1, W2, D_, FF_);
        gemm_split3<1><<<dim3(FF_ / 128, NTOK_ / 128), 256, 0, stream>>>(
            A0, A1, A2, W0, W1, W2, l1b, nullptr, nullptr, F0, F1, F2,
            NTOK_, FF_, D_);
        wtrans_kernel<<<dim3(D_ / 32, FF_ / 32), 256, 0, stream>>>(l2w, W0, W1, W2, FF_, D_);
        gemm_split3<2><<<dim3(D_ / 128, NTOK_ / 128), 256, 0, stream>>>(
            F0, F1, F2, W0, W1, W2, l2b, SRC, SRC, nullptr, nullptr, nullptr,
            NTOK_, D_, FF_);
    }

    // final LN -> Yb (xf)
    ln_row<<<NTOK_, 256, 0, stream>>>(SRC, fln_w, fln_b, Yb, nullptr, nullptr, nullptr);
    // sequence pooling
    rowdot_kernel<<<NTOK_, 256, 0, stream>>>(Yb, pool_w, pool_b, SRAW);
    softmax196_kernel<<<B_, 256, 0, stream>>>(SRAW, AW);
    poolmat_kernel<<<dim3(D_ / 256, B_), 256, 0, stream>>>(AW, Yb, POOLED);
    fc_kernel<<<dim3((CLS_ + 255) / 256, B_), 256, 0, stream>>>(POOLED, fc_w, fc_b, dout);
}

// Round 9
// 12181.451 us; speedup vs baseline: 1.7993x; 1.2820x over previous
//
#include <hip/hip_runtime.h>
#include <hip/hip_bf16.h>

typedef unsigned short u16;
typedef __bf16 bf16x8 __attribute__((ext_vector_type(8)));
typedef float f32x4 __attribute__((ext_vector_type(4)));
typedef u16 u16x8 __attribute__((ext_vector_type(8)));
typedef u16 u16x4 __attribute__((ext_vector_type(4)));

#define B_ 32
#define N_ 196
#define D_ 768
#define H_ 12
#define L_ 12
#define FF_ 3072
#define CLS_ 1000
#define HD_ 64
#define BH_ 384
#define NTOK_ 6272
#define NP_ 224
#define ATTN_PER_B_ 460992   /* H*N*N */
#define NN_ 38416            /* N*N */

__device__ inline u16 f2bf(float f){
    __bf16 h = (__bf16)f;
    return __builtin_bit_cast(u16, h);
}
__device__ inline float bf2f(u16 u){
    __bf16 h = __builtin_bit_cast(__bf16, u);
    return (float)h;
}
// 3-way split: v ~= s0 + s1 + s2 (each bf16), ~24 mantissa bits
__device__ inline void split3(float v, u16& s0, u16& s1, u16& s2){
    s0 = f2bf(v);
    float r = v - bf2f(s0);
    s1 = f2bf(r);
    r = r - bf2f(s1);
    s2 = f2bf(r);
}

// ---------------- elementwise / conversion ----------------

__global__ __launch_bounds__(256)
void addpos_kernel(const float* __restrict__ x, const float* __restrict__ pos,
                   float* __restrict__ src){
    size_t gid = (size_t)blockIdx.x * 256 + threadIdx.x;
    size_t e = gid * 4;
    size_t tok = e / D_;
    size_t d = e % D_;
    size_t pe = (tok % N_) * D_ + d;
    float4 a = *(const float4*)(x + e);
    float4 p = *(const float4*)(pos + pe);
    float4 o = make_float4(a.x + p.x, a.y + p.y, a.z + p.z, a.w + p.w);
    *(float4*)(src + e) = o;
}

// f32 -> 3-way bf16 split
__global__ __launch_bounds__(256)
void cvt_split3(const float* __restrict__ in, u16* __restrict__ o0,
                u16* __restrict__ o1, u16* __restrict__ o2){
    size_t e = ((size_t)blockIdx.x * 256 + threadIdx.x) * 4;
    float4 v = *(const float4*)(in + e);
    u16x4 p0, p1, p2;
    float vv[4] = {v.x, v.y, v.z, v.w};
#pragma unroll
    for (int t = 0; t < 4; ++t){
        u16 a, b, c;
        split3(vv[t], a, b, c);
        p0[t] = a; p1[t] = b; p2[t] = c;
    }
    *(u16x4*)(o0 + e) = p0;
    *(u16x4*)(o1 + e) = p1;
    *(u16x4*)(o2 + e) = p2;
}

// weight transpose + 3-way split: in (K, Nn) f32 -> out (Nn, K) bf16 triple
__global__ __launch_bounds__(256)
void wtrans_kernel(const float* __restrict__ in, u16* __restrict__ o0,
                   u16* __restrict__ o1, u16* __restrict__ o2, int K, int Nn){
    __shared__ float t[32][33];
    int n0 = blockIdx.x * 32, k0 = blockIdx.y * 32;
    int tx = threadIdx.x & 31, ty = threadIdx.x >> 5;   // ty in [0,8)
#pragma unroll
    for (int r = 0; r < 4; ++r)
        t[ty + 8*r][tx] = in[(size_t)(k0 + ty + 8*r) * Nn + n0 + tx];
    __syncthreads();
#pragma unroll
    for (int r = 0; r < 4; ++r){
        float v = t[tx][ty + 8*r];
        size_t oi = (size_t)(n0 + ty + 8*r) * K + k0 + tx;
        u16 a, b, c;
        split3(v, a, b, c);
        o0[oi] = a; o1[oi] = b; o2[oi] = c;
    }
}

// ---------------- row LayerNorm (768 cols), optional 3-way split out ----------------

__global__ __launch_bounds__(256)
void ln_row(const float* __restrict__ in, const float* __restrict__ w,
            const float* __restrict__ bb, float* __restrict__ outF,
            u16* __restrict__ o0, u16* __restrict__ o1, u16* __restrict__ o2){
    int row = blockIdx.x, tid = threadIdx.x;
    const float* base = in + (size_t)row * D_;
    float x0 = base[tid], x1 = base[tid + 256], x2 = base[tid + 512];
    float s = x0 + x1 + x2;
    float q = x0*x0 + x1*x1 + x2*x2;
    __shared__ float red[8];
    for (int o = 32; o > 0; o >>= 1){ s += __shfl_down(s, o); q += __shfl_down(q, o); }
    if ((tid & 63) == 0){ red[tid >> 6] = s; red[4 + (tid >> 6)] = q; }
    __syncthreads();
    s = red[0] + red[1] + red[2] + red[3];
    q = red[4] + red[5] + red[6] + red[7];
    float mu = s * (1.f / D_);
    float rv = rsqrtf(q * (1.f / D_) - mu * mu + 1e-5f);
#pragma unroll
    for (int t = 0; t < 3; ++t){
        int c = tid + t * 256;
        float x = (t == 0 ? x0 : (t == 1 ? x1 : x2));
        float val = (x - mu) * rv * w[c] + bb[c];
        size_t oi = (size_t)row * D_ + c;
        if (outF) outF[oi] = val;
        if (o0){
            u16 a, b, cc;
            split3(val, a, b, cc);
            o0[oi] = a; o1[oi] = b; o2[oi] = cc;
        }
    }
}

// ---------------- split-3 GEMM: C = (A0+A1+A2)(B0+B1+B2)^T, 6-term ----------------

template<int EPI>
__global__ __launch_bounds__(256)
void gemm_split3(const u16* __restrict__ A0, const u16* __restrict__ A1,
                 const u16* __restrict__ A2,
                 const u16* __restrict__ B0, const u16* __restrict__ B1,
                 const u16* __restrict__ B2,
                 const float* __restrict__ bias, const float* __restrict__ res,
                 float* __restrict__ outF, u16* __restrict__ oH,
                 u16* __restrict__ oM, u16* __restrict__ oL,
                 int M, int Nn, int K){
    __shared__ u16 LA0[128][40];
    __shared__ u16 LA1[128][40];
    __shared__ u16 LA2[128][40];
    __shared__ u16 LB0[128][40];
    __shared__ u16 LB1[128][40];
    __shared__ u16 LB2[128][40];
    const int tid = threadIdx.x;
    const int w = tid >> 6, l = tid & 63;
    const int wr = w >> 1, wc = w & 1;
    const int m0 = blockIdx.y * 128, n0 = blockIdx.x * 128;
    f32x4 acc[4][4] = {};
    const int row = tid >> 2, quad = tid & 3;
    const size_t aoff = (size_t)(m0 + row) * K + quad * 8;
    const size_t boff = (size_t)(n0 + row) * K + quad * 8;
    const size_t K64 = (size_t)64 * K;
    const int arow = l & 15, kg = (l >> 4) * 8;
    for (int k0 = 0; k0 < K; k0 += 32){
        u16x8 ra[6], rb[6];
        ra[0] = *(const u16x8*)(A0 + aoff + k0);
        ra[1] = *(const u16x8*)(A0 + aoff + K64 + k0);
        ra[2] = *(const u16x8*)(A1 + aoff + k0);
        ra[3] = *(const u16x8*)(A1 + aoff + K64 + k0);
        ra[4] = *(const u16x8*)(A2 + aoff + k0);
        ra[5] = *(const u16x8*)(A2 + aoff + K64 + k0);
        rb[0] = *(const u16x8*)(B0 + boff + k0);
        rb[1] = *(const u16x8*)(B0 + boff + K64 + k0);
        rb[2] = *(const u16x8*)(B1 + boff + k0);
        rb[3] = *(const u16x8*)(B1 + boff + K64 + k0);
        rb[4] = *(const u16x8*)(B2 + boff + k0);
        rb[5] = *(const u16x8*)(B2 + boff + K64 + k0);
        __syncthreads();
        *(u16x8*)&LA0[row][quad * 8] = ra[0];
        *(u16x8*)&LA0[row + 64][quad * 8] = ra[1];
        *(u16x8*)&LA1[row][quad * 8] = ra[2];
        *(u16x8*)&LA1[row + 64][quad * 8] = ra[3];
        *(u16x8*)&LA2[row][quad * 8] = ra[4];
        *(u16x8*)&LA2[row + 64][quad * 8] = ra[5];
        *(u16x8*)&LB0[row][quad * 8] = rb[0];
        *(u16x8*)&LB0[row + 64][quad * 8] = rb[1];
        *(u16x8*)&LB1[row][quad * 8] = rb[2];
        *(u16x8*)&LB1[row + 64][quad * 8] = rb[3];
        *(u16x8*)&LB2[row][quad * 8] = rb[4];
        *(u16x8*)&LB2[row + 64][quad * 8] = rb[5];
        __syncthreads();
        bf16x8 a0[4], a1[4], a2[4], b0[4], b1[4], b2[4];
#pragma unroll
        for (int m = 0; m < 4; ++m){
            a0[m] = __builtin_bit_cast(bf16x8, *(const u16x8*)&LA0[wr*64 + m*16 + arow][kg]);
            a1[m] = __builtin_bit_cast(bf16x8, *(const u16x8*)&LA1[wr*64 + m*16 + arow][kg]);
            a2[m] = __builtin_bit_cast(bf16x8, *(const u16x8*)&LA2[wr*64 + m*16 + arow][kg]);
        }
#pragma unroll
        for (int n = 0; n < 4; ++n){
            b0[n] = __builtin_bit_cast(bf16x8, *(const u16x8*)&LB0[wc*64 + n*16 + arow][kg]);
            b1[n] = __builtin_bit_cast(bf16x8, *(const u16x8*)&LB1[wc*64 + n*16 + arow][kg]);
            b2[n] = __builtin_bit_cast(bf16x8, *(const u16x8*)&LB2[wc*64 + n*16 + arow][kg]);
        }
        // accumulate smallest-order terms first
#pragma unroll
        for (int m = 0; m < 4; ++m)
#pragma unroll
            for (int n = 0; n < 4; ++n){
                acc[m][n] = __builtin_amdgcn_mfma_f32_16x16x32_bf16(a2[m], b0[n], acc[m][n], 0, 0, 0);
                acc[m][n] = __builtin_amdgcn_mfma_f32_16x16x32_bf16(a1[m], b1[n], acc[m][n], 0, 0, 0);
                acc[m][n] = __builtin_amdgcn_mfma_f32_16x16x32_bf16(a0[m], b2[n], acc[m][n], 0, 0, 0);
                acc[m][n] = __builtin_amdgcn_mfma_f32_16x16x32_bf16(a1[m], b0[n], acc[m][n], 0, 0, 0);
                acc[m][n] = __builtin_amdgcn_mfma_f32_16x16x32_bf16(a0[m], b1[n], acc[m][n], 0, 0, 0);
                acc[m][n] = __builtin_amdgcn_mfma_f32_16x16x32_bf16(a0[m], b0[n], acc[m][n], 0, 0, 0);
            }
    }
    const int r4 = (l >> 4) * 4, c16 = l & 15;
#pragma unroll
    for (int m = 0; m < 4; ++m){
#pragma unroll
        for (int n = 0; n < 4; ++n){
            int colg = n0 + wc*64 + n*16 + c16;
            float bv = bias[colg];
#pragma unroll
            for (int r = 0; r < 4; ++r){
                int rowg = m0 + wr*64 + m*16 + r4 + r;
                size_t oi = (size_t)rowg * Nn + colg;
                float v = acc[m][n][r] + bv;
                if (EPI == 0){
                    outF[oi] = v;
                } else if (EPI == 1){
                    v = 0.5f * v * (1.0f + erff(v * 0.70710678118654752f));
                    u16 a, b, c;
                    split3(v, a, b, c);
                    oH[oi] = a; oM[oi] = b; oL[oi] = c;
                } else {
                    outF[oi] = v + res[oi];
                }
            }
        }
    }
}

// ---------------- q/k normalize+square -> split-3 (padded), V^T split-3 ----------------

__global__ __launch_bounds__(256)
void qkprep_kernel(const float* __restrict__ QKV,
                   u16* __restrict__ Q0, u16* __restrict__ Q1, u16* __restrict__ Q2,
                   u16* __restrict__ K0, u16* __restrict__ K1, u16* __restrict__ K2,
                   u16* __restrict__ VT0, u16* __restrict__ VT1, u16* __restrict__ VT2){
    __shared__ float vbuf[NP_][65];
    int bh = blockIdx.x;
    int b = bh / H_, h = bh % H_;
    int w = threadIdx.x >> 6, l = threadIdx.x & 63;
    size_t base = (size_t)bh * (NP_ * HD_);
    for (int n = w; n < NP_; n += 4){
        size_t oi = base + (size_t)n * HD_ + l;
        if (n < N_){
            const float* row = QKV + (size_t)(b * N_ + n) * (3 * D_) + h * HD_;
            float qv = row[l], kv = row[D_ + l], vv = row[2 * D_ + l];
            double qs = (double)qv * (double)qv, ks = (double)kv * (double)kv;
            double qr = qs, kr = ks;
            for (int o = 32; o > 0; o >>= 1){ qr += __shfl_xor(qr, o); kr += __shfl_xor(kr, o); }
            float q2 = (float)(qs / qr), k2 = (float)(ks / kr);
            u16 a, bb, c;
            split3(q2, a, bb, c);
            Q0[oi] = a; Q1[oi] = bb; Q2[oi] = c;
            split3(k2, a, bb, c);
            K0[oi] = a; K1[oi] = bb; K2[oi] = c;
            vbuf[n][l] = vv;
        } else {
            Q0[oi] = 0; Q1[oi] = 0; Q2[oi] = 0;
            K0[oi] = 0; K1[oi] = 0; K2[oi] = 0;
            vbuf[n][l] = 0.f;
        }
    }
    __syncthreads();
    size_t vtb = (size_t)bh * (HD_ * NP_);
    for (int idx = threadIdx.x; idx < HD_ * NP_; idx += 256){
        int d = idx / NP_, n = idx % NP_;
        u16 a, bb, c;
        split3(vbuf[n][d], a, bb, c);
        VT0[vtb + idx] = a; VT1[vtb + idx] = bb; VT2[vtb + idx] = c;
    }
}

// ---------------- score via split-3 bf16 MFMA (6-term): S = Q2 @ K2^T ----------------

#define SPAD 72

__global__ __launch_bounds__(256)
void score_mfma3(const u16* __restrict__ Q0, const u16* __restrict__ Q1,
                 const u16* __restrict__ Q2,
                 const u16* __restrict__ K0, const u16* __restrict__ K1,
                 const u16* __restrict__ K2,
                 float* __restrict__ S){
    __shared__ u16 Ql[3][32][SPAD];
    __shared__ u16 Kl[3][32][SPAD];
    int i0 = blockIdx.x * 32;
    int bh = blockIdx.y;
    int tid = threadIdx.x;
    size_t base = (size_t)bh * (NP_ * HD_);
    {
        int r = tid >> 3, q = tid & 7;
        size_t src = base + (size_t)(i0 + r) * HD_ + q * 8;
        *(u16x8*)&Ql[0][r][q * 8] = *(const u16x8*)(Q0 + src);
        *(u16x8*)&Ql[1][r][q * 8] = *(const u16x8*)(Q1 + src);
        *(u16x8*)&Ql[2][r][q * 8] = *(const u16x8*)(Q2 + src);
    }
    const int w = tid >> 6, l = tid & 63;
    const int wm = w >> 1, wn = w & 1;
    const int arow = l & 15, kg0 = (l >> 4) * 8;
    const int r4 = (l >> 4) * 4, c16 = l & 15;
    for (int jt = 0; jt < 7; ++jt){
        __syncthreads();
        {
            int r = tid >> 3, q = tid & 7;
            size_t src = base + (size_t)(jt * 32 + r) * HD_ + q * 8;
            *(u16x8*)&Kl[0][r][q * 8] = *(const u16x8*)(K0 + src);
            *(u16x8*)&Kl[1][r][q * 8] = *(const u16x8*)(K1 + src);
            *(u16x8*)&Kl[2][r][q * 8] = *(const u16x8*)(K2 + src);
        }
        __syncthreads();
        f32x4 acc = {};
#pragma unroll
        for (int kk = 0; kk < 2; ++kk){
            int kg = kk * 32 + kg0;
            bf16x8 a0 = __builtin_bit_cast(bf16x8, *(const u16x8*)&Ql[0][wm*16 + arow][kg]);
            bf16x8 a1 = __builtin_bit_cast(bf16x8, *(const u16x8*)&Ql[1][wm*16 + arow][kg]);
            bf16x8 a2 = __builtin_bit_cast(bf16x8, *(const u16x8*)&Ql[2][wm*16 + arow][kg]);
            bf16x8 b0 = __builtin_bit_cast(bf16x8, *(const u16x8*)&Kl[0][wn*16 + arow][kg]);
            bf16x8 b1 = __builtin_bit_cast(bf16x8, *(const u16x8*)&Kl[1][wn*16 + arow][kg]);
            bf16x8 b2 = __builtin_bit_cast(bf16x8, *(const u16x8*)&Kl[2][wn*16 + arow][kg]);
            acc = __builtin_amdgcn_mfma_f32_16x16x32_bf16(a2, b0, acc, 0, 0, 0);
            acc = __builtin_amdgcn_mfma_f32_16x16x32_bf16(a1, b1, acc, 0, 0, 0);
            acc = __builtin_amdgcn_mfma_f32_16x16x32_bf16(a0, b2, acc, 0, 0, 0);
            acc = __builtin_amdgcn_mfma_f32_16x16x32_bf16(a1, b0, acc, 0, 0, 0);
            acc = __builtin_amdgcn_mfma_f32_16x16x32_bf16(a0, b1, acc, 0, 0, 0);
            acc = __builtin_amdgcn_mfma_f32_16x16x32_bf16(a0, b0, acc, 0, 0, 0);
        }
#pragma unroll
        for (int r = 0; r < 4; ++r){
            int i = i0 + wm * 16 + r4 + r;
            int j = jt * 32 + wn * 16 + c16;
            if (i < N_ && j < N_)
                S[((size_t)bh * N_ + i) * N_ + j] = acc[r];
        }
    }
}

// ---------------- batch-LN stats, two-pass, double ----------------

__global__ __launch_bounds__(256)
void statsA_kernel(const float* __restrict__ S, double* __restrict__ part1){
    int b = blockIdx.y, c = blockIdx.x;
    const float* base = S + (size_t)b * ATTN_PER_B_ + (size_t)c * 7203;
    double s = 0.0;
    for (int i = threadIdx.x; i < 7203; i += 256)
        s += (double)base[i];
    __shared__ double red[4];
    for (int o = 32; o > 0; o >>= 1) s += __shfl_down(s, o);
    if ((threadIdx.x & 63) == 0) red[threadIdx.x >> 6] = s;
    __syncthreads();
    if (threadIdx.x == 0) part1[b * 64 + c] = red[0] + red[1] + red[2] + red[3];
}

__global__ __launch_bounds__(64)
void reduceMu_kernel(const double* __restrict__ part1, double* __restrict__ MU){
    int b = blockIdx.x;
    double s = part1[b * 64 + threadIdx.x];
    for (int o = 32; o > 0; o >>= 1) s += __shfl_down(s, o);
    if (threadIdx.x == 0) MU[b] = s / (double)ATTN_PER_B_;
}

__global__ __launch_bounds__(256)
void statsB_kernel(const float* __restrict__ S, const double* __restrict__ MU,
                   double* __restrict__ part2){
    int b = blockIdx.y, c = blockIdx.x;
    double mu = MU[b];
    const float* base = S + (size_t)b * ATTN_PER_B_ + (size_t)c * 7203;
    double q = 0.0;
    for (int i = threadIdx.x; i < 7203; i += 256){
        double d = (double)base[i] - mu;
        q += d * d;
    }
    __shared__ double red[4];
    for (int o = 32; o > 0; o >>= 1) q += __shfl_down(q, o);
    if ((threadIdx.x & 63) == 0) red[threadIdx.x >> 6] = q;
    __syncthreads();
    if (threadIdx.x == 0) part2[b * 64 + c] = red[0] + red[1] + red[2] + red[3];
}

__global__ __launch_bounds__(64)
void reduceR_kernel(const double* __restrict__ part2, const double* __restrict__ MU,
                    float2* __restrict__ musig){
    int b = blockIdx.x;
    double q = part2[b * 64 + threadIdx.x];
    for (int o = 32; o > 0; o >>= 1) q += __shfl_down(q, o);
    if (threadIdx.x == 0){
        double var = q / (double)ATTN_PER_B_;
        musig[b] = make_float2((float)MU[b], (float)(1.0 / sqrt(var + 1e-5)));
    }
}

// ---------------- attn normalize: S in place + padded split-3 A operand ----------------

__global__ __launch_bounds__(256)
void attnnorm_pad(float* __restrict__ S, const float* __restrict__ wv,
                  const float* __restrict__ bv, const float2* __restrict__ musig,
                  u16* __restrict__ AS0, u16* __restrict__ AS1, u16* __restrict__ AS2){
    int gid = blockIdx.x * 256 + threadIdx.x;
    int jg = gid % 56;
    int rem = gid / 56;
    int i = rem % NP_;
    int bh = rem / NP_;
    int b = bh / H_, h = bh % H_;
    float2 ms = musig[b];
    u16x4 p0, p1, p2;
#pragma unroll
    for (int t = 0; t < 4; ++t){
        int j = jg * 4 + t;
        float val = 0.f;
        if (i < N_ && j < N_){
            size_t si = ((size_t)bh * N_ + i) * N_ + j;
            size_t wi = ((size_t)h * N_ + i) * N_ + j;
            float s = S[si];
            val = (s - ms.x) * ms.y * wv[wi] + bv[wi];
            S[si] = val;
        }
        u16 a, bb, c;
        split3(val, a, bb, c);
        p0[t] = a; p1[t] = bb; p2[t] = c;
    }
    size_t oo = (size_t)bh * (NP_ * NP_) + (size_t)i * NP_ + jg * 4;
    *(u16x4*)&AS0[oo] = p0;
    *(u16x4*)&AS1[oo] = p1;
    *(u16x4*)&AS2[oo] = p2;
}

// ---------------- PV via split-3 bf16 MFMA: Y = attn @ V ----------------
// grid (7 i-tiles, BH); 4 waves each own a 16-col block of HD.

__global__ __launch_bounds__(256)
void pv_mfma3(const u16* __restrict__ AS0, const u16* __restrict__ AS1,
              const u16* __restrict__ AS2,
              const u16* __restrict__ VT0, const u16* __restrict__ VT1,
              const u16* __restrict__ VT2,
              float* __restrict__ Y){
    __shared__ u16 Al[3][32][40];
    __shared__ u16 Vl[3][64][40];
    int i0 = blockIdx.x * 32;
    int bh = blockIdx.y;
    int b = bh / H_, h = bh % H_;
    int tid = threadIdx.x;
    size_t abase = (size_t)bh * (NP_ * NP_) + (size_t)i0 * NP_;
    size_t vbase = (size_t)bh * (HD_ * NP_);
    const int w = tid >> 6, l = tid & 63;
    const int arow = l & 15, kg0 = (l >> 4) * 8;
    const int r4 = (l >> 4) * 4, c16 = l & 15;
    f32x4 acc[2] = {};
    for (int k0 = 0; k0 < NP_; k0 += 32){
        __syncthreads();
        // stage A: 3 splits x 32 rows x 32 cols / 8 = 384 chunks
        for (int c = tid; c < 384; c += 256){
            int s = c >> 7, rem = c & 127;
            int r = rem >> 2, q = rem & 3;
            const u16* src = (s == 0 ? AS0 : (s == 1 ? AS1 : AS2));
            *(u16x8*)&Al[s][r][q * 8] = *(const u16x8*)(src + abase + (size_t)r * NP_ + k0 + q * 8);
        }
        // stage VT: 3 splits x 64 rows x 32 cols / 8 = 768 chunks
        for (int c = tid; c < 768; c += 256){
            int s = c >> 8, rem = c & 255;
            int r = rem >> 2, q = rem & 3;
            const u16* src = (s == 0 ? VT0 : (s == 1 ? VT1 : VT2));
            *(u16x8*)&Vl[s][r][q * 8] = *(const u16x8*)(src + vbase + (size_t)r * NP_ + k0 + q * 8);
        }
        __syncthreads();
        bf16x8 a0[2], a1[2], a2[2];
#pragma unroll
        for (int m = 0; m < 2; ++m){
            a0[m] = __builtin_bit_cast(bf16x8, *(const u16x8*)&Al[0][m*16 + arow][kg0]);
            a1[m] = __builtin_bit_cast(bf16x8, *(const u16x8*)&Al[1][m*16 + arow][kg0]);
            a2[m] = __builtin_bit_cast(bf16x8, *(const u16x8*)&Al[2][m*16 + arow][kg0]);
        }
        bf16x8 b0 = __builtin_bit_cast(bf16x8, *(const u16x8*)&Vl[0][w*16 + arow][kg0]);
        bf16x8 b1 = __builtin_bit_cast(bf16x8, *(const u16x8*)&Vl[1][w*16 + arow][kg0]);
        bf16x8 b2 = __builtin_bit_cast(bf16x8, *(const u16x8*)&Vl[2][w*16 + arow][kg0]);
#pragma unroll
        for (int m = 0; m < 2; ++m){
            acc[m] = __builtin_amdgcn_mfma_f32_16x16x32_bf16(a2[m], b0, acc[m], 0, 0, 0);
            acc[m] = __builtin_amdgcn_mfma_f32_16x16x32_bf16(a1[m], b1, acc[m], 0, 0, 0);
            acc[m] = __builtin_amdgcn_mfma_f32_16x16x32_bf16(a0[m], b2, acc[m], 0, 0, 0);
            acc[m] = __builtin_amdgcn_mfma_f32_16x16x32_bf16(a1[m], b0, acc[m], 0, 0, 0);
            acc[m] = __builtin_amdgcn_mfma_f32_16x16x32_bf16(a0[m], b1, acc[m], 0, 0, 0);
            acc[m] = __builtin_amdgcn_mfma_f32_16x16x32_bf16(a0[m], b0, acc[m], 0, 0, 0);
        }
    }
#pragma unroll
    for (int m = 0; m < 2; ++m)
#pragma unroll
        for (int r = 0; r < 4; ++r){
            int i = i0 + m * 16 + r4 + r;
            if (i < N_)
                Y[((size_t)b * N_ + i) * D_ + h * HD_ + w * 16 + c16] = acc[m][r];
        }
}

// ---------------- final pooling ----------------

__global__ __launch_bounds__(256)
void rowdot_kernel(const float* __restrict__ xf, const float* __restrict__ pw,
                   const float* __restrict__ pb, float* __restrict__ sraw){
    int row = blockIdx.x, tid = threadIdx.x;
    const float* base = xf + (size_t)row * D_;
    float s = base[tid] * pw[tid] + base[tid + 256] * pw[tid + 256] + base[tid + 512] * pw[tid + 512];
    __shared__ float red[4];
    for (int o = 32; o > 0; o >>= 1) s += __shfl_xor(s, o);
    if ((tid & 63) == 0) red[tid >> 6] = s;
    __syncthreads();
    if (tid == 0) sraw[row] = red[0] + red[1] + red[2] + red[3] + pb[0];
}

__global__ __launch_bounds__(256)
void softmax196_kernel(const float* __restrict__ sraw, float* __restrict__ aw){
    int b = blockIdx.x, tid = threadIdx.x;
    __shared__ float red[8];
    float v = (tid < N_) ? sraw[b * N_ + tid] : -3.0e38f;
    float m = v;
    for (int o = 32; o > 0; o >>= 1) m = fmaxf(m, __shfl_xor(m, o));
    if ((tid & 63) == 0) red[tid >> 6] = m;
    __syncthreads();
    float M = fmaxf(fmaxf(red[0], red[1]), fmaxf(red[2], red[3]));
    float e = (tid < N_) ? expf(v - M) : 0.f;
    float s = e;
    for (int o = 32; o > 0; o >>= 1) s += __shfl_xor(s, o);
    if ((tid & 63) == 0) red[4 + (tid >> 6)] = s;
    __syncthreads();
    float S = red[4] + red[5] + red[6] + red[7];
    if (tid < N_) aw[b * N_ + tid] = e / S;
}

__global__ __launch_bounds__(256)
void poolmat_kernel(const float* __restrict__ aw, const float* __restrict__ xf,
                    float* __restrict__ pooled){
    int b = blockIdx.y;
    int d = blockIdx.x * 256 + threadIdx.x;
    float acc = 0.f;
    for (int n = 0; n < N_; ++n)
        acc += aw[b * N_ + n] * xf[((size_t)b * N_ + n) * D_ + d];
    pooled[b * D_ + d] = acc;
}

__global__ __launch_bounds__(256)
void fc_kernel(const float* __restrict__ pooled, const float* __restrict__ fw,
               const float* __restrict__ fb, float* __restrict__ out){
    int b = blockIdx.y;
    int c = blockIdx.x * 256 + threadIdx.x;
    if (c >= CLS_) return;
    float acc = fb[c];
    for (int d = 0; d < D_; ++d)
        acc += pooled[b * D_ + d] * fw[(size_t)d * CLS_ + c];
    out[b * CLS_ + c] = acc;
}

__global__ __launch_bounds__(256)
void zero_logits(float* __restrict__ out){
    out[blockIdx.x * 256 + threadIdx.x] = 0.f;
}

// ---------------- launcher ----------------

extern "C" void kernel_launch(void* const* d_in, const int* in_sizes, int n_in,
                              void* d_out, int out_size, void* d_ws, size_t ws_size,
                              hipStream_t stream){
    const float* x        = (const float*)d_in[0];
    const float* pos_emb  = (const float*)d_in[1];
    const float* qkv_w    = (const float*)d_in[2];
    const float* qkv_b    = (const float*)d_in[3];
    const float* proj_w   = (const float*)d_in[4];
    const float* proj_b   = (const float*)d_in[5];
    const float* lin1_w   = (const float*)d_in[6];
    const float* lin1_b   = (const float*)d_in[7];
    const float* lin2_w   = (const float*)d_in[8];
    const float* lin2_b   = (const float*)d_in[9];
    const float* pre_ln_w = (const float*)d_in[10];
    const float* pre_ln_b = (const float*)d_in[11];
    const float* norm1_w  = (const float*)d_in[12];
    const float* norm1_b  = (const float*)d_in[13];
    const float* attn_ln_w= (const float*)d_in[14];
    const float* attn_ln_b= (const float*)d_in[15];
    const float* fln_w    = (const float*)d_in[16];
    const float* fln_b    = (const float*)d_in[17];
    const float* pool_w   = (const float*)d_in[18];
    const float* pool_b   = (const float*)d_in[19];
    const float* fc_w     = (const float*)d_in[20];
    const float* fc_b     = (const float*)d_in[21];

    float* dout = (float*)d_out;
    float* S = dout + (size_t)B_ * CLS_;   // attn region (B,H,196,196) f32

    char* ws = (char*)d_ws;
    size_t off = 0;
    auto alloc = [&](size_t bytes)->char*{
        char* p = ws + off;
        off += (bytes + 255) & ~(size_t)255;
        return p;
    };
    float* SRC   = (float*)alloc((size_t)NTOK_ * D_ * 4);
    float* Yb    = (float*)alloc((size_t)NTOK_ * D_ * 4);
    float* TMP   = (float*)alloc((size_t)NTOK_ * D_ * 4);
    float* QKV   = (float*)alloc((size_t)NTOK_ * 3 * D_ * 4);
    u16*   A0    = (u16*)  alloc((size_t)NTOK_ * D_ * 2);
    u16*   A1    = (u16*)  alloc((size_t)NTOK_ * D_ * 2);
    u16*   A2    = (u16*)  alloc((size_t)NTOK_ * D_ * 2);
    u16*   W0    = (u16*)  alloc((size_t)FF_ * D_ * 2);
    u16*   W1    = (u16*)  alloc((size_t)FF_ * D_ * 2);
    u16*   W2    = (u16*)  alloc((size_t)FF_ * D_ * 2);
    u16*   F0    = (u16*)  alloc((size_t)NTOK_ * FF_ * 2);   // aliases attn split-3 A
    u16*   F1    = (u16*)  alloc((size_t)NTOK_ * FF_ * 2);
    u16*   F2    = (u16*)  alloc((size_t)NTOK_ * FF_ * 2);
    u16*   Q0b   = (u16*)  alloc((size_t)BH_ * NP_ * HD_ * 2);
    u16*   Q1b   = (u16*)  alloc((size_t)BH_ * NP_ * HD_ * 2);
    u16*   Q2b   = (u16*)  alloc((size_t)BH_ * NP_ * HD_ * 2);
    u16*   K0b   = (u16*)  alloc((size_t)BH_ * NP_ * HD_ * 2);
    u16*   K1b   = (u16*)  alloc((size_t)BH_ * NP_ * HD_ * 2);
    u16*   K2b   = (u16*)  alloc((size_t)BH_ * NP_ * HD_ * 2);
    u16*   VT0   = (u16*)  alloc((size_t)BH_ * HD_ * NP_ * 2);
    u16*   VT1   = (u16*)  alloc((size_t)BH_ * HD_ * NP_ * 2);
    u16*   VT2   = (u16*)  alloc((size_t)BH_ * HD_ * NP_ * 2);
    double* P1   = (double*)alloc((size_t)B_ * 64 * 8);
    double* P2   = (double*)alloc((size_t)B_ * 64 * 8);
    double* MU   = (double*)alloc((size_t)B_ * 8);
    float2* MUSIG= (float2*)alloc((size_t)B_ * 8);
    float* SRAW  = (float*)alloc((size_t)NTOK_ * 4);
    float* AW    = (float*)alloc((size_t)NTOK_ * 4);
    float* POOLED= (float*)alloc((size_t)B_ * D_ * 4);
    u16* AS0 = F0, *AS1 = F1, *AS2 = F2;   // NTOK*FF == BH*NP*NP exactly

    if (ws_size < off){
        zero_logits<<<(B_ * CLS_) / 256, 256, 0, stream>>>(dout);
        return;
    }

    const int cvt_blocks = NTOK_ * D_ / (256 * 4);  // 4704
    const int an_blocks = (int)((size_t)BH_ * NP_ * NP_ / (256 * 4));  // 18816

    addpos_kernel<<<cvt_blocks, 256, 0, stream>>>(x, pos_emb, SRC);

    for (int l = 0; l < L_; ++l){
        const float* qw  = qkv_w  + (size_t)l * D_ * 3 * D_;
        const float* qb  = qkv_b  + (size_t)l * 3 * D_;
        const float* pw  = proj_w + (size_t)l * D_ * D_;
        const float* pb  = proj_b + (size_t)l * D_;
        const float* l1w = lin1_w + (size_t)l * D_ * FF_;
        const float* l1b = lin1_b + (size_t)l * FF_;
        const float* l2w = lin2_w + (size_t)l * FF_ * D_;
        const float* l2b = lin2_b + (size_t)l * D_;
        const float* prw = pre_ln_w + (size_t)l * D_;
        const float* prb = pre_ln_b + (size_t)l * D_;
        const float* n1w = norm1_w + (size_t)l * D_;
        const float* n1b = norm1_b + (size_t)l * D_;
        const float* awl = attn_ln_w + (size_t)l * H_ * N_ * N_;
        const float* abl = attn_ln_b + (size_t)l * H_ * N_ * N_;

        // pre-LN -> split3 A operand
        ln_row<<<NTOK_, 256, 0, stream>>>(SRC, prw, prb, nullptr, A0, A1, A2);
        // qkv
        wtrans_kernel<<<dim3(3 * D_ / 32, D_ / 32), 256, 0, stream>>>(qw, W0, W1, W2, D_, 3 * D_);
        gemm_split3<0><<<dim3(3 * D_ / 128, NTOK_ / 128), 256, 0, stream>>>(
            A0, A1, A2, W0, W1, W2, qb, nullptr, QKV, nullptr, nullptr, nullptr,
            NTOK_, 3 * D_, D_);
        // q/k normalize+square -> split3 (padded), V^T split3
        qkprep_kernel<<<BH_, 256, 0, stream>>>(QKV, Q0b, Q1b, Q2b, K0b, K1b, K2b,
                                               VT0, VT1, VT2);
        // scores via split-3 MFMA (6-term)
        score_mfma3<<<dim3(7, BH_), 256, 0, stream>>>(Q0b, Q1b, Q2b, K0b, K1b, K2b, S);
        // batch LN over (H,N,N): two-pass double stats
        statsA_kernel<<<dim3(64, B_), 256, 0, stream>>>(S, P1);
        reduceMu_kernel<<<B_, 64, 0, stream>>>(P1, MU);
        statsB_kernel<<<dim3(64, B_), 256, 0, stream>>>(S, MU, P2);
        reduceR_kernel<<<B_, 64, 0, stream>>>(P2, MU, MUSIG);
        attnnorm_pad<<<an_blocks, 256, 0, stream>>>(S, awl, abl, MUSIG, AS0, AS1, AS2);
        // attn @ V via split-3 MFMA -> Yb (B,N,D)
        pv_mfma3<<<dim3(7, BH_), 256, 0, stream>>>(AS0, AS1, AS2, VT0, VT1, VT2, Yb);
        // proj + residual
        cvt_split3<<<cvt_blocks, 256, 0, stream>>>(Yb, A0, A1, A2);
        wtrans_kernel<<<dim3(D_ / 32, D_ / 32), 256, 0, stream>>>(pw, W0, W1, W2, D_, D_);
        gemm_split3<2><<<dim3(D_ / 128, NTOK_ / 128), 256, 0, stream>>>(
            A0, A1, A2, W0, W1, W2, pb, SRC, TMP, nullptr, nullptr, nullptr,
            NTOK_, D_, D_);
        // norm1 -> SRC f32 + split3
        ln_row<<<NTOK_, 256, 0, stream>>>(TMP, n1w, n1b, SRC, A0, A1, A2);
        // MLP
        wtrans_kernel<<<dim3(FF_ / 32, D_ / 32), 256, 0, stream>>>(l1w, W0, W1, W2, D_, FF_);
        gemm_split3<1><<<dim3(FF_ / 128, NTOK_ / 128), 256, 0, stream>>>(
            A0, A1, A2, W0, W1, W2, l1b, nullptr, nullptr, F0, F1, F2,
            NTOK_, FF_, D_);
        wtrans_kernel<<<dim3(D_ / 32, FF_ / 32), 256, 0, stream>>>(l2w, W0, W1, W2, FF_, D_);
        gemm_split3<2><<<dim3(D_ / 128, NTOK_ / 128), 256, 0, stream>>>(
            F0, F1, F2, W0, W1, W2, l2b, SRC, SRC, nullptr, nullptr, nullptr,
            NTOK_, D_, FF_);
    }

    // final LN -> Yb (xf)
    ln_row<<<NTOK_, 256, 0, stream>>>(SRC, fln_w, fln_b, Yb, nullptr, nullptr, nullptr);
    // sequence pooling
    rowdot_kernel<<<NTOK_, 256, 0, stream>>>(Yb, pool_w, pool_b, SRAW);
    softmax196_kernel<<<B_, 256, 0, stream>>>(SRAW, AW);
    poolmat_kernel<<<dim3(D_ / 256, B_), 256, 0, stream>>>(AW, Yb, POOLED);
    fc_kernel<<<dim3((CLS_ + 255) / 256, B_), 256, 0, stream>>>(POOLED, fc_w, fc_b, dout);
}

// Round 10
// 9699.116 us; speedup vs baseline: 2.2598x; 1.2559x over previous
//
#include <hip/hip_runtime.h>
#include <hip/hip_bf16.h>

typedef unsigned short u16;
typedef __bf16 bf16x8 __attribute__((ext_vector_type(8)));
typedef _Float16 f16x8 __attribute__((ext_vector_type(8)));
typedef float f32x4 __attribute__((ext_vector_type(4)));
typedef u16 u16x8 __attribute__((ext_vector_type(8)));
typedef u16 u16x4 __attribute__((ext_vector_type(4)));

#define B_ 32
#define N_ 196
#define D_ 768
#define H_ 12
#define L_ 12
#define FF_ 3072
#define CLS_ 1000
#define HD_ 64
#define BH_ 384
#define NTOK_ 6272
#define NP_ 224
#define ATTN_PER_B_ 460992   /* H*N*N */
#define NN_ 38416            /* N*N */

__device__ inline u16 f2bf(float f){
    __bf16 h = (__bf16)f;
    return __builtin_bit_cast(u16, h);
}
__device__ inline float bf2f(u16 u){
    __bf16 h = __builtin_bit_cast(__bf16, u);
    return (float)h;
}
// bf16 3-way split: v ~= s0+s1+s2, rep error ~2^-27
__device__ inline void split3(float v, u16& s0, u16& s1, u16& s2){
    s0 = f2bf(v);
    float r = v - bf2f(s0);
    s1 = f2bf(r);
    r = r - bf2f(s1);
    s2 = f2bf(r);
}
__device__ inline u16 f2h(float f){
    _Float16 h = (_Float16)f;
    return __builtin_bit_cast(u16, h);
}
__device__ inline float h2f(u16 u){
    _Float16 h = __builtin_bit_cast(_Float16, u);
    return (float)h;
}
// fp16 2-way split: v ~= h0+h1, rep error ~2^-23
__device__ inline void split2h(float v, u16& h0, u16& h1){
    h0 = f2h(v);
    h1 = f2h(v - h2f(h0));
}

// ---------------- elementwise / conversion ----------------

__global__ __launch_bounds__(256)
void addpos_kernel(const float* __restrict__ x, const float* __restrict__ pos,
                   float* __restrict__ src){
    size_t gid = (size_t)blockIdx.x * 256 + threadIdx.x;
    size_t e = gid * 4;
    size_t tok = e / D_;
    size_t d = e % D_;
    size_t pe = (tok % N_) * D_ + d;
    float4 a = *(const float4*)(x + e);
    float4 p = *(const float4*)(pos + pe);
    float4 o = make_float4(a.x + p.x, a.y + p.y, a.z + p.z, a.w + p.w);
    *(float4*)(src + e) = o;
}

// f32 -> fp16 split-2
__global__ __launch_bounds__(256)
void cvt_split2h(const float* __restrict__ in, u16* __restrict__ o0,
                 u16* __restrict__ o1){
    size_t e = ((size_t)blockIdx.x * 256 + threadIdx.x) * 4;
    float4 v = *(const float4*)(in + e);
    u16x4 p0, p1;
    float vv[4] = {v.x, v.y, v.z, v.w};
#pragma unroll
    for (int t = 0; t < 4; ++t){
        u16 a, b;
        split2h(vv[t], a, b);
        p0[t] = a; p1[t] = b;
    }
    *(u16x4*)(o0 + e) = p0;
    *(u16x4*)(o1 + e) = p1;
}

// weight transpose + fp16 split-2: in (K, Nn) f32 -> out (Nn, K)
__global__ __launch_bounds__(256)
void wtrans_kernel(const float* __restrict__ in, u16* __restrict__ o0,
                   u16* __restrict__ o1, int K, int Nn){
    __shared__ float t[32][33];
    int n0 = blockIdx.x * 32, k0 = blockIdx.y * 32;
    int tx = threadIdx.x & 31, ty = threadIdx.x >> 5;   // ty in [0,8)
#pragma unroll
    for (int r = 0; r < 4; ++r)
        t[ty + 8*r][tx] = in[(size_t)(k0 + ty + 8*r) * Nn + n0 + tx];
    __syncthreads();
#pragma unroll
    for (int r = 0; r < 4; ++r){
        float v = t[tx][ty + 8*r];
        size_t oi = (size_t)(n0 + ty + 8*r) * K + k0 + tx;
        u16 a, b;
        split2h(v, a, b);
        o0[oi] = a; o1[oi] = b;
    }
}

// ---------------- row LayerNorm (768 cols), optional fp16 split-2 out ----------------

__global__ __launch_bounds__(256)
void ln_row(const float* __restrict__ in, const float* __restrict__ w,
            const float* __restrict__ bb, float* __restrict__ outF,
            u16* __restrict__ o0, u16* __restrict__ o1){
    int row = blockIdx.x, tid = threadIdx.x;
    const float* base = in + (size_t)row * D_;
    float x0 = base[tid], x1 = base[tid + 256], x2 = base[tid + 512];
    float s = x0 + x1 + x2;
    float q = x0*x0 + x1*x1 + x2*x2;
    __shared__ float red[8];
    for (int o = 32; o > 0; o >>= 1){ s += __shfl_down(s, o); q += __shfl_down(q, o); }
    if ((tid & 63) == 0){ red[tid >> 6] = s; red[4 + (tid >> 6)] = q; }
    __syncthreads();
    s = red[0] + red[1] + red[2] + red[3];
    q = red[4] + red[5] + red[6] + red[7];
    float mu = s * (1.f / D_);
    float rv = rsqrtf(q * (1.f / D_) - mu * mu + 1e-5f);
#pragma unroll
    for (int t = 0; t < 3; ++t){
        int c = tid + t * 256;
        float x = (t == 0 ? x0 : (t == 1 ? x1 : x2));
        float val = (x - mu) * rv * w[c] + bb[c];
        size_t oi = (size_t)row * D_ + c;
        if (outF) outF[oi] = val;
        if (o0){
            u16 a, b;
            split2h(val, a, b);
            o0[oi] = a; o1[oi] = b;
        }
    }
}

// ---------------- fp16 split-2 GEMM: C = (A0+A1)(B0+B1)^T, 4-term exact ----------------
// EPI 0: outF = acc + bias
// EPI 1: split2h out = gelu(acc + bias)
// EPI 2: outF = acc + bias + res

template<int EPI>
__global__ __launch_bounds__(256)
void gemm_f16s2(const u16* __restrict__ A0, const u16* __restrict__ A1,
                const u16* __restrict__ B0, const u16* __restrict__ B1,
                const float* __restrict__ bias, const float* __restrict__ res,
                float* __restrict__ outF, u16* __restrict__ oH,
                u16* __restrict__ oL, int M, int Nn, int K){
    __shared__ u16 LA0[128][40];
    __shared__ u16 LA1[128][40];
    __shared__ u16 LB0[128][40];
    __shared__ u16 LB1[128][40];
    const int tid = threadIdx.x;
    const int w = tid >> 6, l = tid & 63;
    const int wr = w >> 1, wc = w & 1;
    const int m0 = blockIdx.y * 128, n0 = blockIdx.x * 128;
    f32x4 acc[4][4] = {};
    const int row = tid >> 2, quad = tid & 3;
    const size_t aoff = (size_t)(m0 + row) * K + quad * 8;
    const size_t boff = (size_t)(n0 + row) * K + quad * 8;
    const size_t K64 = (size_t)64 * K;
    const int arow = l & 15, kg = (l >> 4) * 8;
    for (int k0 = 0; k0 < K; k0 += 32){
        u16x8 ra[4], rb[4];
        ra[0] = *(const u16x8*)(A0 + aoff + k0);
        ra[1] = *(const u16x8*)(A0 + aoff + K64 + k0);
        ra[2] = *(const u16x8*)(A1 + aoff + k0);
        ra[3] = *(const u16x8*)(A1 + aoff + K64 + k0);
        rb[0] = *(const u16x8*)(B0 + boff + k0);
        rb[1] = *(const u16x8*)(B0 + boff + K64 + k0);
        rb[2] = *(const u16x8*)(B1 + boff + k0);
        rb[3] = *(const u16x8*)(B1 + boff + K64 + k0);
        __syncthreads();
        *(u16x8*)&LA0[row][quad * 8] = ra[0];
        *(u16x8*)&LA0[row + 64][quad * 8] = ra[1];
        *(u16x8*)&LA1[row][quad * 8] = ra[2];
        *(u16x8*)&LA1[row + 64][quad * 8] = ra[3];
        *(u16x8*)&LB0[row][quad * 8] = rb[0];
        *(u16x8*)&LB0[row + 64][quad * 8] = rb[1];
        *(u16x8*)&LB1[row][quad * 8] = rb[2];
        *(u16x8*)&LB1[row + 64][quad * 8] = rb[3];
        __syncthreads();
        f16x8 a0[4], a1[4], b0[4], b1[4];
#pragma unroll
        for (int m = 0; m < 4; ++m){
            a0[m] = __builtin_bit_cast(f16x8, *(const u16x8*)&LA0[wr*64 + m*16 + arow][kg]);
            a1[m] = __builtin_bit_cast(f16x8, *(const u16x8*)&LA1[wr*64 + m*16 + arow][kg]);
        }
#pragma unroll
        for (int n = 0; n < 4; ++n){
            b0[n] = __builtin_bit_cast(f16x8, *(const u16x8*)&LB0[wc*64 + n*16 + arow][kg]);
            b1[n] = __builtin_bit_cast(f16x8, *(const u16x8*)&LB1[wc*64 + n*16 + arow][kg]);
        }
        // accumulate smallest-order terms first
#pragma unroll
        for (int m = 0; m < 4; ++m)
#pragma unroll
            for (int n = 0; n < 4; ++n){
                acc[m][n] = __builtin_amdgcn_mfma_f32_16x16x32_f16(a1[m], b1[n], acc[m][n], 0, 0, 0);
                acc[m][n] = __builtin_amdgcn_mfma_f32_16x16x32_f16(a1[m], b0[n], acc[m][n], 0, 0, 0);
                acc[m][n] = __builtin_amdgcn_mfma_f32_16x16x32_f16(a0[m], b1[n], acc[m][n], 0, 0, 0);
                acc[m][n] = __builtin_amdgcn_mfma_f32_16x16x32_f16(a0[m], b0[n], acc[m][n], 0, 0, 0);
            }
    }
    const int r4 = (l >> 4) * 4, c16 = l & 15;
#pragma unroll
    for (int m = 0; m < 4; ++m){
#pragma unroll
        for (int n = 0; n < 4; ++n){
            int colg = n0 + wc*64 + n*16 + c16;
            float bv = bias[colg];
#pragma unroll
            for (int r = 0; r < 4; ++r){
                int rowg = m0 + wr*64 + m*16 + r4 + r;
                size_t oi = (size_t)rowg * Nn + colg;
                float v = acc[m][n][r] + bv;
                if (EPI == 0){
                    outF[oi] = v;
                } else if (EPI == 1){
                    v = 0.5f * v * (1.0f + erff(v * 0.70710678118654752f));
                    u16 a, b;
                    split2h(v, a, b);
                    oH[oi] = a; oL[oi] = b;
                } else {
                    outF[oi] = v + res[oi];
                }
            }
        }
    }
}

// ---------------- q/k normalize+square -> bf16 split-3 (padded), V^T split-3 ----------------

__global__ __launch_bounds__(256)
void qkprep_kernel(const float* __restrict__ QKV,
                   u16* __restrict__ Q0, u16* __restrict__ Q1, u16* __restrict__ Q2,
                   u16* __restrict__ K0, u16* __restrict__ K1, u16* __restrict__ K2,
                   u16* __restrict__ VT0, u16* __restrict__ VT1, u16* __restrict__ VT2){
    __shared__ float vbuf[NP_][65];
    int bh = blockIdx.x;
    int b = bh / H_, h = bh % H_;
    int w = threadIdx.x >> 6, l = threadIdx.x & 63;
    size_t base = (size_t)bh * (NP_ * HD_);
    for (int n = w; n < NP_; n += 4){
        size_t oi = base + (size_t)n * HD_ + l;
        if (n < N_){
            const float* row = QKV + (size_t)(b * N_ + n) * (3 * D_) + h * HD_;
            float qv = row[l], kv = row[D_ + l], vv = row[2 * D_ + l];
            double qs = (double)qv * (double)qv, ks = (double)kv * (double)kv;
            double qr = qs, kr = ks;
            for (int o = 32; o > 0; o >>= 1){ qr += __shfl_xor(qr, o); kr += __shfl_xor(kr, o); }
            float q2 = (float)(qs / qr), k2 = (float)(ks / kr);
            u16 a, bb, c;
            split3(q2, a, bb, c);
            Q0[oi] = a; Q1[oi] = bb; Q2[oi] = c;
            split3(k2, a, bb, c);
            K0[oi] = a; K1[oi] = bb; K2[oi] = c;
            vbuf[n][l] = vv;
        } else {
            Q0[oi] = 0; Q1[oi] = 0; Q2[oi] = 0;
            K0[oi] = 0; K1[oi] = 0; K2[oi] = 0;
            vbuf[n][l] = 0.f;
        }
    }
    __syncthreads();
    size_t vtb = (size_t)bh * (HD_ * NP_);
    for (int idx = threadIdx.x; idx < HD_ * NP_; idx += 256){
        int d = idx / NP_, n = idx % NP_;
        u16 a, bb, c;
        split3(vbuf[n][d], a, bb, c);
        VT0[vtb + idx] = a; VT1[vtb + idx] = bb; VT2[vtb + idx] = c;
    }
}

// ---------------- score via bf16 split-3 MFMA (6-term): S = Q2 @ K2^T ----------------

#define SPAD 72

__global__ __launch_bounds__(256)
void score_mfma3(const u16* __restrict__ Q0, const u16* __restrict__ Q1,
                 const u16* __restrict__ Q2,
                 const u16* __restrict__ K0, const u16* __restrict__ K1,
                 const u16* __restrict__ K2,
                 float* __restrict__ S){
    __shared__ u16 Ql[3][32][SPAD];
    __shared__ u16 Kl[3][32][SPAD];
    int i0 = blockIdx.x * 32;
    int bh = blockIdx.y;
    int tid = threadIdx.x;
    size_t base = (size_t)bh * (NP_ * HD_);
    {
        int r = tid >> 3, q = tid & 7;
        size_t src = base + (size_t)(i0 + r) * HD_ + q * 8;
        *(u16x8*)&Ql[0][r][q * 8] = *(const u16x8*)(Q0 + src);
        *(u16x8*)&Ql[1][r][q * 8] = *(const u16x8*)(Q1 + src);
        *(u16x8*)&Ql[2][r][q * 8] = *(const u16x8*)(Q2 + src);
    }
    const int w = tid >> 6, l = tid & 63;
    const int wm = w >> 1, wn = w & 1;
    const int arow = l & 15, kg0 = (l >> 4) * 8;
    const int r4 = (l >> 4) * 4, c16 = l & 15;
    for (int jt = 0; jt < 7; ++jt){
        __syncthreads();
        {
            int r = tid >> 3, q = tid & 7;
            size_t src = base + (size_t)(jt * 32 + r) * HD_ + q * 8;
            *(u16x8*)&Kl[0][r][q * 8] = *(const u16x8*)(K0 + src);
            *(u16x8*)&Kl[1][r][q * 8] = *(const u16x8*)(K1 + src);
            *(u16x8*)&Kl[2][r][q * 8] = *(const u16x8*)(K2 + src);
        }
        __syncthreads();
        f32x4 acc = {};
#pragma unroll
        for (int kk = 0; kk < 2; ++kk){
            int kg = kk * 32 + kg0;
            bf16x8 a0 = __builtin_bit_cast(bf16x8, *(const u16x8*)&Ql[0][wm*16 + arow][kg]);
            bf16x8 a1 = __builtin_bit_cast(bf16x8, *(const u16x8*)&Ql[1][wm*16 + arow][kg]);
            bf16x8 a2 = __builtin_bit_cast(bf16x8, *(const u16x8*)&Ql[2][wm*16 + arow][kg]);
            bf16x8 b0 = __builtin_bit_cast(bf16x8, *(const u16x8*)&Kl[0][wn*16 + arow][kg]);
            bf16x8 b1 = __builtin_bit_cast(bf16x8, *(const u16x8*)&Kl[1][wn*16 + arow][kg]);
            bf16x8 b2 = __builtin_bit_cast(bf16x8, *(const u16x8*)&Kl[2][wn*16 + arow][kg]);
            acc = __builtin_amdgcn_mfma_f32_16x16x32_bf16(a2, b0, acc, 0, 0, 0);
            acc = __builtin_amdgcn_mfma_f32_16x16x32_bf16(a1, b1, acc, 0, 0, 0);
            acc = __builtin_amdgcn_mfma_f32_16x16x32_bf16(a0, b2, acc, 0, 0, 0);
            acc = __builtin_amdgcn_mfma_f32_16x16x32_bf16(a1, b0, acc, 0, 0, 0);
            acc = __builtin_amdgcn_mfma_f32_16x16x32_bf16(a0, b1, acc, 0, 0, 0);
            acc = __builtin_amdgcn_mfma_f32_16x16x32_bf16(a0, b0, acc, 0, 0, 0);
        }
#pragma unroll
        for (int r = 0; r < 4; ++r){
            int i = i0 + wm * 16 + r4 + r;
            int j = jt * 32 + wn * 16 + c16;
            if (i < N_ && j < N_)
                S[((size_t)bh * N_ + i) * N_ + j] = acc[r];
        }
    }
}

// ---------------- batch-LN stats, two-pass, double ----------------

__global__ __launch_bounds__(256)
void statsA_kernel(const float* __restrict__ S, double* __restrict__ part1){
    int b = blockIdx.y, c = blockIdx.x;
    const float* base = S + (size_t)b * ATTN_PER_B_ + (size_t)c * 7203;
    double s = 0.0;
    for (int i = threadIdx.x; i < 7203; i += 256)
        s += (double)base[i];
    __shared__ double red[4];
    for (int o = 32; o > 0; o >>= 1) s += __shfl_down(s, o);
    if ((threadIdx.x & 63) == 0) red[threadIdx.x >> 6] = s;
    __syncthreads();
    if (threadIdx.x == 0) part1[b * 64 + c] = red[0] + red[1] + red[2] + red[3];
}

__global__ __launch_bounds__(64)
void reduceMu_kernel(const double* __restrict__ part1, double* __restrict__ MU){
    int b = blockIdx.x;
    double s = part1[b * 64 + threadIdx.x];
    for (int o = 32; o > 0; o >>= 1) s += __shfl_down(s, o);
    if (threadIdx.x == 0) MU[b] = s / (double)ATTN_PER_B_;
}

__global__ __launch_bounds__(256)
void statsB_kernel(const float* __restrict__ S, const double* __restrict__ MU,
                   double* __restrict__ part2){
    int b = blockIdx.y, c = blockIdx.x;
    double mu = MU[b];
    const float* base = S + (size_t)b * ATTN_PER_B_ + (size_t)c * 7203;
    double q = 0.0;
    for (int i = threadIdx.x; i < 7203; i += 256){
        double d = (double)base[i] - mu;
        q += d * d;
    }
    __shared__ double red[4];
    for (int o = 32; o > 0; o >>= 1) q += __shfl_down(q, o);
    if ((threadIdx.x & 63) == 0) red[threadIdx.x >> 6] = q;
    __syncthreads();
    if (threadIdx.x == 0) part2[b * 64 + c] = red[0] + red[1] + red[2] + red[3];
}

__global__ __launch_bounds__(64)
void reduceR_kernel(const double* __restrict__ part2, const double* __restrict__ MU,
                    float2* __restrict__ musig){
    int b = blockIdx.x;
    double q = part2[b * 64 + threadIdx.x];
    for (int o = 32; o > 0; o >>= 1) q += __shfl_down(q, o);
    if (threadIdx.x == 0){
        double var = q / (double)ATTN_PER_B_;
        musig[b] = make_float2((float)MU[b], (float)(1.0 / sqrt(var + 1e-5)));
    }
}

// ---------------- attn normalize: S in place + padded bf16 split-3 A operand ----------------

__global__ __launch_bounds__(256)
void attnnorm_pad(float* __restrict__ S, const float* __restrict__ wv,
                  const float* __restrict__ bv, const float2* __restrict__ musig,
                  u16* __restrict__ AS0, u16* __restrict__ AS1, u16* __restrict__ AS2){
    int gid = blockIdx.x * 256 + threadIdx.x;
    int jg = gid % 56;
    int rem = gid / 56;
    int i = rem % NP_;
    int bh = rem / NP_;
    int b = bh / H_, h = bh % H_;
    float2 ms = musig[b];
    u16x4 p0, p1, p2;
#pragma unroll
    for (int t = 0; t < 4; ++t){
        int j = jg * 4 + t;
        float val = 0.f;
        if (i < N_ && j < N_){
            size_t si = ((size_t)bh * N_ + i) * N_ + j;
            size_t wi = ((size_t)h * N_ + i) * N_ + j;
            float s = S[si];
            val = (s - ms.x) * ms.y * wv[wi] + bv[wi];
            S[si] = val;
        }
        u16 a, bb, c;
        split3(val, a, bb, c);
        p0[t] = a; p1[t] = bb; p2[t] = c;
    }
    size_t oo = (size_t)bh * (NP_ * NP_) + (size_t)i * NP_ + jg * 4;
    *(u16x4*)&AS0[oo] = p0;
    *(u16x4*)&AS1[oo] = p1;
    *(u16x4*)&AS2[oo] = p2;
}

// ---------------- PV via bf16 split-3 MFMA: Y = attn @ V ----------------

__global__ __launch_bounds__(256)
void pv_mfma3(const u16* __restrict__ AS0, const u16* __restrict__ AS1,
              const u16* __restrict__ AS2,
              const u16* __restrict__ VT0, const u16* __restrict__ VT1,
              const u16* __restrict__ VT2,
              float* __restrict__ Y){
    __shared__ u16 Al[3][32][40];
    __shared__ u16 Vl[3][64][40];
    int i0 = blockIdx.x * 32;
    int bh = blockIdx.y;
    int b = bh / H_, h = bh % H_;
    int tid = threadIdx.x;
    size_t abase = (size_t)bh * (NP_ * NP_) + (size_t)i0 * NP_;
    size_t vbase = (size_t)bh * (HD_ * NP_);
    const int w = tid >> 6, l = tid & 63;
    const int arow = l & 15, kg0 = (l >> 4) * 8;
    const int r4 = (l >> 4) * 4, c16 = l & 15;
    f32x4 acc[2] = {};
    for (int k0 = 0; k0 < NP_; k0 += 32){
        __syncthreads();
        for (int c = tid; c < 384; c += 256){
            int s = c >> 7, rem = c & 127;
            int r = rem >> 2, q = rem & 3;
            const u16* src = (s == 0 ? AS0 : (s == 1 ? AS1 : AS2));
            *(u16x8*)&Al[s][r][q * 8] = *(const u16x8*)(src + abase + (size_t)r * NP_ + k0 + q * 8);
        }
        for (int c = tid; c < 768; c += 256){
            int s = c >> 8, rem = c & 255;
            int r = rem >> 2, q = rem & 3;
            const u16* src = (s == 0 ? VT0 : (s == 1 ? VT1 : VT2));
            *(u16x8*)&Vl[s][r][q * 8] = *(const u16x8*)(src + vbase + (size_t)r * NP_ + k0 + q * 8);
        }
        __syncthreads();
        bf16x8 a0[2], a1[2], a2[2];
#pragma unroll
        for (int m = 0; m < 2; ++m){
            a0[m] = __builtin_bit_cast(bf16x8, *(const u16x8*)&Al[0][m*16 + arow][kg0]);
            a1[m] = __builtin_bit_cast(bf16x8, *(const u16x8*)&Al[1][m*16 + arow][kg0]);
            a2[m] = __builtin_bit_cast(bf16x8, *(const u16x8*)&Al[2][m*16 + arow][kg0]);
        }
        bf16x8 b0 = __builtin_bit_cast(bf16x8, *(const u16x8*)&Vl[0][w*16 + arow][kg0]);
        bf16x8 b1 = __builtin_bit_cast(bf16x8, *(const u16x8*)&Vl[1][w*16 + arow][kg0]);
        bf16x8 b2 = __builtin_bit_cast(bf16x8, *(const u16x8*)&Vl[2][w*16 + arow][kg0]);
#pragma unroll
        for (int m = 0; m < 2; ++m){
            acc[m] = __builtin_amdgcn_mfma_f32_16x16x32_bf16(a2[m], b0, acc[m], 0, 0, 0);
            acc[m] = __builtin_amdgcn_mfma_f32_16x16x32_bf16(a1[m], b1, acc[m], 0, 0, 0);
            acc[m] = __builtin_amdgcn_mfma_f32_16x16x32_bf16(a0[m], b2, acc[m], 0, 0, 0);
            acc[m] = __builtin_amdgcn_mfma_f32_16x16x32_bf16(a1[m], b0, acc[m], 0, 0, 0);
            acc[m] = __builtin_amdgcn_mfma_f32_16x16x32_bf16(a0[m], b1, acc[m], 0, 0, 0);
            acc[m] = __builtin_amdgcn_mfma_f32_16x16x32_bf16(a0[m], b0, acc[m], 0, 0, 0);
        }
    }
#pragma unroll
    for (int m = 0; m < 2; ++m)
#pragma unroll
        for (int r = 0; r < 4; ++r){
            int i = i0 + m * 16 + r4 + r;
            if (i < N_)
                Y[((size_t)b * N_ + i) * D_ + h * HD_ + w * 16 + c16] = acc[m][r];
        }
}

// ---------------- final pooling ----------------

__global__ __launch_bounds__(256)
void rowdot_kernel(const float* __restrict__ xf, const float* __restrict__ pw,
                   const float* __restrict__ pb, float* __restrict__ sraw){
    int row = blockIdx.x, tid = threadIdx.x;
    const float* base = xf + (size_t)row * D_;
    float s = base[tid] * pw[tid] + base[tid + 256] * pw[tid + 256] + base[tid + 512] * pw[tid + 512];
    __shared__ float red[4];
    for (int o = 32; o > 0; o >>= 1) s += __shfl_xor(s, o);
    if ((tid & 63) == 0) red[tid >> 6] = s;
    __syncthreads();
    if (tid == 0) sraw[row] = red[0] + red[1] + red[2] + red[3] + pb[0];
}

__global__ __launch_bounds__(256)
void softmax196_kernel(const float* __restrict__ sraw, float* __restrict__ aw){
    int b = blockIdx.x, tid = threadIdx.x;
    __shared__ float red[8];
    float v = (tid < N_) ? sraw[b * N_ + tid] : -3.0e38f;
    float m = v;
    for (int o = 32; o > 0; o >>= 1) m = fmaxf(m, __shfl_xor(m, o));
    if ((tid & 63) == 0) red[tid >> 6] = m;
    __syncthreads();
    float M = fmaxf(fmaxf(red[0], red[1]), fmaxf(red[2], red[3]));
    float e = (tid < N_) ? expf(v - M) : 0.f;
    float s = e;
    for (int o = 32; o > 0; o >>= 1) s += __shfl_xor(s, o);
    if ((tid & 63) == 0) red[4 + (tid >> 6)] = s;
    __syncthreads();
    float S = red[4] + red[5] + red[6] + red[7];
    if (tid < N_) aw[b * N_ + tid] = e / S;
}

__global__ __launch_bounds__(256)
void poolmat_kernel(const float* __restrict__ aw, const float* __restrict__ xf,
                    float* __restrict__ pooled){
    int b = blockIdx.y;
    int d = blockIdx.x * 256 + threadIdx.x;
    float acc = 0.f;
    for (int n = 0; n < N_; ++n)
        acc += aw[b * N_ + n] * xf[((size_t)b * N_ + n) * D_ + d];
    pooled[b * D_ + d] = acc;
}

__global__ __launch_bounds__(256)
void fc_kernel(const float* __restrict__ pooled, const float* __restrict__ fw,
               const float* __restrict__ fb, float* __restrict__ out){
    int b = blockIdx.y;
    int c = blockIdx.x * 256 + threadIdx.x;
    if (c >= CLS_) return;
    float acc = fb[c];
    for (int d = 0; d < D_; ++d)
        acc += pooled[b * D_ + d] * fw[(size_t)d * CLS_ + c];
    out[b * CLS_ + c] = acc;
}

__global__ __launch_bounds__(256)
void zero_logits(float* __restrict__ out){
    out[blockIdx.x * 256 + threadIdx.x] = 0.f;
}

// ---------------- launcher ----------------

extern "C" void kernel_launch(void* const* d_in, const int* in_sizes, int n_in,
                              void* d_out, int out_size, void* d_ws, size_t ws_size,
                              hipStream_t stream){
    const float* x        = (const float*)d_in[0];
    const float* pos_emb  = (const float*)d_in[1];
    const float* qkv_w    = (const float*)d_in[2];
    const float* qkv_b    = (const float*)d_in[3];
    const float* proj_w   = (const float*)d_in[4];
    const float* proj_b   = (const float*)d_in[5];
    const float* lin1_w   = (const float*)d_in[6];
    const float* lin1_b   = (const float*)d_in[7];
    const float* lin2_w   = (const float*)d_in[8];
    const float* lin2_b   = (const float*)d_in[9];
    const float* pre_ln_w = (const float*)d_in[10];
    const float* pre_ln_b = (const float*)d_in[11];
    const float* norm1_w  = (const float*)d_in[12];
    const float* norm1_b  = (const float*)d_in[13];
    const float* attn_ln_w= (const float*)d_in[14];
    const float* attn_ln_b= (const float*)d_in[15];
    const float* fln_w    = (const float*)d_in[16];
    const float* fln_b    = (const float*)d_in[17];
    const float* pool_w   = (const float*)d_in[18];
    const float* pool_b   = (const float*)d_in[19];
    const float* fc_w     = (const float*)d_in[20];
    const float* fc_b     = (const float*)d_in[21];

    float* dout = (float*)d_out;
    float* S = dout + (size_t)B_ * CLS_;   // attn region (B,H,196,196) f32

    char* ws = (char*)d_ws;
    size_t off = 0;
    auto alloc = [&](size_t bytes)->char*{
        char* p = ws + off;
        off += (bytes + 255) & ~(size_t)255;
        return p;
    };
    float* SRC   = (float*)alloc((size_t)NTOK_ * D_ * 4);
    float* Yb    = (float*)alloc((size_t)NTOK_ * D_ * 4);
    float* TMP   = (float*)alloc((size_t)NTOK_ * D_ * 4);
    float* QKV   = (float*)alloc((size_t)NTOK_ * 3 * D_ * 4);
    u16*   A0    = (u16*)  alloc((size_t)NTOK_ * D_ * 2);
    u16*   A1    = (u16*)  alloc((size_t)NTOK_ * D_ * 2);
    u16*   W0    = (u16*)  alloc((size_t)FF_ * D_ * 2);
    u16*   W1    = (u16*)  alloc((size_t)FF_ * D_ * 2);
    u16*   F0    = (u16*)  alloc((size_t)NTOK_ * FF_ * 2);   // aliases attn AS0
    u16*   F1    = (u16*)  alloc((size_t)NTOK_ * FF_ * 2);   // aliases attn AS1
    u16*   F2    = (u16*)  alloc((size_t)NTOK_ * FF_ * 2);   // attn AS2 only
    u16*   Q0b   = (u16*)  alloc((size_t)BH_ * NP_ * HD_ * 2);
    u16*   Q1b   = (u16*)  alloc((size_t)BH_ * NP_ * HD_ * 2);
    u16*   Q2b   = (u16*)  alloc((size_t)BH_ * NP_ * HD_ * 2);
    u16*   K0b   = (u16*)  alloc((size_t)BH_ * NP_ * HD_ * 2);
    u16*   K1b   = (u16*)  alloc((size_t)BH_ * NP_ * HD_ * 2);
    u16*   K2b   = (u16*)  alloc((size_t)BH_ * NP_ * HD_ * 2);
    u16*   VT0   = (u16*)  alloc((size_t)BH_ * HD_ * NP_ * 2);
    u16*   VT1   = (u16*)  alloc((size_t)BH_ * HD_ * NP_ * 2);
    u16*   VT2   = (u16*)  alloc((size_t)BH_ * HD_ * NP_ * 2);
    double* P1   = (double*)alloc((size_t)B_ * 64 * 8);
    double* P2   = (double*)alloc((size_t)B_ * 64 * 8);
    double* MU   = (double*)alloc((size_t)B_ * 8);
    float2* MUSIG= (float2*)alloc((size_t)B_ * 8);
    float* SRAW  = (float*)alloc((size_t)NTOK_ * 4);
    float* AW    = (float*)alloc((size_t)NTOK_ * 4);
    float* POOLED= (float*)alloc((size_t)B_ * D_ * 4);
    u16* AS0 = F0, *AS1 = F1, *AS2 = F2;   // NTOK*FF == BH*NP*NP exactly

    if (ws_size < off){
        zero_logits<<<(B_ * CLS_) / 256, 256, 0, stream>>>(dout);
        return;
    }

    const int cvt_blocks = NTOK_ * D_ / (256 * 4);  // 4704
    const int an_blocks = (int)((size_t)BH_ * NP_ * NP_ / (256 * 4));  // 18816

    addpos_kernel<<<cvt_blocks, 256, 0, stream>>>(x, pos_emb, SRC);

    for (int l = 0; l < L_; ++l){
        const float* qw  = qkv_w  + (size_t)l * D_ * 3 * D_;
        const float* qb  = qkv_b  + (size_t)l * 3 * D_;
        const float* pw  = proj_w + (size_t)l * D_ * D_;
        const float* pb  = proj_b + (size_t)l * D_;
        const float* l1w = lin1_w + (size_t)l * D_ * FF_;
        const float* l1b = lin1_b + (size_t)l * FF_;
        const float* l2w = lin2_w + (size_t)l * FF_ * D_;
        const float* l2b = lin2_b + (size_t)l * D_;
        const float* prw = pre_ln_w + (size_t)l * D_;
        const float* prb = pre_ln_b + (size_t)l * D_;
        const float* n1w = norm1_w + (size_t)l * D_;
        const float* n1b = norm1_b + (size_t)l * D_;
        const float* awl = attn_ln_w + (size_t)l * H_ * N_ * N_;
        const float* abl = attn_ln_b + (size_t)l * H_ * N_ * N_;

        // pre-LN -> fp16 split-2 A operand
        ln_row<<<NTOK_, 256, 0, stream>>>(SRC, prw, prb, nullptr, A0, A1);
        // qkv
        wtrans_kernel<<<dim3(3 * D_ / 32, D_ / 32), 256, 0, stream>>>(qw, W0, W1, D_, 3 * D_);
        gemm_f16s2<0><<<dim3(3 * D_ / 128, NTOK_ / 128), 256, 0, stream>>>(
            A0, A1, W0, W1, qb, nullptr, QKV, nullptr, nullptr, NTOK_, 3 * D_, D_);
        // q/k normalize+square -> bf16 split3 (padded), V^T split3
        qkprep_kernel<<<BH_, 256, 0, stream>>>(QKV, Q0b, Q1b, Q2b, K0b, K1b, K2b,
                                               VT0, VT1, VT2);
        // scores via split-3 MFMA (6-term)
        score_mfma3<<<dim3(7, BH_), 256, 0, stream>>>(Q0b, Q1b, Q2b, K0b, K1b, K2b, S);
        // batch LN over (H,N,N): two-pass double stats
        statsA_kernel<<<dim3(64, B_), 256, 0, stream>>>(S, P1);
        reduceMu_kernel<<<B_, 64, 0, stream>>>(P1, MU);
        statsB_kernel<<<dim3(64, B_), 256, 0, stream>>>(S, MU, P2);
        reduceR_kernel<<<B_, 64, 0, stream>>>(P2, MU, MUSIG);
        attnnorm_pad<<<an_blocks, 256, 0, stream>>>(S, awl, abl, MUSIG, AS0, AS1, AS2);
        // attn @ V via split-3 MFMA -> Yb (B,N,D)
        pv_mfma3<<<dim3(7, BH_), 256, 0, stream>>>(AS0, AS1, AS2, VT0, VT1, VT2, Yb);
        // proj + residual
        cvt_split2h<<<cvt_blocks, 256, 0, stream>>>(Yb, A0, A1);
        wtrans_kernel<<<dim3(D_ / 32, D_ / 32), 256, 0, stream>>>(pw, W0, W1, D_, D_);
        gemm_f16s2<2><<<dim3(D_ / 128, NTOK_ / 128), 256, 0, stream>>>(
            A0, A1, W0, W1, pb, SRC, TMP, nullptr, nullptr, NTOK_, D_, D_);
        // norm1 -> SRC f32 + fp16 split2
        ln_row<<<NTOK_, 256, 0, stream>>>(TMP, n1w, n1b, SRC, A0, A1);
        // MLP
        wtrans_kernel<<<dim3(FF_ / 32, D_ / 32), 256, 0, stream>>>(l1w, W0, W1, D_, FF_);
        gemm_f16s2<1><<<dim3(FF_ / 128, NTOK_ / 128), 256, 0, stream>>>(
            A0, A1, W0, W1, l1b, nullptr, nullptr, F0, F1, NTOK_, FF_, D_);
        wtrans_kernel<<<dim3(D_ / 32, FF_ / 32), 256, 0, stream>>>(l2w, W0, W1, FF_, D_);
        gemm_f16s2<2><<<dim3(D_ / 128, NTOK_ / 128), 256, 0, stream>>>(
            F0, F1, W0, W1, l2b, SRC, SRC, nullptr, nullptr, NTOK_, D_, FF_);
    }

    // final LN -> Yb (xf)
    ln_row<<<NTOK_, 256, 0, stream>>>(SRC, fln_w, fln_b, Yb, nullptr, nullptr);
    // sequence pooling
    rowdot_kernel<<<NTOK_, 256, 0, stream>>>(Yb, pool_w, pool_b, SRAW);
    softmax196_kernel<<<B_, 256, 0, stream>>>(SRAW, AW);
    poolmat_kernel<<<dim3(D_ / 256, B_), 256, 0, stream>>>(AW, Yb, POOLED);
    fc_kernel<<<dim3((CLS_ + 255) / 256, B_), 256, 0, stream>>>(POOLED, fc_w, fc_b, dout);
}

// Round 11
// 9390.977 us; speedup vs baseline: 2.3340x; 1.0328x over previous
//
#include <hip/hip_runtime.h>
#include <hip/hip_bf16.h>

typedef unsigned short u16;
typedef __bf16 bf16x8 __attribute__((ext_vector_type(8)));
typedef _Float16 f16x8 __attribute__((ext_vector_type(8)));
typedef float f32x4 __attribute__((ext_vector_type(4)));
typedef u16 u16x8 __attribute__((ext_vector_type(8)));
typedef u16 u16x4 __attribute__((ext_vector_type(4)));

#define B_ 32
#define N_ 196
#define D_ 768
#define H_ 12
#define L_ 12
#define FF_ 3072
#define CLS_ 1000
#define HD_ 64
#define BH_ 384
#define NTOK_ 6272
#define NP_ 224
#define ATTN_PER_B_ 460992   /* H*N*N */
#define NN_ 38416            /* N*N */

__device__ inline u16 f2bf(float f){
    __bf16 h = (__bf16)f;
    return __builtin_bit_cast(u16, h);
}
__device__ inline float bf2f(u16 u){
    __bf16 h = __builtin_bit_cast(__bf16, u);
    return (float)h;
}
// bf16 3-way split: v ~= s0+s1+s2, rep error ~2^-27
__device__ inline void split3(float v, u16& s0, u16& s1, u16& s2){
    s0 = f2bf(v);
    float r = v - bf2f(s0);
    s1 = f2bf(r);
    r = r - bf2f(s1);
    s2 = f2bf(r);
}
__device__ inline u16 f2h(float f){
    _Float16 h = (_Float16)f;
    return __builtin_bit_cast(u16, h);
}
__device__ inline float h2f(u16 u){
    _Float16 h = __builtin_bit_cast(_Float16, u);
    return (float)h;
}
// fp16 2-way split: v ~= h0+h1, rep error ~2^-23
__device__ inline void split2h(float v, u16& h0, u16& h1){
    h0 = f2h(v);
    h1 = f2h(v - h2f(h0));
}

// ---------------- elementwise / conversion ----------------

__global__ __launch_bounds__(256)
void addpos_kernel(const float* __restrict__ x, const float* __restrict__ pos,
                   float* __restrict__ src){
    size_t gid = (size_t)blockIdx.x * 256 + threadIdx.x;
    size_t e = gid * 4;
    size_t tok = e / D_;
    size_t d = e % D_;
    size_t pe = (tok % N_) * D_ + d;
    float4 a = *(const float4*)(x + e);
    float4 p = *(const float4*)(pos + pe);
    float4 o = make_float4(a.x + p.x, a.y + p.y, a.z + p.z, a.w + p.w);
    *(float4*)(src + e) = o;
}

// f32 -> fp16 split-2
__global__ __launch_bounds__(256)
void cvt_split2h(const float* __restrict__ in, u16* __restrict__ o0,
                 u16* __restrict__ o1){
    size_t e = ((size_t)blockIdx.x * 256 + threadIdx.x) * 4;
    float4 v = *(const float4*)(in + e);
    u16x4 p0, p1;
    float vv[4] = {v.x, v.y, v.z, v.w};
#pragma unroll
    for (int t = 0; t < 4; ++t){
        u16 a, b;
        split2h(vv[t], a, b);
        p0[t] = a; p1[t] = b;
    }
    *(u16x4*)(o0 + e) = p0;
    *(u16x4*)(o1 + e) = p1;
}

// weight transpose + fp16 split-2: in (K, Nn) f32 -> out (Nn, K)
__global__ __launch_bounds__(256)
void wtrans_kernel(const float* __restrict__ in, u16* __restrict__ o0,
                   u16* __restrict__ o1, int K, int Nn){
    __shared__ float t[32][33];
    int n0 = blockIdx.x * 32, k0 = blockIdx.y * 32;
    int tx = threadIdx.x & 31, ty = threadIdx.x >> 5;   // ty in [0,8)
#pragma unroll
    for (int r = 0; r < 4; ++r)
        t[ty + 8*r][tx] = in[(size_t)(k0 + ty + 8*r) * Nn + n0 + tx];
    __syncthreads();
#pragma unroll
    for (int r = 0; r < 4; ++r){
        float v = t[tx][ty + 8*r];
        size_t oi = (size_t)(n0 + ty + 8*r) * K + k0 + tx;
        u16 a, b;
        split2h(v, a, b);
        o0[oi] = a; o1[oi] = b;
    }
}

// ---------------- row LayerNorm (768 cols), optional fp16 split-2 out ----------------

__global__ __launch_bounds__(256)
void ln_row(const float* __restrict__ in, const float* __restrict__ w,
            const float* __restrict__ bb, float* __restrict__ outF,
            u16* __restrict__ o0, u16* __restrict__ o1){
    int row = blockIdx.x, tid = threadIdx.x;
    const float* base = in + (size_t)row * D_;
    float x0 = base[tid], x1 = base[tid + 256], x2 = base[tid + 512];
    float s = x0 + x1 + x2;
    float q = x0*x0 + x1*x1 + x2*x2;
    __shared__ float red[8];
    for (int o = 32; o > 0; o >>= 1){ s += __shfl_down(s, o); q += __shfl_down(q, o); }
    if ((tid & 63) == 0){ red[tid >> 6] = s; red[4 + (tid >> 6)] = q; }
    __syncthreads();
    s = red[0] + red[1] + red[2] + red[3];
    q = red[4] + red[5] + red[6] + red[7];
    float mu = s * (1.f / D_);
    float rv = rsqrtf(q * (1.f / D_) - mu * mu + 1e-5f);
#pragma unroll
    for (int t = 0; t < 3; ++t){
        int c = tid + t * 256;
        float x = (t == 0 ? x0 : (t == 1 ? x1 : x2));
        float val = (x - mu) * rv * w[c] + bb[c];
        size_t oi = (size_t)row * D_ + c;
        if (outF) outF[oi] = val;
        if (o0){
            u16 a, b;
            split2h(val, a, b);
            o0[oi] = a; o1[oi] = b;
        }
    }
}

// ---------------- fp16 split-2 GEMM with global_load_lds staging ----------------
// C = (A0+A1)(B0+B1)^T, 4-term exact.
// LDS: 4 linear buffers [128 rows][32 u16], XOR chunk swizzle q' = q ^ ((row>>1)&3)
// applied on the per-lane global SOURCE address and on ds_read (rule: both sides).
// EPI 0: outF = acc + bias
// EPI 1: split2h out = gelu(acc + bias)
// EPI 2: outF = acc + bias + res

template<int EPI>
__global__ __launch_bounds__(256)
void gemm_f16s2(const u16* __restrict__ A0, const u16* __restrict__ A1,
                const u16* __restrict__ B0, const u16* __restrict__ B1,
                const float* __restrict__ bias, const float* __restrict__ res,
                float* __restrict__ outF, u16* __restrict__ oH,
                u16* __restrict__ oL, int M, int Nn, int K){
    __shared__ u16 LA0[128 * 32];
    __shared__ u16 LA1[128 * 32];
    __shared__ u16 LB0[128 * 32];
    __shared__ u16 LB1[128 * 32];
    const int tid = threadIdx.x;
    const int w = tid >> 6, l = tid & 63;
    const int wr = w >> 1, wc = w & 1;
    const int m0 = blockIdx.y * 128, n0 = blockIdx.x * 128;
    // staging: wave w owns one buffer; 8 x global_load_lds(16B) per K-step.
    u16* lbuf = (w == 0 ? LA0 : w == 1 ? LA1 : w == 2 ? LB0 : LB1);
    const u16* gsrc = (w == 0 ? A0 : w == 1 ? A1 : w == 2 ? B0 : B1);
    const int rowbase = (w < 2 ? m0 : n0);
    const int lq = (l & 3) ^ ((l >> 3) & 3);     // swizzled logical 16B-chunk
    const u16* gp = gsrc + (size_t)(rowbase + (l >> 2)) * K + lq * 8;
    const size_t gstep = (size_t)16 * K;
    f32x4 acc[4][4] = {};
    const int arow = l & 15;
    const int qsel = l >> 4;
    for (int k0 = 0; k0 < K; k0 += 32){
        __syncthreads();
        {
            const u16* gpk = gp + k0;
#pragma unroll
            for (int i = 0; i < 8; ++i){
                __builtin_amdgcn_global_load_lds(
                    (const __attribute__((address_space(1))) unsigned int*)gpk,
                    (__attribute__((address_space(3))) unsigned int*)(lbuf + i * 512),
                    16, 0, 0);
                gpk += gstep;
            }
        }
        __syncthreads();
        f16x8 a0[4], a1[4], b0[4], b1[4];
#pragma unroll
        for (int m = 0; m < 4; ++m){
            int row = wr * 64 + m * 16 + arow;
            int off = row * 32 + ((qsel ^ ((row >> 1) & 3)) * 8);
            a0[m] = __builtin_bit_cast(f16x8, *(const u16x8*)&LA0[off]);
            a1[m] = __builtin_bit_cast(f16x8, *(const u16x8*)&LA1[off]);
        }
#pragma unroll
        for (int n = 0; n < 4; ++n){
            int row = wc * 64 + n * 16 + arow;
            int off = row * 32 + ((qsel ^ ((row >> 1) & 3)) * 8);
            b0[n] = __builtin_bit_cast(f16x8, *(const u16x8*)&LB0[off]);
            b1[n] = __builtin_bit_cast(f16x8, *(const u16x8*)&LB1[off]);
        }
        // accumulate smallest-order terms first
#pragma unroll
        for (int m = 0; m < 4; ++m)
#pragma unroll
            for (int n = 0; n < 4; ++n){
                acc[m][n] = __builtin_amdgcn_mfma_f32_16x16x32_f16(a1[m], b1[n], acc[m][n], 0, 0, 0);
                acc[m][n] = __builtin_amdgcn_mfma_f32_16x16x32_f16(a1[m], b0[n], acc[m][n], 0, 0, 0);
                acc[m][n] = __builtin_amdgcn_mfma_f32_16x16x32_f16(a0[m], b1[n], acc[m][n], 0, 0, 0);
                acc[m][n] = __builtin_amdgcn_mfma_f32_16x16x32_f16(a0[m], b0[n], acc[m][n], 0, 0, 0);
            }
    }
    const int r4 = (l >> 4) * 4, c16 = l & 15;
#pragma unroll
    for (int m = 0; m < 4; ++m){
#pragma unroll
        for (int n = 0; n < 4; ++n){
            int colg = n0 + wc*64 + n*16 + c16;
            float bv = bias[colg];
#pragma unroll
            for (int r = 0; r < 4; ++r){
                int rowg = m0 + wr*64 + m*16 + r4 + r;
                size_t oi = (size_t)rowg * Nn + colg;
                float v = acc[m][n][r] + bv;
                if (EPI == 0){
                    outF[oi] = v;
                } else if (EPI == 1){
                    v = 0.5f * v * (1.0f + erff(v * 0.70710678118654752f));
                    u16 a, b;
                    split2h(v, a, b);
                    oH[oi] = a; oL[oi] = b;
                } else {
                    outF[oi] = v + res[oi];
                }
            }
        }
    }
}

// ---------------- q/k normalize+square -> bf16 split-3 (padded), V^T split-3 ----------------

__global__ __launch_bounds__(256)
void qkprep_kernel(const float* __restrict__ QKV,
                   u16* __restrict__ Q0, u16* __restrict__ Q1, u16* __restrict__ Q2,
                   u16* __restrict__ K0, u16* __restrict__ K1, u16* __restrict__ K2,
                   u16* __restrict__ VT0, u16* __restrict__ VT1, u16* __restrict__ VT2){
    __shared__ float vbuf[NP_][65];
    int bh = blockIdx.x;
    int b = bh / H_, h = bh % H_;
    int w = threadIdx.x >> 6, l = threadIdx.x & 63;
    size_t base = (size_t)bh * (NP_ * HD_);
    for (int n = w; n < NP_; n += 4){
        size_t oi = base + (size_t)n * HD_ + l;
        if (n < N_){
            const float* row = QKV + (size_t)(b * N_ + n) * (3 * D_) + h * HD_;
            float qv = row[l], kv = row[D_ + l], vv = row[2 * D_ + l];
            double qs = (double)qv * (double)qv, ks = (double)kv * (double)kv;
            double qr = qs, kr = ks;
            for (int o = 32; o > 0; o >>= 1){ qr += __shfl_xor(qr, o); kr += __shfl_xor(kr, o); }
            float q2 = (float)(qs / qr), k2 = (float)(ks / kr);
            u16 a, bb, c;
            split3(q2, a, bb, c);
            Q0[oi] = a; Q1[oi] = bb; Q2[oi] = c;
            split3(k2, a, bb, c);
            K0[oi] = a; K1[oi] = bb; K2[oi] = c;
            vbuf[n][l] = vv;
        } else {
            Q0[oi] = 0; Q1[oi] = 0; Q2[oi] = 0;
            K0[oi] = 0; K1[oi] = 0; K2[oi] = 0;
            vbuf[n][l] = 0.f;
        }
    }
    __syncthreads();
    size_t vtb = (size_t)bh * (HD_ * NP_);
    for (int idx = threadIdx.x; idx < HD_ * NP_; idx += 256){
        int d = idx / NP_, n = idx % NP_;
        u16 a, bb, c;
        split3(vbuf[n][d], a, bb, c);
        VT0[vtb + idx] = a; VT1[vtb + idx] = bb; VT2[vtb + idx] = c;
    }
}

// ---------------- score via bf16 split-3 MFMA (6-term): S = Q2 @ K2^T ----------------

#define SPAD 72

__global__ __launch_bounds__(256)
void score_mfma3(const u16* __restrict__ Q0, const u16* __restrict__ Q1,
                 const u16* __restrict__ Q2,
                 const u16* __restrict__ K0, const u16* __restrict__ K1,
                 const u16* __restrict__ K2,
                 float* __restrict__ S){
    __shared__ u16 Ql[3][32][SPAD];
    __shared__ u16 Kl[3][32][SPAD];
    int i0 = blockIdx.x * 32;
    int bh = blockIdx.y;
    int tid = threadIdx.x;
    size_t base = (size_t)bh * (NP_ * HD_);
    {
        int r = tid >> 3, q = tid & 7;
        size_t src = base + (size_t)(i0 + r) * HD_ + q * 8;
        *(u16x8*)&Ql[0][r][q * 8] = *(const u16x8*)(Q0 + src);
        *(u16x8*)&Ql[1][r][q * 8] = *(const u16x8*)(Q1 + src);
        *(u16x8*)&Ql[2][r][q * 8] = *(const u16x8*)(Q2 + src);
    }
    const int w = tid >> 6, l = tid & 63;
    const int wm = w >> 1, wn = w & 1;
    const int arow = l & 15, kg0 = (l >> 4) * 8;
    const int r4 = (l >> 4) * 4, c16 = l & 15;
    for (int jt = 0; jt < 7; ++jt){
        __syncthreads();
        {
            int r = tid >> 3, q = tid & 7;
            size_t src = base + (size_t)(jt * 32 + r) * HD_ + q * 8;
            *(u16x8*)&Kl[0][r][q * 8] = *(const u16x8*)(K0 + src);
            *(u16x8*)&Kl[1][r][q * 8] = *(const u16x8*)(K1 + src);
            *(u16x8*)&Kl[2][r][q * 8] = *(const u16x8*)(K2 + src);
        }
        __syncthreads();
        f32x4 acc = {};
#pragma unroll
        for (int kk = 0; kk < 2; ++kk){
            int kg = kk * 32 + kg0;
            bf16x8 a0 = __builtin_bit_cast(bf16x8, *(const u16x8*)&Ql[0][wm*16 + arow][kg]);
            bf16x8 a1 = __builtin_bit_cast(bf16x8, *(const u16x8*)&Ql[1][wm*16 + arow][kg]);
            bf16x8 a2 = __builtin_bit_cast(bf16x8, *(const u16x8*)&Ql[2][wm*16 + arow][kg]);
            bf16x8 b0 = __builtin_bit_cast(bf16x8, *(const u16x8*)&Kl[0][wn*16 + arow][kg]);
            bf16x8 b1 = __builtin_bit_cast(bf16x8, *(const u16x8*)&Kl[1][wn*16 + arow][kg]);
            bf16x8 b2 = __builtin_bit_cast(bf16x8, *(const u16x8*)&Kl[2][wn*16 + arow][kg]);
            acc = __builtin_amdgcn_mfma_f32_16x16x32_bf16(a2, b0, acc, 0, 0, 0);
            acc = __builtin_amdgcn_mfma_f32_16x16x32_bf16(a1, b1, acc, 0, 0, 0);
            acc = __builtin_amdgcn_mfma_f32_16x16x32_bf16(a0, b2, acc, 0, 0, 0);
            acc = __builtin_amdgcn_mfma_f32_16x16x32_bf16(a1, b0, acc, 0, 0, 0);
            acc = __builtin_amdgcn_mfma_f32_16x16x32_bf16(a0, b1, acc, 0, 0, 0);
            acc = __builtin_amdgcn_mfma_f32_16x16x32_bf16(a0, b0, acc, 0, 0, 0);
        }
#pragma unroll
        for (int r = 0; r < 4; ++r){
            int i = i0 + wm * 16 + r4 + r;
            int j = jt * 32 + wn * 16 + c16;
            if (i < N_ && j < N_)
                S[((size_t)bh * N_ + i) * N_ + j] = acc[r];
        }
    }
}

// ---------------- batch-LN stats, two-pass, double ----------------

__global__ __launch_bounds__(256)
void statsA_kernel(const float* __restrict__ S, double* __restrict__ part1){
    int b = blockIdx.y, c = blockIdx.x;
    const float* base = S + (size_t)b * ATTN_PER_B_ + (size_t)c * 7203;
    double s = 0.0;
    for (int i = threadIdx.x; i < 7203; i += 256)
        s += (double)base[i];
    __shared__ double red[4];
    for (int o = 32; o > 0; o >>= 1) s += __shfl_down(s, o);
    if ((threadIdx.x & 63) == 0) red[threadIdx.x >> 6] = s;
    __syncthreads();
    if (threadIdx.x == 0) part1[b * 64 + c] = red[0] + red[1] + red[2] + red[3];
}

__global__ __launch_bounds__(64)
void reduceMu_kernel(const double* __restrict__ part1, double* __restrict__ MU){
    int b = blockIdx.x;
    double s = part1[b * 64 + threadIdx.x];
    for (int o = 32; o > 0; o >>= 1) s += __shfl_down(s, o);
    if (threadIdx.x == 0) MU[b] = s / (double)ATTN_PER_B_;
}

__global__ __launch_bounds__(256)
void statsB_kernel(const float* __restrict__ S, const double* __restrict__ MU,
                   double* __restrict__ part2){
    int b = blockIdx.y, c = blockIdx.x;
    double mu = MU[b];
    const float* base = S + (size_t)b * ATTN_PER_B_ + (size_t)c * 7203;
    double q = 0.0;
    for (int i = threadIdx.x; i < 7203; i += 256){
        double d = (double)base[i] - mu;
        q += d * d;
    }
    __shared__ double red[4];
    for (int o = 32; o > 0; o >>= 1) q += __shfl_down(q, o);
    if ((threadIdx.x & 63) == 0) red[threadIdx.x >> 6] = q;
    __syncthreads();
    if (threadIdx.x == 0) part2[b * 64 + c] = red[0] + red[1] + red[2] + red[3];
}

__global__ __launch_bounds__(64)
void reduceR_kernel(const double* __restrict__ part2, const double* __restrict__ MU,
                    float2* __restrict__ musig){
    int b = blockIdx.x;
    double q = part2[b * 64 + threadIdx.x];
    for (int o = 32; o > 0; o >>= 1) q += __shfl_down(q, o);
    if (threadIdx.x == 0){
        double var = q / (double)ATTN_PER_B_;
        musig[b] = make_float2((float)MU[b], (float)(1.0 / sqrt(var + 1e-5)));
    }
}

// ---------------- attn normalize: S in place + padded bf16 split-3 A operand ----------------

__global__ __launch_bounds__(256)
void attnnorm_pad(float* __restrict__ S, const float* __restrict__ wv,
                  const float* __restrict__ bv, const float2* __restrict__ musig,
                  u16* __restrict__ AS0, u16* __restrict__ AS1, u16* __restrict__ AS2){
    int gid = blockIdx.x * 256 + threadIdx.x;
    int jg = gid % 56;
    int rem = gid / 56;
    int i = rem % NP_;
    int bh = rem / NP_;
    int b = bh / H_, h = bh % H_;
    float2 ms = musig[b];
    u16x4 p0, p1, p2;
#pragma unroll
    for (int t = 0; t < 4; ++t){
        int j = jg * 4 + t;
        float val = 0.f;
        if (i < N_ && j < N_){
            size_t si = ((size_t)bh * N_ + i) * N_ + j;
            size_t wi = ((size_t)h * N_ + i) * N_ + j;
            float s = S[si];
            val = (s - ms.x) * ms.y * wv[wi] + bv[wi];
            S[si] = val;
        }
        u16 a, bb, c;
        split3(val, a, bb, c);
        p0[t] = a; p1[t] = bb; p2[t] = c;
    }
    size_t oo = (size_t)bh * (NP_ * NP_) + (size_t)i * NP_ + jg * 4;
    *(u16x4*)&AS0[oo] = p0;
    *(u16x4*)&AS1[oo] = p1;
    *(u16x4*)&AS2[oo] = p2;
}

// ---------------- PV via bf16 split-3 MFMA: Y = attn @ V ----------------

__global__ __launch_bounds__(256)
void pv_mfma3(const u16* __restrict__ AS0, const u16* __restrict__ AS1,
              const u16* __restrict__ AS2,
              const u16* __restrict__ VT0, const u16* __restrict__ VT1,
              const u16* __restrict__ VT2,
              float* __restrict__ Y){
    __shared__ u16 Al[3][32][40];
    __shared__ u16 Vl[3][64][40];
    int i0 = blockIdx.x * 32;
    int bh = blockIdx.y;
    int b = bh / H_, h = bh % H_;
    int tid = threadIdx.x;
    size_t abase = (size_t)bh * (NP_ * NP_) + (size_t)i0 * NP_;
    size_t vbase = (size_t)bh * (HD_ * NP_);
    const int w = tid >> 6, l = tid & 63;
    const int arow = l & 15, kg0 = (l >> 4) * 8;
    const int r4 = (l >> 4) * 4, c16 = l & 15;
    f32x4 acc[2] = {};
    for (int k0 = 0; k0 < NP_; k0 += 32){
        __syncthreads();
        for (int c = tid; c < 384; c += 256){
            int s = c >> 7, rem = c & 127;
            int r = rem >> 2, q = rem & 3;
            const u16* src = (s == 0 ? AS0 : (s == 1 ? AS1 : AS2));
            *(u16x8*)&Al[s][r][q * 8] = *(const u16x8*)(src + abase + (size_t)r * NP_ + k0 + q * 8);
        }
        for (int c = tid; c < 768; c += 256){
            int s = c >> 8, rem = c & 255;
            int r = rem >> 2, q = rem & 3;
            const u16* src = (s == 0 ? VT0 : (s == 1 ? VT1 : VT2));
            *(u16x8*)&Vl[s][r][q * 8] = *(const u16x8*)(src + vbase + (size_t)r * NP_ + k0 + q * 8);
        }
        __syncthreads();
        bf16x8 a0[2], a1[2], a2[2];
#pragma unroll
        for (int m = 0; m < 2; ++m){
            a0[m] = __builtin_bit_cast(bf16x8, *(const u16x8*)&Al[0][m*16 + arow][kg0]);
            a1[m] = __builtin_bit_cast(bf16x8, *(const u16x8*)&Al[1][m*16 + arow][kg0]);
            a2[m] = __builtin_bit_cast(bf16x8, *(const u16x8*)&Al[2][m*16 + arow][kg0]);
        }
        bf16x8 b0 = __builtin_bit_cast(bf16x8, *(const u16x8*)&Vl[0][w*16 + arow][kg0]);
        bf16x8 b1 = __builtin_bit_cast(bf16x8, *(const u16x8*)&Vl[1][w*16 + arow][kg0]);
        bf16x8 b2 = __builtin_bit_cast(bf16x8, *(const u16x8*)&Vl[2][w*16 + arow][kg0]);
#pragma unroll
        for (int m = 0; m < 2; ++m){
            acc[m] = __builtin_amdgcn_mfma_f32_16x16x32_bf16(a2[m], b0, acc[m], 0, 0, 0);
            acc[m] = __builtin_amdgcn_mfma_f32_16x16x32_bf16(a1[m], b1, acc[m], 0, 0, 0);
            acc[m] = __builtin_amdgcn_mfma_f32_16x16x32_bf16(a0[m], b2, acc[m], 0, 0, 0);
            acc[m] = __builtin_amdgcn_mfma_f32_16x16x32_bf16(a1[m], b0, acc[m], 0, 0, 0);
            acc[m] = __builtin_amdgcn_mfma_f32_16x16x32_bf16(a0[m], b1, acc[m], 0, 0, 0);
            acc[m] = __builtin_amdgcn_mfma_f32_16x16x32_bf16(a0[m], b0, acc[m], 0, 0, 0);
        }
    }
#pragma unroll
    for (int m = 0; m < 2; ++m)
#pragma unroll
        for (int r = 0; r < 4; ++r){
            int i = i0 + m * 16 + r4 + r;
            if (i < N_)
                Y[((size_t)b * N_ + i) * D_ + h * HD_ + w * 16 + c16] = acc[m][r];
        }
}

// ---------------- final pooling ----------------

__global__ __launch_bounds__(256)
void rowdot_kernel(const float* __restrict__ xf, const float* __restrict__ pw,
                   const float* __restrict__ pb, float* __restrict__ sraw){
    int row = blockIdx.x, tid = threadIdx.x;
    const float* base = xf + (size_t)row * D_;
    float s = base[tid] * pw[tid] + base[tid + 256] * pw[tid + 256] + base[tid + 512] * pw[tid + 512];
    __shared__ float red[4];
    for (int o = 32; o > 0; o >>= 1) s += __shfl_xor(s, o);
    if ((tid & 63) == 0) red[tid >> 6] = s;
    __syncthreads();
    if (tid == 0) sraw[row] = red[0] + red[1] + red[2] + red[3] + pb[0];
}

__global__ __launch_bounds__(256)
void softmax196_kernel(const float* __restrict__ sraw, float* __restrict__ aw){
    int b = blockIdx.x, tid = threadIdx.x;
    __shared__ float red[8];
    float v = (tid < N_) ? sraw[b * N_ + tid] : -3.0e38f;
    float m = v;
    for (int o = 32; o > 0; o >>= 1) m = fmaxf(m, __shfl_xor(m, o));
    if ((tid & 63) == 0) red[tid >> 6] = m;
    __syncthreads();
    float M = fmaxf(fmaxf(red[0], red[1]), fmaxf(red[2], red[3]));
    float e = (tid < N_) ? expf(v - M) : 0.f;
    float s = e;
    for (int o = 32; o > 0; o >>= 1) s += __shfl_xor(s, o);
    if ((tid & 63) == 0) red[4 + (tid >> 6)] = s;
    __syncthreads();
    float S = red[4] + red[5] + red[6] + red[7];
    if (tid < N_) aw[b * N_ + tid] = e / S;
}

__global__ __launch_bounds__(256)
void poolmat_kernel(const float* __restrict__ aw, const float* __restrict__ xf,
                    float* __restrict__ pooled){
    int b = blockIdx.y;
    int d = blockIdx.x * 256 + threadIdx.x;
    float acc = 0.f;
    for (int n = 0; n < N_; ++n)
        acc += aw[b * N_ + n] * xf[((size_t)b * N_ + n) * D_ + d];
    pooled[b * D_ + d] = acc;
}

__global__ __launch_bounds__(256)
void fc_kernel(const float* __restrict__ pooled, const float* __restrict__ fw,
               const float* __restrict__ fb, float* __restrict__ out){
    int b = blockIdx.y;
    int c = blockIdx.x * 256 + threadIdx.x;
    if (c >= CLS_) return;
    float acc = fb[c];
    for (int d = 0; d < D_; ++d)
        acc += pooled[b * D_ + d] * fw[(size_t)d * CLS_ + c];
    out[b * CLS_ + c] = acc;
}

__global__ __launch_bounds__(256)
void zero_logits(float* __restrict__ out){
    out[blockIdx.x * 256 + threadIdx.x] = 0.f;
}

// ---------------- launcher ----------------

extern "C" void kernel_launch(void* const* d_in, const int* in_sizes, int n_in,
                              void* d_out, int out_size, void* d_ws, size_t ws_size,
                              hipStream_t stream){
    const float* x        = (const float*)d_in[0];
    const float* pos_emb  = (const float*)d_in[1];
    const float* qkv_w    = (const float*)d_in[2];
    const float* qkv_b    = (const float*)d_in[3];
    const float* proj_w   = (const float*)d_in[4];
    const float* proj_b   = (const float*)d_in[5];
    const float* lin1_w   = (const float*)d_in[6];
    const float* lin1_b   = (const float*)d_in[7];
    const float* lin2_w   = (const float*)d_in[8];
    const float* lin2_b   = (const float*)d_in[9];
    const float* pre_ln_w = (const float*)d_in[10];
    const float* pre_ln_b = (const float*)d_in[11];
    const float* norm1_w  = (const float*)d_in[12];
    const float* norm1_b  = (const float*)d_in[13];
    const float* attn_ln_w= (const float*)d_in[14];
    const float* attn_ln_b= (const float*)d_in[15];
    const float* fln_w    = (const float*)d_in[16];
    const float* fln_b    = (const float*)d_in[17];
    const float* pool_w   = (const float*)d_in[18];
    const float* pool_b   = (const float*)d_in[19];
    const float* fc_w     = (const float*)d_in[20];
    const float* fc_b     = (const float*)d_in[21];

    float* dout = (float*)d_out;
    float* S = dout + (size_t)B_ * CLS_;   // attn region (B,H,196,196) f32

    char* ws = (char*)d_ws;
    size_t off = 0;
    auto alloc = [&](size_t bytes)->char*{
        char* p = ws + off;
        off += (bytes + 255) & ~(size_t)255;
        return p;
    };
    float* SRC   = (float*)alloc((size_t)NTOK_ * D_ * 4);
    float* Yb    = (float*)alloc((size_t)NTOK_ * D_ * 4);
    float* TMP   = (float*)alloc((size_t)NTOK_ * D_ * 4);
    float* QKV   = (float*)alloc((size_t)NTOK_ * 3 * D_ * 4);
    u16*   A0    = (u16*)  alloc((size_t)NTOK_ * D_ * 2);
    u16*   A1    = (u16*)  alloc((size_t)NTOK_ * D_ * 2);
    u16*   W0    = (u16*)  alloc((size_t)FF_ * D_ * 2);
    u16*   W1    = (u16*)  alloc((size_t)FF_ * D_ * 2);
    u16*   F0    = (u16*)  alloc((size_t)NTOK_ * FF_ * 2);   // aliases attn AS0
    u16*   F1    = (u16*)  alloc((size_t)NTOK_ * FF_ * 2);   // aliases attn AS1
    u16*   F2    = (u16*)  alloc((size_t)NTOK_ * FF_ * 2);   // attn AS2 only
    u16*   Q0b   = (u16*)  alloc((size_t)BH_ * NP_ * HD_ * 2);
    u16*   Q1b   = (u16*)  alloc((size_t)BH_ * NP_ * HD_ * 2);
    u16*   Q2b   = (u16*)  alloc((size_t)BH_ * NP_ * HD_ * 2);
    u16*   K0b   = (u16*)  alloc((size_t)BH_ * NP_ * HD_ * 2);
    u16*   K1b   = (u16*)  alloc((size_t)BH_ * NP_ * HD_ * 2);
    u16*   K2b   = (u16*)  alloc((size_t)BH_ * NP_ * HD_ * 2);
    u16*   VT0   = (u16*)  alloc((size_t)BH_ * HD_ * NP_ * 2);
    u16*   VT1   = (u16*)  alloc((size_t)BH_ * HD_ * NP_ * 2);
    u16*   VT2   = (u16*)  alloc((size_t)BH_ * HD_ * NP_ * 2);
    double* P1   = (double*)alloc((size_t)B_ * 64 * 8);
    double* P2   = (double*)alloc((size_t)B_ * 64 * 8);
    double* MU   = (double*)alloc((size_t)B_ * 8);
    float2* MUSIG= (float2*)alloc((size_t)B_ * 8);
    float* SRAW  = (float*)alloc((size_t)NTOK_ * 4);
    float* AW    = (float*)alloc((size_t)NTOK_ * 4);
    float* POOLED= (float*)alloc((size_t)B_ * D_ * 4);
    u16* AS0 = F0, *AS1 = F1, *AS2 = F2;   // NTOK*FF == BH*NP*NP exactly

    if (ws_size < off){
        zero_logits<<<(B_ * CLS_) / 256, 256, 0, stream>>>(dout);
        return;
    }

    const int cvt_blocks = NTOK_ * D_ / (256 * 4);  // 4704
    const int an_blocks = (int)((size_t)BH_ * NP_ * NP_ / (256 * 4));  // 18816

    addpos_kernel<<<cvt_blocks, 256, 0, stream>>>(x, pos_emb, SRC);

    for (int l = 0; l < L_; ++l){
        const float* qw  = qkv_w  + (size_t)l * D_ * 3 * D_;
        const float* qb  = qkv_b  + (size_t)l * 3 * D_;
        const float* pw  = proj_w + (size_t)l * D_ * D_;
        const float* pb  = proj_b + (size_t)l * D_;
        const float* l1w = lin1_w + (size_t)l * D_ * FF_;
        const float* l1b = lin1_b + (size_t)l * FF_;
        const float* l2w = lin2_w + (size_t)l * FF_ * D_;
        const float* l2b = lin2_b + (size_t)l * D_;
        const float* prw = pre_ln_w + (size_t)l * D_;
        const float* prb = pre_ln_b + (size_t)l * D_;
        const float* n1w = norm1_w + (size_t)l * D_;
        const float* n1b = norm1_b + (size_t)l * D_;
        const float* awl = attn_ln_w + (size_t)l * H_ * N_ * N_;
        const float* abl = attn_ln_b + (size_t)l * H_ * N_ * N_;

        // pre-LN -> fp16 split-2 A operand
        ln_row<<<NTOK_, 256, 0, stream>>>(SRC, prw, prb, nullptr, A0, A1);
        // qkv
        wtrans_kernel<<<dim3(3 * D_ / 32, D_ / 32), 256, 0, stream>>>(qw, W0, W1, D_, 3 * D_);
        gemm_f16s2<0><<<dim3(3 * D_ / 128, NTOK_ / 128), 256, 0, stream>>>(
            A0, A1, W0, W1, qb, nullptr, QKV, nullptr, nullptr, NTOK_, 3 * D_, D_);
        // q/k normalize+square -> bf16 split3 (padded), V^T split3
        qkprep_kernel<<<BH_, 256, 0, stream>>>(QKV, Q0b, Q1b, Q2b, K0b, K1b, K2b,
                                               VT0, VT1, VT2);
        // scores via split-3 MFMA (6-term)
        score_mfma3<<<dim3(7, BH_), 256, 0, stream>>>(Q0b, Q1b, Q2b, K0b, K1b, K2b, S);
        // batch LN over (H,N,N): two-pass double stats
        statsA_kernel<<<dim3(64, B_), 256, 0, stream>>>(S, P1);
        reduceMu_kernel<<<B_, 64, 0, stream>>>(P1, MU);
        statsB_kernel<<<dim3(64, B_), 256, 0, stream>>>(S, MU, P2);
        reduceR_kernel<<<B_, 64, 0, stream>>>(P2, MU, MUSIG);
        attnnorm_pad<<<an_blocks, 256, 0, stream>>>(S, awl, abl, MUSIG, AS0, AS1, AS2);
        // attn @ V via split-3 MFMA -> Yb (B,N,D)
        pv_mfma3<<<dim3(7, BH_), 256, 0, stream>>>(AS0, AS1, AS2, VT0, VT1, VT2, Yb);
        // proj + residual
        cvt_split2h<<<cvt_blocks, 256, 0, stream>>>(Yb, A0, A1);
        wtrans_kernel<<<dim3(D_ / 32, D_ / 32), 256, 0, stream>>>(pw, W0, W1, D_, D_);
        gemm_f16s2<2><<<dim3(D_ / 128, NTOK_ / 128), 256, 0, stream>>>(
            A0, A1, W0, W1, pb, SRC, TMP, nullptr, nullptr, NTOK_, D_, D_);
        // norm1 -> SRC f32 + fp16 split2
        ln_row<<<NTOK_, 256, 0, stream>>>(TMP, n1w, n1b, SRC, A0, A1);
        // MLP
        wtrans_kernel<<<dim3(FF_ / 32, D_ / 32), 256, 0, stream>>>(l1w, W0, W1, D_, FF_);
        gemm_f16s2<1><<<dim3(FF_ / 128, NTOK_ / 128), 256, 0, stream>>>(
            A0, A1, W0, W1, l1b, nullptr, nullptr, F0, F1, NTOK_, FF_, D_);
        wtrans_kernel<<<dim3(D_ / 32, FF_ / 32), 256, 0, stream>>>(l2w, W0, W1, FF_, D_);
        gemm_f16s2<2><<<dim3(D_ / 128, NTOK_ / 128), 256, 0, stream>>>(
            F0, F1, W0, W1, l2b, SRC, SRC, nullptr, nullptr, NTOK_, D_, FF_);
    }

    // final LN -> Yb (xf)
    ln_row<<<NTOK_, 256, 0, stream>>>(SRC, fln_w, fln_b, Yb, nullptr, nullptr);
    // sequence pooling
    rowdot_kernel<<<NTOK_, 256, 0, stream>>>(Yb, pool_w, pool_b, SRAW);
    softmax196_kernel<<<B_, 256, 0, stream>>>(SRAW, AW);
    poolmat_kernel<<<dim3(D_ / 256, B_), 256, 0, stream>>>(AW, Yb, POOLED);
    fc_kernel<<<dim3((CLS_ + 255) / 256, B_), 256, 0, stream>>>(POOLED, fc_w, fc_b, dout);
}

// Round 12
// 8773.029 us; speedup vs baseline: 2.4984x; 1.0704x over previous
//
#include <hip/hip_runtime.h>
#include <hip/hip_bf16.h>

typedef unsigned short u16;
typedef __bf16 bf16x8 __attribute__((ext_vector_type(8)));
typedef _Float16 f16x8 __attribute__((ext_vector_type(8)));
typedef float f32x4 __attribute__((ext_vector_type(4)));
typedef u16 u16x8 __attribute__((ext_vector_type(8)));
typedef u16 u16x4 __attribute__((ext_vector_type(4)));

#define B_ 32
#define N_ 196
#define D_ 768
#define H_ 12
#define L_ 12
#define FF_ 3072
#define CLS_ 1000
#define HD_ 64
#define BH_ 384
#define NTOK_ 6272
#define NP_ 224
#define ATTN_PER_B_ 460992   /* H*N*N */
#define NN_ 38416            /* N*N */

__device__ inline u16 f2bf(float f){
    __bf16 h = (__bf16)f;
    return __builtin_bit_cast(u16, h);
}
__device__ inline float bf2f(u16 u){
    __bf16 h = __builtin_bit_cast(__bf16, u);
    return (float)h;
}
// bf16 3-way split: v ~= s0+s1+s2, rep error ~2^-27
__device__ inline void split3(float v, u16& s0, u16& s1, u16& s2){
    s0 = f2bf(v);
    float r = v - bf2f(s0);
    s1 = f2bf(r);
    r = r - bf2f(s1);
    s2 = f2bf(r);
}
__device__ inline u16 f2h(float f){
    _Float16 h = (_Float16)f;
    return __builtin_bit_cast(u16, h);
}
__device__ inline float h2f(u16 u){
    _Float16 h = __builtin_bit_cast(_Float16, u);
    return (float)h;
}
// fp16 2-way split: v ~= h0+h1, rep error ~2^-23
__device__ inline void split2h(float v, u16& h0, u16& h1){
    h0 = f2h(v);
    h1 = f2h(v - h2f(h0));
}

// ---------------- elementwise / conversion ----------------

__global__ __launch_bounds__(256)
void addpos_kernel(const float* __restrict__ x, const float* __restrict__ pos,
                   float* __restrict__ src){
    size_t gid = (size_t)blockIdx.x * 256 + threadIdx.x;
    size_t e = gid * 4;
    size_t tok = e / D_;
    size_t d = e % D_;
    size_t pe = (tok % N_) * D_ + d;
    float4 a = *(const float4*)(x + e);
    float4 p = *(const float4*)(pos + pe);
    float4 o = make_float4(a.x + p.x, a.y + p.y, a.z + p.z, a.w + p.w);
    *(float4*)(src + e) = o;
}

// weight transpose + fp16 split-2: in (K, Nn) f32 -> out (Nn, K)
__global__ __launch_bounds__(256)
void wtrans_kernel(const float* __restrict__ in, u16* __restrict__ o0,
                   u16* __restrict__ o1, int K, int Nn){
    __shared__ float t[32][33];
    int n0 = blockIdx.x * 32, k0 = blockIdx.y * 32;
    int tx = threadIdx.x & 31, ty = threadIdx.x >> 5;   // ty in [0,8)
#pragma unroll
    for (int r = 0; r < 4; ++r)
        t[ty + 8*r][tx] = in[(size_t)(k0 + ty + 8*r) * Nn + n0 + tx];
    __syncthreads();
#pragma unroll
    for (int r = 0; r < 4; ++r){
        float v = t[tx][ty + 8*r];
        size_t oi = (size_t)(n0 + ty + 8*r) * K + k0 + tx;
        u16 a, b;
        split2h(v, a, b);
        o0[oi] = a; o1[oi] = b;
    }
}

// ---------------- row LayerNorm (768 cols), optional fp16 split-2 out ----------------

__global__ __launch_bounds__(256)
void ln_row(const float* __restrict__ in, const float* __restrict__ w,
            const float* __restrict__ bb, float* __restrict__ outF,
            u16* __restrict__ o0, u16* __restrict__ o1){
    int row = blockIdx.x, tid = threadIdx.x;
    const float* base = in + (size_t)row * D_;
    float x0 = base[tid], x1 = base[tid + 256], x2 = base[tid + 512];
    float s = x0 + x1 + x2;
    float q = x0*x0 + x1*x1 + x2*x2;
    __shared__ float red[8];
    for (int o = 32; o > 0; o >>= 1){ s += __shfl_down(s, o); q += __shfl_down(q, o); }
    if ((tid & 63) == 0){ red[tid >> 6] = s; red[4 + (tid >> 6)] = q; }
    __syncthreads();
    s = red[0] + red[1] + red[2] + red[3];
    q = red[4] + red[5] + red[6] + red[7];
    float mu = s * (1.f / D_);
    float rv = rsqrtf(q * (1.f / D_) - mu * mu + 1e-5f);
#pragma unroll
    for (int t = 0; t < 3; ++t){
        int c = tid + t * 256;
        float x = (t == 0 ? x0 : (t == 1 ? x1 : x2));
        float val = (x - mu) * rv * w[c] + bb[c];
        size_t oi = (size_t)row * D_ + c;
        if (outF) outF[oi] = val;
        if (o0){
            u16 a, b;
            split2h(val, a, b);
            o0[oi] = a; o1[oi] = b;
        }
    }
}

// ---------------- fp16 split-2 GEMM, 3-term, global_load_lds staging ----------------
// C = (A0+A1)(B0+B1)^T ~= A1B0 + A0B1 + A0B0 (dropped A1B1 ~ 2^-22 rel).
// XCD-bijective block swizzle on a flattened 1-D grid.
// EPI 0: outF = acc + bias
// EPI 1: split2h out = gelu(acc + bias)
// EPI 2: outF = acc + bias + res

template<int EPI>
__global__ __launch_bounds__(256)
void gemm_f16s2(const u16* __restrict__ A0, const u16* __restrict__ A1,
                const u16* __restrict__ B0, const u16* __restrict__ B1,
                const float* __restrict__ bias, const float* __restrict__ res,
                float* __restrict__ outF, u16* __restrict__ oH,
                u16* __restrict__ oL, int M, int Nn, int K){
    __shared__ u16 LA0[128 * 32];
    __shared__ u16 LA1[128 * 32];
    __shared__ u16 LB0[128 * 32];
    __shared__ u16 LB1[128 * 32];
    const int tid = threadIdx.x;
    const int w = tid >> 6, l = tid & 63;
    const int wr = w >> 1, wc = w & 1;
    // XCD-bijective swizzle (m204): consecutive remapped ids stay on one XCD
    const int nwg = gridDim.x;
    const int nbx = Nn >> 7;
    {
    }
    const int orig = blockIdx.x;
    const int qq = nwg >> 3, rr = nwg & 7;
    const int xcd = orig & 7, local = orig >> 3;
    const int wg = (xcd < rr ? xcd * (qq + 1) : rr * (qq + 1) + (xcd - rr) * qq) + local;
    const int m0 = (wg / nbx) * 128, n0 = (wg % nbx) * 128;
    // staging: wave w owns one buffer; 8 x global_load_lds(16B) per K-step.
    u16* lbuf = (w == 0 ? LA0 : w == 1 ? LA1 : w == 2 ? LB0 : LB1);
    const u16* gsrc = (w == 0 ? A0 : w == 1 ? A1 : w == 2 ? B0 : B1);
    const int rowbase = (w < 2 ? m0 : n0);
    const int lq = (l & 3) ^ ((l >> 3) & 3);     // swizzled logical 16B-chunk
    const u16* gp = gsrc + (size_t)(rowbase + (l >> 2)) * K + lq * 8;
    const size_t gstep = (size_t)16 * K;
    f32x4 acc[4][4] = {};
    const int arow = l & 15;
    const int qsel = l >> 4;
    for (int k0 = 0; k0 < K; k0 += 32){
        __syncthreads();
        {
            const u16* gpk = gp + k0;
#pragma unroll
            for (int i = 0; i < 8; ++i){
                __builtin_amdgcn_global_load_lds(
                    (const __attribute__((address_space(1))) unsigned int*)gpk,
                    (__attribute__((address_space(3))) unsigned int*)(lbuf + i * 512),
                    16, 0, 0);
                gpk += gstep;
            }
        }
        __syncthreads();
        f16x8 a0[4], a1[4], b0[4], b1[4];
#pragma unroll
        for (int m = 0; m < 4; ++m){
            int row = wr * 64 + m * 16 + arow;
            int off = row * 32 + ((qsel ^ ((row >> 1) & 3)) * 8);
            a0[m] = __builtin_bit_cast(f16x8, *(const u16x8*)&LA0[off]);
            a1[m] = __builtin_bit_cast(f16x8, *(const u16x8*)&LA1[off]);
        }
#pragma unroll
        for (int n = 0; n < 4; ++n){
            int row = wc * 64 + n * 16 + arow;
            int off = row * 32 + ((qsel ^ ((row >> 1) & 3)) * 8);
            b0[n] = __builtin_bit_cast(f16x8, *(const u16x8*)&LB0[off]);
            b1[n] = __builtin_bit_cast(f16x8, *(const u16x8*)&LB1[off]);
        }
        // 3-term, smallest-order first (A1B1 dropped: ~2^-22 relative)
#pragma unroll
        for (int m = 0; m < 4; ++m)
#pragma unroll
            for (int n = 0; n < 4; ++n){
                acc[m][n] = __builtin_amdgcn_mfma_f32_16x16x32_f16(a1[m], b0[n], acc[m][n], 0, 0, 0);
                acc[m][n] = __builtin_amdgcn_mfma_f32_16x16x32_f16(a0[m], b1[n], acc[m][n], 0, 0, 0);
                acc[m][n] = __builtin_amdgcn_mfma_f32_16x16x32_f16(a0[m], b0[n], acc[m][n], 0, 0, 0);
            }
    }
    const int r4 = (l >> 4) * 4, c16 = l & 15;
#pragma unroll
    for (int m = 0; m < 4; ++m){
#pragma unroll
        for (int n = 0; n < 4; ++n){
            int colg = n0 + wc*64 + n*16 + c16;
            float bv = bias[colg];
#pragma unroll
            for (int r = 0; r < 4; ++r){
                int rowg = m0 + wr*64 + m*16 + r4 + r;
                size_t oi = (size_t)rowg * Nn + colg;
                float v = acc[m][n][r] + bv;
                if (EPI == 0){
                    outF[oi] = v;
                } else if (EPI == 1){
                    v = 0.5f * v * (1.0f + erff(v * 0.70710678118654752f));
                    u16 a, b;
                    split2h(v, a, b);
                    oH[oi] = a; oL[oi] = b;
                } else {
                    outF[oi] = v + res[oi];
                }
            }
        }
    }
}

// ---------------- q/k normalize+square -> bf16 split-3 (padded), V^T split-3 ----------------

__global__ __launch_bounds__(256)
void qkprep_kernel(const float* __restrict__ QKV,
                   u16* __restrict__ Q0, u16* __restrict__ Q1, u16* __restrict__ Q2,
                   u16* __restrict__ K0, u16* __restrict__ K1, u16* __restrict__ K2,
                   u16* __restrict__ VT0, u16* __restrict__ VT1, u16* __restrict__ VT2){
    __shared__ float vbuf[NP_][65];
    int bh = blockIdx.x;
    int b = bh / H_, h = bh % H_;
    int w = threadIdx.x >> 6, l = threadIdx.x & 63;
    size_t base = (size_t)bh * (NP_ * HD_);
    for (int n = w; n < NP_; n += 4){
        size_t oi = base + (size_t)n * HD_ + l;
        if (n < N_){
            const float* row = QKV + (size_t)(b * N_ + n) * (3 * D_) + h * HD_;
            float qv = row[l], kv = row[D_ + l], vv = row[2 * D_ + l];
            double qs = (double)qv * (double)qv, ks = (double)kv * (double)kv;
            double qr = qs, kr = ks;
            for (int o = 32; o > 0; o >>= 1){ qr += __shfl_xor(qr, o); kr += __shfl_xor(kr, o); }
            float q2 = (float)(qs / qr), k2 = (float)(ks / kr);
            u16 a, bb, c;
            split3(q2, a, bb, c);
            Q0[oi] = a; Q1[oi] = bb; Q2[oi] = c;
            split3(k2, a, bb, c);
            K0[oi] = a; K1[oi] = bb; K2[oi] = c;
            vbuf[n][l] = vv;
        } else {
            Q0[oi] = 0; Q1[oi] = 0; Q2[oi] = 0;
            K0[oi] = 0; K1[oi] = 0; K2[oi] = 0;
            vbuf[n][l] = 0.f;
        }
    }
    __syncthreads();
    size_t vtb = (size_t)bh * (HD_ * NP_);
    for (int idx = threadIdx.x; idx < HD_ * NP_; idx += 256){
        int d = idx / NP_, n = idx % NP_;
        u16 a, bb, c;
        split3(vbuf[n][d], a, bb, c);
        VT0[vtb + idx] = a; VT1[vtb + idx] = bb; VT2[vtb + idx] = c;
    }
}

// ---------------- score via bf16 split-3 MFMA (6-term): S = Q2 @ K2^T ----------------

#define SPAD 72

__global__ __launch_bounds__(256)
void score_mfma3(const u16* __restrict__ Q0, const u16* __restrict__ Q1,
                 const u16* __restrict__ Q2,
                 const u16* __restrict__ K0, const u16* __restrict__ K1,
                 const u16* __restrict__ K2,
                 float* __restrict__ S){
    __shared__ u16 Ql[3][32][SPAD];
    __shared__ u16 Kl[3][32][SPAD];
    int i0 = blockIdx.x * 32;
    int bh = blockIdx.y;
    int tid = threadIdx.x;
    size_t base = (size_t)bh * (NP_ * HD_);
    {
        int r = tid >> 3, q = tid & 7;
        size_t src = base + (size_t)(i0 + r) * HD_ + q * 8;
        *(u16x8*)&Ql[0][r][q * 8] = *(const u16x8*)(Q0 + src);
        *(u16x8*)&Ql[1][r][q * 8] = *(const u16x8*)(Q1 + src);
        *(u16x8*)&Ql[2][r][q * 8] = *(const u16x8*)(Q2 + src);
    }
    const int w = tid >> 6, l = tid & 63;
    const int wm = w >> 1, wn = w & 1;
    const int arow = l & 15, kg0 = (l >> 4) * 8;
    const int r4 = (l >> 4) * 4, c16 = l & 15;
    for (int jt = 0; jt < 7; ++jt){
        __syncthreads();
        {
            int r = tid >> 3, q = tid & 7;
            size_t src = base + (size_t)(jt * 32 + r) * HD_ + q * 8;
            *(u16x8*)&Kl[0][r][q * 8] = *(const u16x8*)(K0 + src);
            *(u16x8*)&Kl[1][r][q * 8] = *(const u16x8*)(K1 + src);
            *(u16x8*)&Kl[2][r][q * 8] = *(const u16x8*)(K2 + src);
        }
        __syncthreads();
        f32x4 acc = {};
#pragma unroll
        for (int kk = 0; kk < 2; ++kk){
            int kg = kk * 32 + kg0;
            bf16x8 a0 = __builtin_bit_cast(bf16x8, *(const u16x8*)&Ql[0][wm*16 + arow][kg]);
            bf16x8 a1 = __builtin_bit_cast(bf16x8, *(const u16x8*)&Ql[1][wm*16 + arow][kg]);
            bf16x8 a2 = __builtin_bit_cast(bf16x8, *(const u16x8*)&Ql[2][wm*16 + arow][kg]);
            bf16x8 b0 = __builtin_bit_cast(bf16x8, *(const u16x8*)&Kl[0][wn*16 + arow][kg]);
            bf16x8 b1 = __builtin_bit_cast(bf16x8, *(const u16x8*)&Kl[1][wn*16 + arow][kg]);
            bf16x8 b2 = __builtin_bit_cast(bf16x8, *(const u16x8*)&Kl[2][wn*16 + arow][kg]);
            acc = __builtin_amdgcn_mfma_f32_16x16x32_bf16(a2, b0, acc, 0, 0, 0);
            acc = __builtin_amdgcn_mfma_f32_16x16x32_bf16(a1, b1, acc, 0, 0, 0);
            acc = __builtin_amdgcn_mfma_f32_16x16x32_bf16(a0, b2, acc, 0, 0, 0);
            acc = __builtin_amdgcn_mfma_f32_16x16x32_bf16(a1, b0, acc, 0, 0, 0);
            acc = __builtin_amdgcn_mfma_f32_16x16x32_bf16(a0, b1, acc, 0, 0, 0);
            acc = __builtin_amdgcn_mfma_f32_16x16x32_bf16(a0, b0, acc, 0, 0, 0);
        }
#pragma unroll
        for (int r = 0; r < 4; ++r){
            int i = i0 + wm * 16 + r4 + r;
            int j = jt * 32 + wn * 16 + c16;
            if (i < N_ && j < N_)
                S[((size_t)bh * N_ + i) * N_ + j] = acc[r];
        }
    }
}

// ---------------- batch-LN stats, two-pass, double ----------------

__global__ __launch_bounds__(256)
void statsA_kernel(const float* __restrict__ S, double* __restrict__ part1){
    int b = blockIdx.y, c = blockIdx.x;
    const float* base = S + (size_t)b * ATTN_PER_B_ + (size_t)c * 7203;
    double s = 0.0;
    for (int i = threadIdx.x; i < 7203; i += 256)
        s += (double)base[i];
    __shared__ double red[4];
    for (int o = 32; o > 0; o >>= 1) s += __shfl_down(s, o);
    if ((threadIdx.x & 63) == 0) red[threadIdx.x >> 6] = s;
    __syncthreads();
    if (threadIdx.x == 0) part1[b * 64 + c] = red[0] + red[1] + red[2] + red[3];
}

__global__ __launch_bounds__(64)
void reduceMu_kernel(const double* __restrict__ part1, double* __restrict__ MU){
    int b = blockIdx.x;
    double s = part1[b * 64 + threadIdx.x];
    for (int o = 32; o > 0; o >>= 1) s += __shfl_down(s, o);
    if (threadIdx.x == 0) MU[b] = s / (double)ATTN_PER_B_;
}

__global__ __launch_bounds__(256)
void statsB_kernel(const float* __restrict__ S, const double* __restrict__ MU,
                   double* __restrict__ part2){
    int b = blockIdx.y, c = blockIdx.x;
    double mu = MU[b];
    const float* base = S + (size_t)b * ATTN_PER_B_ + (size_t)c * 7203;
    double q = 0.0;
    for (int i = threadIdx.x; i < 7203; i += 256){
        double d = (double)base[i] - mu;
        q += d * d;
    }
    __shared__ double red[4];
    for (int o = 32; o > 0; o >>= 1) q += __shfl_down(q, o);
    if ((threadIdx.x & 63) == 0) red[threadIdx.x >> 6] = q;
    __syncthreads();
    if (threadIdx.x == 0) part2[b * 64 + c] = red[0] + red[1] + red[2] + red[3];
}

__global__ __launch_bounds__(64)
void reduceR_kernel(const double* __restrict__ part2, const double* __restrict__ MU,
                    float2* __restrict__ musig){
    int b = blockIdx.x;
    double q = part2[b * 64 + threadIdx.x];
    for (int o = 32; o > 0; o >>= 1) q += __shfl_down(q, o);
    if (threadIdx.x == 0){
        double var = q / (double)ATTN_PER_B_;
        musig[b] = make_float2((float)MU[b], (float)(1.0 / sqrt(var + 1e-5)));
    }
}

// ---------------- attn normalize: S in place + padded bf16 split-3 A operand ----------------

__global__ __launch_bounds__(256)
void attnnorm_pad(float* __restrict__ S, const float* __restrict__ wv,
                  const float* __restrict__ bv, const float2* __restrict__ musig,
                  u16* __restrict__ AS0, u16* __restrict__ AS1, u16* __restrict__ AS2){
    int gid = blockIdx.x * 256 + threadIdx.x;
    int jg = gid % 56;
    int rem = gid / 56;
    int i = rem % NP_;
    int bh = rem / NP_;
    int b = bh / H_, h = bh % H_;
    float2 ms = musig[b];
    u16x4 p0, p1, p2;
#pragma unroll
    for (int t = 0; t < 4; ++t){
        int j = jg * 4 + t;
        float val = 0.f;
        if (i < N_ && j < N_){
            size_t si = ((size_t)bh * N_ + i) * N_ + j;
            size_t wi = ((size_t)h * N_ + i) * N_ + j;
            float s = S[si];
            val = (s - ms.x) * ms.y * wv[wi] + bv[wi];
            S[si] = val;
        }
        u16 a, bb, c;
        split3(val, a, bb, c);
        p0[t] = a; p1[t] = bb; p2[t] = c;
    }
    size_t oo = (size_t)bh * (NP_ * NP_) + (size_t)i * NP_ + jg * 4;
    *(u16x4*)&AS0[oo] = p0;
    *(u16x4*)&AS1[oo] = p1;
    *(u16x4*)&AS2[oo] = p2;
}

// ---------------- PV via bf16 split-3 MFMA: Y = attn @ V, epilogue -> fp16 split-2 ----------------

__global__ __launch_bounds__(256)
void pv_mfma3(const u16* __restrict__ AS0, const u16* __restrict__ AS1,
              const u16* __restrict__ AS2,
              const u16* __restrict__ VT0, const u16* __restrict__ VT1,
              const u16* __restrict__ VT2,
              u16* __restrict__ PA0, u16* __restrict__ PA1){
    __shared__ u16 Al[3][32][40];
    __shared__ u16 Vl[3][64][40];
    int i0 = blockIdx.x * 32;
    int bh = blockIdx.y;
    int b = bh / H_, h = bh % H_;
    int tid = threadIdx.x;
    size_t abase = (size_t)bh * (NP_ * NP_) + (size_t)i0 * NP_;
    size_t vbase = (size_t)bh * (HD_ * NP_);
    const int w = tid >> 6, l = tid & 63;
    const int arow = l & 15, kg0 = (l >> 4) * 8;
    const int r4 = (l >> 4) * 4, c16 = l & 15;
    f32x4 acc[2] = {};
    for (int k0 = 0; k0 < NP_; k0 += 32){
        __syncthreads();
        for (int c = tid; c < 384; c += 256){
            int s = c >> 7, rem = c & 127;
            int r = rem >> 2, q = rem & 3;
            const u16* src = (s == 0 ? AS0 : (s == 1 ? AS1 : AS2));
            *(u16x8*)&Al[s][r][q * 8] = *(const u16x8*)(src + abase + (size_t)r * NP_ + k0 + q * 8);
        }
        for (int c = tid; c < 768; c += 256){
            int s = c >> 8, rem = c & 255;
            int r = rem >> 2, q = rem & 3;
            const u16* src = (s == 0 ? VT0 : (s == 1 ? VT1 : VT2));
            *(u16x8*)&Vl[s][r][q * 8] = *(const u16x8*)(src + vbase + (size_t)r * NP_ + k0 + q * 8);
        }
        __syncthreads();
        bf16x8 a0[2], a1[2], a2[2];
#pragma unroll
        for (int m = 0; m < 2; ++m){
            a0[m] = __builtin_bit_cast(bf16x8, *(const u16x8*)&Al[0][m*16 + arow][kg0]);
            a1[m] = __builtin_bit_cast(bf16x8, *(const u16x8*)&Al[1][m*16 + arow][kg0]);
            a2[m] = __builtin_bit_cast(bf16x8, *(const u16x8*)&Al[2][m*16 + arow][kg0]);
        }
        bf16x8 b0 = __builtin_bit_cast(bf16x8, *(const u16x8*)&Vl[0][w*16 + arow][kg0]);
        bf16x8 b1 = __builtin_bit_cast(bf16x8, *(const u16x8*)&Vl[1][w*16 + arow][kg0]);
        bf16x8 b2 = __builtin_bit_cast(bf16x8, *(const u16x8*)&Vl[2][w*16 + arow][kg0]);
#pragma unroll
        for (int m = 0; m < 2; ++m){
            acc[m] = __builtin_amdgcn_mfma_f32_16x16x32_bf16(a2[m], b0, acc[m], 0, 0, 0);
            acc[m] = __builtin_amdgcn_mfma_f32_16x16x32_bf16(a1[m], b1, acc[m], 0, 0, 0);
            acc[m] = __builtin_amdgcn_mfma_f32_16x16x32_bf16(a0[m], b2, acc[m], 0, 0, 0);
            acc[m] = __builtin_amdgcn_mfma_f32_16x16x32_bf16(a1[m], b0, acc[m], 0, 0, 0);
            acc[m] = __builtin_amdgcn_mfma_f32_16x16x32_bf16(a0[m], b1, acc[m], 0, 0, 0);
            acc[m] = __builtin_amdgcn_mfma_f32_16x16x32_bf16(a0[m], b0, acc[m], 0, 0, 0);
        }
    }
#pragma unroll
    for (int m = 0; m < 2; ++m)
#pragma unroll
        for (int r = 0; r < 4; ++r){
            int i = i0 + m * 16 + r4 + r;
            if (i < N_){
                size_t oi = ((size_t)b * N_ + i) * D_ + h * HD_ + w * 16 + c16;
                u16 s0, s1;
                split2h(acc[m][r], s0, s1);
                PA0[oi] = s0; PA1[oi] = s1;
            }
        }
}

// ---------------- final pooling ----------------

__global__ __launch_bounds__(256)
void rowdot_kernel(const float* __restrict__ xf, const float* __restrict__ pw,
                   const float* __restrict__ pb, float* __restrict__ sraw){
    int row = blockIdx.x, tid = threadIdx.x;
    const float* base = xf + (size_t)row * D_;
    float s = base[tid] * pw[tid] + base[tid + 256] * pw[tid + 256] + base[tid + 512] * pw[tid + 512];
    __shared__ float red[4];
    for (int o = 32; o > 0; o >>= 1) s += __shfl_xor(s, o);
    if ((tid & 63) == 0) red[tid >> 6] = s;
    __syncthreads();
    if (tid == 0) sraw[row] = red[0] + red[1] + red[2] + red[3] + pb[0];
}

__global__ __launch_bounds__(256)
void softmax196_kernel(const float* __restrict__ sraw, float* __restrict__ aw){
    int b = blockIdx.x, tid = threadIdx.x;
    __shared__ float red[8];
    float v = (tid < N_) ? sraw[b * N_ + tid] : -3.0e38f;
    float m = v;
    for (int o = 32; o > 0; o >>= 1) m = fmaxf(m, __shfl_xor(m, o));
    if ((tid & 63) == 0) red[tid >> 6] = m;
    __syncthreads();
    float M = fmaxf(fmaxf(red[0], red[1]), fmaxf(red[2], red[3]));
    float e = (tid < N_) ? expf(v - M) : 0.f;
    float s = e;
    for (int o = 32; o > 0; o >>= 1) s += __shfl_xor(s, o);
    if ((tid & 63) == 0) red[4 + (tid >> 6)] = s;
    __syncthreads();
    float S = red[4] + red[5] + red[6] + red[7];
    if (tid < N_) aw[b * N_ + tid] = e / S;
}

__global__ __launch_bounds__(256)
void poolmat_kernel(const float* __restrict__ aw, const float* __restrict__ xf,
                    float* __restrict__ pooled){
    int b = blockIdx.y;
    int d = blockIdx.x * 256 + threadIdx.x;
    float acc = 0.f;
    for (int n = 0; n < N_; ++n)
        acc += aw[b * N_ + n] * xf[((size_t)b * N_ + n) * D_ + d];
    pooled[b * D_ + d] = acc;
}

__global__ __launch_bounds__(256)
void fc_kernel(const float* __restrict__ pooled, const float* __restrict__ fw,
               const float* __restrict__ fb, float* __restrict__ out){
    int b = blockIdx.y;
    int c = blockIdx.x * 256 + threadIdx.x;
    if (c >= CLS_) return;
    float acc = fb[c];
    for (int d = 0; d < D_; ++d)
        acc += pooled[b * D_ + d] * fw[(size_t)d * CLS_ + c];
    out[b * CLS_ + c] = acc;
}

__global__ __launch_bounds__(256)
void zero_logits(float* __restrict__ out){
    out[blockIdx.x * 256 + threadIdx.x] = 0.f;
}

// ---------------- launcher ----------------

extern "C" void kernel_launch(void* const* d_in, const int* in_sizes, int n_in,
                              void* d_out, int out_size, void* d_ws, size_t ws_size,
                              hipStream_t stream){
    const float* x        = (const float*)d_in[0];
    const float* pos_emb  = (const float*)d_in[1];
    const float* qkv_w    = (const float*)d_in[2];
    const float* qkv_b    = (const float*)d_in[3];
    const float* proj_w   = (const float*)d_in[4];
    const float* proj_b   = (const float*)d_in[5];
    const float* lin1_w   = (const float*)d_in[6];
    const float* lin1_b   = (const float*)d_in[7];
    const float* lin2_w   = (const float*)d_in[8];
    const float* lin2_b   = (const float*)d_in[9];
    const float* pre_ln_w = (const float*)d_in[10];
    const float* pre_ln_b = (const float*)d_in[11];
    const float* norm1_w  = (const float*)d_in[12];
    const float* norm1_b  = (const float*)d_in[13];
    const float* attn_ln_w= (const float*)d_in[14];
    const float* attn_ln_b= (const float*)d_in[15];
    const float* fln_w    = (const float*)d_in[16];
    const float* fln_b    = (const float*)d_in[17];
    const float* pool_w   = (const float*)d_in[18];
    const float* pool_b   = (const float*)d_in[19];
    const float* fc_w     = (const float*)d_in[20];
    const float* fc_b     = (const float*)d_in[21];

    float* dout = (float*)d_out;
    float* S = dout + (size_t)B_ * CLS_;   // attn region (B,H,196,196) f32

    char* ws = (char*)d_ws;
    size_t off = 0;
    auto alloc = [&](size_t bytes)->char*{
        char* p = ws + off;
        off += (bytes + 255) & ~(size_t)255;
        return p;
    };
    float* SRC   = (float*)alloc((size_t)NTOK_ * D_ * 4);
    float* Yb    = (float*)alloc((size_t)NTOK_ * D_ * 4);
    float* TMP   = (float*)alloc((size_t)NTOK_ * D_ * 4);
    float* QKV   = (float*)alloc((size_t)NTOK_ * 3 * D_ * 4);
    u16*   A0    = (u16*)  alloc((size_t)NTOK_ * D_ * 2);
    u16*   A1    = (u16*)  alloc((size_t)NTOK_ * D_ * 2);
    u16*   W0    = (u16*)  alloc((size_t)FF_ * D_ * 2);
    u16*   W1    = (u16*)  alloc((size_t)FF_ * D_ * 2);
    u16*   F0    = (u16*)  alloc((size_t)NTOK_ * FF_ * 2);   // aliases attn AS0
    u16*   F1    = (u16*)  alloc((size_t)NTOK_ * FF_ * 2);   // aliases attn AS1
    u16*   F2    = (u16*)  alloc((size_t)NTOK_ * FF_ * 2);   // attn AS2 only
    u16*   Q0b   = (u16*)  alloc((size_t)BH_ * NP_ * HD_ * 2);
    u16*   Q1b   = (u16*)  alloc((size_t)BH_ * NP_ * HD_ * 2);
    u16*   Q2b   = (u16*)  alloc((size_t)BH_ * NP_ * HD_ * 2);
    u16*   K0b   = (u16*)  alloc((size_t)BH_ * NP_ * HD_ * 2);
    u16*   K1b   = (u16*)  alloc((size_t)BH_ * NP_ * HD_ * 2);
    u16*   K2b   = (u16*)  alloc((size_t)BH_ * NP_ * HD_ * 2);
    u16*   VT0   = (u16*)  alloc((size_t)BH_ * HD_ * NP_ * 2);
    u16*   VT1   = (u16*)  alloc((size_t)BH_ * HD_ * NP_ * 2);
    u16*   VT2   = (u16*)  alloc((size_t)BH_ * HD_ * NP_ * 2);
    double* P1   = (double*)alloc((size_t)B_ * 64 * 8);
    double* P2   = (double*)alloc((size_t)B_ * 64 * 8);
    double* MU   = (double*)alloc((size_t)B_ * 8);
    float2* MUSIG= (float2*)alloc((size_t)B_ * 8);
    float* SRAW  = (float*)alloc((size_t)NTOK_ * 4);
    float* AW    = (float*)alloc((size_t)NTOK_ * 4);
    float* POOLED= (float*)alloc((size_t)B_ * D_ * 4);
    u16* AS0 = F0, *AS1 = F1, *AS2 = F2;   // NTOK*FF == BH*NP*NP exactly

    if (ws_size < off){
        zero_logits<<<(B_ * CLS_) / 256, 256, 0, stream>>>(dout);
        return;
    }

    const int cvt_blocks = NTOK_ * D_ / (256 * 4);  // 4704
    const int an_blocks = (int)((size_t)BH_ * NP_ * NP_ / (256 * 4));  // 18816

    addpos_kernel<<<cvt_blocks, 256, 0, stream>>>(x, pos_emb, SRC);

    for (int l = 0; l < L_; ++l){
        const float* qw  = qkv_w  + (size_t)l * D_ * 3 * D_;
        const float* qb  = qkv_b  + (size_t)l * 3 * D_;
        const float* pw  = proj_w + (size_t)l * D_ * D_;
        const float* pb  = proj_b + (size_t)l * D_;
        const float* l1w = lin1_w + (size_t)l * D_ * FF_;
        const float* l1b = lin1_b + (size_t)l * FF_;
        const float* l2w = lin2_w + (size_t)l * FF_ * D_;
        const float* l2b = lin2_b + (size_t)l * D_;
        const float* prw = pre_ln_w + (size_t)l * D_;
        const float* prb = pre_ln_b + (size_t)l * D_;
        const float* n1w = norm1_w + (size_t)l * D_;
        const float* n1b = norm1_b + (size_t)l * D_;
        const float* awl = attn_ln_w + (size_t)l * H_ * N_ * N_;
        const float* abl = attn_ln_b + (size_t)l * H_ * N_ * N_;

        // pre-LN -> fp16 split-2 A operand
        ln_row<<<NTOK_, 256, 0, stream>>>(SRC, prw, prb, nullptr, A0, A1);
        // qkv
        wtrans_kernel<<<dim3(3 * D_ / 32, D_ / 32), 256, 0, stream>>>(qw, W0, W1, D_, 3 * D_);
        gemm_f16s2<0><<<(3 * D_ / 128) * (NTOK_ / 128), 256, 0, stream>>>(
            A0, A1, W0, W1, qb, nullptr, QKV, nullptr, nullptr, NTOK_, 3 * D_, D_);
        // q/k normalize+square -> bf16 split3 (padded), V^T split3
        qkprep_kernel<<<BH_, 256, 0, stream>>>(QKV, Q0b, Q1b, Q2b, K0b, K1b, K2b,
                                               VT0, VT1, VT2);
        // scores via split-3 MFMA (6-term)
        score_mfma3<<<dim3(7, BH_), 256, 0, stream>>>(Q0b, Q1b, Q2b, K0b, K1b, K2b, S);
        // batch LN over (H,N,N): two-pass double stats
        statsA_kernel<<<dim3(64, B_), 256, 0, stream>>>(S, P1);
        reduceMu_kernel<<<B_, 64, 0, stream>>>(P1, MU);
        statsB_kernel<<<dim3(64, B_), 256, 0, stream>>>(S, MU, P2);
        reduceR_kernel<<<B_, 64, 0, stream>>>(P2, MU, MUSIG);
        attnnorm_pad<<<an_blocks, 256, 0, stream>>>(S, awl, abl, MUSIG, AS0, AS1, AS2);
        // attn @ V via split-3 MFMA -> fp16 split-2 A operand (fused cvt)
        pv_mfma3<<<dim3(7, BH_), 256, 0, stream>>>(AS0, AS1, AS2, VT0, VT1, VT2, A0, A1);
        // proj + residual
        wtrans_kernel<<<dim3(D_ / 32, D_ / 32), 256, 0, stream>>>(pw, W0, W1, D_, D_);
        gemm_f16s2<2><<<(D_ / 128) * (NTOK_ / 128), 256, 0, stream>>>(
            A0, A1, W0, W1, pb, SRC, TMP, nullptr, nullptr, NTOK_, D_, D_);
        // norm1 -> SRC f32 + fp16 split2
        ln_row<<<NTOK_, 256, 0, stream>>>(TMP, n1w, n1b, SRC, A0, A1);
        // MLP
        wtrans_kernel<<<dim3(FF_ / 32, D_ / 32), 256, 0, stream>>>(l1w, W0, W1, D_, FF_);
        gemm_f16s2<1><<<(FF_ / 128) * (NTOK_ / 128), 256, 0, stream>>>(
            A0, A1, W0, W1, l1b, nullptr, nullptr, F0, F1, NTOK_, FF_, D_);
        wtrans_kernel<<<dim3(D_ / 32, FF_ / 32), 256, 0, stream>>>(l2w, W0, W1, FF_, D_);
        gemm_f16s2<2><<<(D_ / 128) * (NTOK_ / 128), 256, 0, stream>>>(
            F0, F1, W0, W1, l2b, SRC, SRC, nullptr, nullptr, NTOK_, D_, FF_);
    }

    // final LN -> Yb (xf)
    ln_row<<<NTOK_, 256, 0, stream>>>(SRC, fln_w, fln_b, Yb, nullptr, nullptr);
    // sequence pooling
    rowdot_kernel<<<NTOK_, 256, 0, stream>>>(Yb, pool_w, pool_b, SRAW);
    softmax196_kernel<<<B_, 256, 0, stream>>>(SRAW, AW);
    poolmat_kernel<<<dim3(D_ / 256, B_), 256, 0, stream>>>(AW, Yb, POOLED);
    fc_kernel<<<dim3((CLS_ + 255) / 256, B_), 256, 0, stream>>>(POOLED, fc_w, fc_b, dout);
}

// Round 13
// 8325.513 us; speedup vs baseline: 2.6327x; 1.0538x over previous
//
#include <hip/hip_runtime.h>
#include <hip/hip_bf16.h>

typedef unsigned short u16;
typedef __bf16 bf16x8 __attribute__((ext_vector_type(8)));
typedef _Float16 f16x8 __attribute__((ext_vector_type(8)));
typedef float f32x4 __attribute__((ext_vector_type(4)));
typedef u16 u16x8 __attribute__((ext_vector_type(8)));
typedef u16 u16x4 __attribute__((ext_vector_type(4)));

#define B_ 32
#define N_ 196
#define D_ 768
#define H_ 12
#define L_ 12
#define FF_ 3072
#define CLS_ 1000
#define HD_ 64
#define BH_ 384
#define NTOK_ 6272
#define NP_ 224
#define ATTN_PER_B_ 460992   /* H*N*N */
#define NN_ 38416            /* N*N */

__device__ inline u16 f2bf(float f){
    __bf16 h = (__bf16)f;
    return __builtin_bit_cast(u16, h);
}
__device__ inline float bf2f(u16 u){
    __bf16 h = __builtin_bit_cast(__bf16, u);
    return (float)h;
}
// bf16 3-way split: v ~= s0+s1+s2, rep error ~2^-27
__device__ inline void split3(float v, u16& s0, u16& s1, u16& s2){
    s0 = f2bf(v);
    float r = v - bf2f(s0);
    s1 = f2bf(r);
    r = r - bf2f(s1);
    s2 = f2bf(r);
}
__device__ inline u16 f2h(float f){
    _Float16 h = (_Float16)f;
    return __builtin_bit_cast(u16, h);
}
__device__ inline float h2f(u16 u){
    _Float16 h = __builtin_bit_cast(_Float16, u);
    return (float)h;
}
// fp16 2-way split: v ~= h0+h1, rep error ~2^-23
__device__ inline void split2h(float v, u16& h0, u16& h1){
    h0 = f2h(v);
    h1 = f2h(v - h2f(h0));
}

// ---------------- elementwise / conversion ----------------

__global__ __launch_bounds__(256)
void addpos_kernel(const float* __restrict__ x, const float* __restrict__ pos,
                   float* __restrict__ src){
    size_t gid = (size_t)blockIdx.x * 256 + threadIdx.x;
    size_t e = gid * 4;
    size_t tok = e / D_;
    size_t d = e % D_;
    size_t pe = (tok % N_) * D_ + d;
    float4 a = *(const float4*)(x + e);
    float4 p = *(const float4*)(pos + pe);
    float4 o = make_float4(a.x + p.x, a.y + p.y, a.z + p.z, a.w + p.w);
    *(float4*)(src + e) = o;
}

// weight transpose + fp16 split-2: in (K, Nn) f32 -> out (Nn, K)
__global__ __launch_bounds__(256)
void wtrans_kernel(const float* __restrict__ in, u16* __restrict__ o0,
                   u16* __restrict__ o1, int K, int Nn){
    __shared__ float t[32][33];
    int n0 = blockIdx.x * 32, k0 = blockIdx.y * 32;
    int tx = threadIdx.x & 31, ty = threadIdx.x >> 5;   // ty in [0,8)
#pragma unroll
    for (int r = 0; r < 4; ++r)
        t[ty + 8*r][tx] = in[(size_t)(k0 + ty + 8*r) * Nn + n0 + tx];
    __syncthreads();
#pragma unroll
    for (int r = 0; r < 4; ++r){
        float v = t[tx][ty + 8*r];
        size_t oi = (size_t)(n0 + ty + 8*r) * K + k0 + tx;
        u16 a, b;
        split2h(v, a, b);
        o0[oi] = a; o1[oi] = b;
    }
}

// ---------------- row LayerNorm (768 cols), optional fp16 split-2 out ----------------

__global__ __launch_bounds__(256)
void ln_row(const float* __restrict__ in, const float* __restrict__ w,
            const float* __restrict__ bb, float* __restrict__ outF,
            u16* __restrict__ o0, u16* __restrict__ o1){
    int row = blockIdx.x, tid = threadIdx.x;
    const float* base = in + (size_t)row * D_;
    float x0 = base[tid], x1 = base[tid + 256], x2 = base[tid + 512];
    float s = x0 + x1 + x2;
    float q = x0*x0 + x1*x1 + x2*x2;
    __shared__ float red[8];
    for (int o = 32; o > 0; o >>= 1){ s += __shfl_down(s, o); q += __shfl_down(q, o); }
    if ((tid & 63) == 0){ red[tid >> 6] = s; red[4 + (tid >> 6)] = q; }
    __syncthreads();
    s = red[0] + red[1] + red[2] + red[3];
    q = red[4] + red[5] + red[6] + red[7];
    float mu = s * (1.f / D_);
    float rv = rsqrtf(q * (1.f / D_) - mu * mu + 1e-5f);
#pragma unroll
    for (int t = 0; t < 3; ++t){
        int c = tid + t * 256;
        float x = (t == 0 ? x0 : (t == 1 ? x1 : x2));
        float val = (x - mu) * rv * w[c] + bb[c];
        size_t oi = (size_t)row * D_ + c;
        if (outF) outF[oi] = val;
        if (o0){
            u16 a, b;
            split2h(val, a, b);
            o0[oi] = a; o1[oi] = b;
        }
    }
}

// ---------------- fp16 split-2 GEMM, 3-term, double-buffered global_load_lds ----------------
// C = (A0+A1)(B0+B1)^T ~= A1B0 + A0B1 + A0B0 (dropped A1B1 ~ 2^-22 rel).
// Prefetch pipeline: stage tile t+1 into buf[1-cur] BEFORE computing tile t from
// buf[cur]; ONE barrier per K-step (its implicit vmcnt(0) drains the prefetch).
// XCD-bijective block swizzle on a flattened 1-D grid.

template<int EPI>
__global__ __launch_bounds__(256)
void gemm_f16s2(const u16* __restrict__ A0, const u16* __restrict__ A1,
                const u16* __restrict__ B0, const u16* __restrict__ B1,
                const float* __restrict__ bias, const float* __restrict__ res,
                float* __restrict__ outF, u16* __restrict__ oH,
                u16* __restrict__ oL, int M, int Nn, int K){
    __shared__ u16 Lds[2][4][128 * 32];   // [buf][operand][row*32+col]
    const int tid = threadIdx.x;
    const int w = tid >> 6, l = tid & 63;
    const int wr = w >> 1, wc = w & 1;
    // XCD-bijective swizzle (m204)
    const int nwg = gridDim.x;
    const int nbx = Nn >> 7;
    const int orig = blockIdx.x;
    const int qq = nwg >> 3, rr = nwg & 7;
    const int xcd = orig & 7, local = orig >> 3;
    const int wg = (xcd < rr ? xcd * (qq + 1) : rr * (qq + 1) + (xcd - rr) * qq) + local;
    const int m0 = (wg / nbx) * 128, n0 = (wg % nbx) * 128;
    // staging: wave w owns one operand; 8 x global_load_lds(16B) per K-step.
    const u16* gsrc = (w == 0 ? A0 : w == 1 ? A1 : w == 2 ? B0 : B1);
    const int rowbase = (w < 2 ? m0 : n0);
    const int lq = (l & 3) ^ ((l >> 3) & 3);     // swizzled logical 16B-chunk
    const u16* gp = gsrc + (size_t)(rowbase + (l >> 2)) * K + lq * 8;
    const size_t gstep = (size_t)16 * K;
    f32x4 acc[4][4] = {};
    const int arow = l & 15;
    const int qsel = l >> 4;
    const int nsteps = K >> 5;

    auto stage = [&](int buf, int k0){
        u16* lbuf = &Lds[buf][w][0];
        const u16* gpk = gp + k0;
#pragma unroll
        for (int i = 0; i < 8; ++i){
            __builtin_amdgcn_global_load_lds(
                (const __attribute__((address_space(1))) unsigned int*)gpk,
                (__attribute__((address_space(3))) unsigned int*)(lbuf + i * 512),
                16, 0, 0);
            gpk += gstep;
        }
    };

    stage(0, 0);
    for (int step = 0; step < nsteps; ++step){
        const int cur = step & 1;
        __syncthreads();   // drains buf[cur] loads; orders prior reads of buf[1-cur]
        if (step + 1 < nsteps) stage(1 - cur, (step + 1) << 5);
        f16x8 a0[4], a1[4], b0[4], b1[4];
#pragma unroll
        for (int m = 0; m < 4; ++m){
            int row = wr * 64 + m * 16 + arow;
            int off = row * 32 + ((qsel ^ ((row >> 1) & 3)) * 8);
            a0[m] = __builtin_bit_cast(f16x8, *(const u16x8*)&Lds[cur][0][off]);
            a1[m] = __builtin_bit_cast(f16x8, *(const u16x8*)&Lds[cur][1][off]);
        }
#pragma unroll
        for (int n = 0; n < 4; ++n){
            int row = wc * 64 + n * 16 + arow;
            int off = row * 32 + ((qsel ^ ((row >> 1) & 3)) * 8);
            b0[n] = __builtin_bit_cast(f16x8, *(const u16x8*)&Lds[cur][2][off]);
            b1[n] = __builtin_bit_cast(f16x8, *(const u16x8*)&Lds[cur][3][off]);
        }
        // 3-term, smallest-order first (A1B1 dropped: ~2^-22 relative)
#pragma unroll
        for (int m = 0; m < 4; ++m)
#pragma unroll
            for (int n = 0; n < 4; ++n){
                acc[m][n] = __builtin_amdgcn_mfma_f32_16x16x32_f16(a1[m], b0[n], acc[m][n], 0, 0, 0);
                acc[m][n] = __builtin_amdgcn_mfma_f32_16x16x32_f16(a0[m], b1[n], acc[m][n], 0, 0, 0);
                acc[m][n] = __builtin_amdgcn_mfma_f32_16x16x32_f16(a0[m], b0[n], acc[m][n], 0, 0, 0);
            }
    }
    const int r4 = (l >> 4) * 4, c16 = l & 15;
#pragma unroll
    for (int m = 0; m < 4; ++m){
#pragma unroll
        for (int n = 0; n < 4; ++n){
            int colg = n0 + wc*64 + n*16 + c16;
            float bv = bias[colg];
#pragma unroll
            for (int r = 0; r < 4; ++r){
                int rowg = m0 + wr*64 + m*16 + r4 + r;
                size_t oi = (size_t)rowg * Nn + colg;
                float v = acc[m][n][r] + bv;
                if (EPI == 0){
                    outF[oi] = v;
                } else if (EPI == 1){
                    v = 0.5f * v * (1.0f + erff(v * 0.70710678118654752f));
                    u16 a, b;
                    split2h(v, a, b);
                    oH[oi] = a; oL[oi] = b;
                } else {
                    outF[oi] = v + res[oi];
                }
            }
        }
    }
}

// ---------------- q/k normalize+square -> bf16 split-3 (padded), V^T split-3 ----------------

__global__ __launch_bounds__(256)
void qkprep_kernel(const float* __restrict__ QKV,
                   u16* __restrict__ Q0, u16* __restrict__ Q1, u16* __restrict__ Q2,
                   u16* __restrict__ K0, u16* __restrict__ K1, u16* __restrict__ K2,
                   u16* __restrict__ VT0, u16* __restrict__ VT1, u16* __restrict__ VT2){
    __shared__ float vbuf[NP_][65];
    int bh = blockIdx.x;
    int b = bh / H_, h = bh % H_;
    int w = threadIdx.x >> 6, l = threadIdx.x & 63;
    size_t base = (size_t)bh * (NP_ * HD_);
    for (int n = w; n < NP_; n += 4){
        size_t oi = base + (size_t)n * HD_ + l;
        if (n < N_){
            const float* row = QKV + (size_t)(b * N_ + n) * (3 * D_) + h * HD_;
            float qv = row[l], kv = row[D_ + l], vv = row[2 * D_ + l];
            double qs = (double)qv * (double)qv, ks = (double)kv * (double)kv;
            double qr = qs, kr = ks;
            for (int o = 32; o > 0; o >>= 1){ qr += __shfl_xor(qr, o); kr += __shfl_xor(kr, o); }
            float q2 = (float)(qs / qr), k2 = (float)(ks / kr);
            u16 a, bb, c;
            split3(q2, a, bb, c);
            Q0[oi] = a; Q1[oi] = bb; Q2[oi] = c;
            split3(k2, a, bb, c);
            K0[oi] = a; K1[oi] = bb; K2[oi] = c;
            vbuf[n][l] = vv;
        } else {
            Q0[oi] = 0; Q1[oi] = 0; Q2[oi] = 0;
            K0[oi] = 0; K1[oi] = 0; K2[oi] = 0;
            vbuf[n][l] = 0.f;
        }
    }
    __syncthreads();
    size_t vtb = (size_t)bh * (HD_ * NP_);
    for (int idx = threadIdx.x; idx < HD_ * NP_; idx += 256){
        int d = idx / NP_, n = idx % NP_;
        u16 a, bb, c;
        split3(vbuf[n][d], a, bb, c);
        VT0[vtb + idx] = a; VT1[vtb + idx] = bb; VT2[vtb + idx] = c;
    }
}

// ---------------- score via bf16 split-3 MFMA (6-term): S = Q2 @ K2^T ----------------

#define SPAD 72

__global__ __launch_bounds__(256)
void score_mfma3(const u16* __restrict__ Q0, const u16* __restrict__ Q1,
                 const u16* __restrict__ Q2,
                 const u16* __restrict__ K0, const u16* __restrict__ K1,
                 const u16* __restrict__ K2,
                 float* __restrict__ S){
    __shared__ u16 Ql[3][32][SPAD];
    __shared__ u16 Kl[3][32][SPAD];
    int i0 = blockIdx.x * 32;
    int bh = blockIdx.y;
    int tid = threadIdx.x;
    size_t base = (size_t)bh * (NP_ * HD_);
    {
        int r = tid >> 3, q = tid & 7;
        size_t src = base + (size_t)(i0 + r) * HD_ + q * 8;
        *(u16x8*)&Ql[0][r][q * 8] = *(const u16x8*)(Q0 + src);
        *(u16x8*)&Ql[1][r][q * 8] = *(const u16x8*)(Q1 + src);
        *(u16x8*)&Ql[2][r][q * 8] = *(const u16x8*)(Q2 + src);
    }
    const int w = tid >> 6, l = tid & 63;
    const int wm = w >> 1, wn = w & 1;
    const int arow = l & 15, kg0 = (l >> 4) * 8;
    const int r4 = (l >> 4) * 4, c16 = l & 15;
    for (int jt = 0; jt < 7; ++jt){
        __syncthreads();
        {
            int r = tid >> 3, q = tid & 7;
            size_t src = base + (size_t)(jt * 32 + r) * HD_ + q * 8;
            *(u16x8*)&Kl[0][r][q * 8] = *(const u16x8*)(K0 + src);
            *(u16x8*)&Kl[1][r][q * 8] = *(const u16x8*)(K1 + src);
            *(u16x8*)&Kl[2][r][q * 8] = *(const u16x8*)(K2 + src);
        }
        __syncthreads();
        f32x4 acc = {};
#pragma unroll
        for (int kk = 0; kk < 2; ++kk){
            int kg = kk * 32 + kg0;
            bf16x8 a0 = __builtin_bit_cast(bf16x8, *(const u16x8*)&Ql[0][wm*16 + arow][kg]);
            bf16x8 a1 = __builtin_bit_cast(bf16x8, *(const u16x8*)&Ql[1][wm*16 + arow][kg]);
            bf16x8 a2 = __builtin_bit_cast(bf16x8, *(const u16x8*)&Ql[2][wm*16 + arow][kg]);
            bf16x8 b0 = __builtin_bit_cast(bf16x8, *(const u16x8*)&Kl[0][wn*16 + arow][kg]);
            bf16x8 b1 = __builtin_bit_cast(bf16x8, *(const u16x8*)&Kl[1][wn*16 + arow][kg]);
            bf16x8 b2 = __builtin_bit_cast(bf16x8, *(const u16x8*)&Kl[2][wn*16 + arow][kg]);
            acc = __builtin_amdgcn_mfma_f32_16x16x32_bf16(a2, b0, acc, 0, 0, 0);
            acc = __builtin_amdgcn_mfma_f32_16x16x32_bf16(a1, b1, acc, 0, 0, 0);
            acc = __builtin_amdgcn_mfma_f32_16x16x32_bf16(a0, b2, acc, 0, 0, 0);
            acc = __builtin_amdgcn_mfma_f32_16x16x32_bf16(a1, b0, acc, 0, 0, 0);
            acc = __builtin_amdgcn_mfma_f32_16x16x32_bf16(a0, b1, acc, 0, 0, 0);
            acc = __builtin_amdgcn_mfma_f32_16x16x32_bf16(a0, b0, acc, 0, 0, 0);
        }
#pragma unroll
        for (int r = 0; r < 4; ++r){
            int i = i0 + wm * 16 + r4 + r;
            int j = jt * 32 + wn * 16 + c16;
            if (i < N_ && j < N_)
                S[((size_t)bh * N_ + i) * N_ + j] = acc[r];
        }
    }
}

// ---------------- batch-LN stats, two-pass, double ----------------

__global__ __launch_bounds__(256)
void statsA_kernel(const float* __restrict__ S, double* __restrict__ part1){
    int b = blockIdx.y, c = blockIdx.x;
    const float* base = S + (size_t)b * ATTN_PER_B_ + (size_t)c * 7203;
    double s = 0.0;
    for (int i = threadIdx.x; i < 7203; i += 256)
        s += (double)base[i];
    __shared__ double red[4];
    for (int o = 32; o > 0; o >>= 1) s += __shfl_down(s, o);
    if ((threadIdx.x & 63) == 0) red[threadIdx.x >> 6] = s;
    __syncthreads();
    if (threadIdx.x == 0) part1[b * 64 + c] = red[0] + red[1] + red[2] + red[3];
}

__global__ __launch_bounds__(64)
void reduceMu_kernel(const double* __restrict__ part1, double* __restrict__ MU){
    int b = blockIdx.x;
    double s = part1[b * 64 + threadIdx.x];
    for (int o = 32; o > 0; o >>= 1) s += __shfl_down(s, o);
    if (threadIdx.x == 0) MU[b] = s / (double)ATTN_PER_B_;
}

__global__ __launch_bounds__(256)
void statsB_kernel(const float* __restrict__ S, const double* __restrict__ MU,
                   double* __restrict__ part2){
    int b = blockIdx.y, c = blockIdx.x;
    double mu = MU[b];
    const float* base = S + (size_t)b * ATTN_PER_B_ + (size_t)c * 7203;
    double q = 0.0;
    for (int i = threadIdx.x; i < 7203; i += 256){
        double d = (double)base[i] - mu;
        q += d * d;
    }
    __shared__ double red[4];
    for (int o = 32; o > 0; o >>= 1) q += __shfl_down(q, o);
    if ((threadIdx.x & 63) == 0) red[threadIdx.x >> 6] = q;
    __syncthreads();
    if (threadIdx.x == 0) part2[b * 64 + c] = red[0] + red[1] + red[2] + red[3];
}

__global__ __launch_bounds__(64)
void reduceR_kernel(const double* __restrict__ part2, const double* __restrict__ MU,
                    float2* __restrict__ musig){
    int b = blockIdx.x;
    double q = part2[b * 64 + threadIdx.x];
    for (int o = 32; o > 0; o >>= 1) q += __shfl_down(q, o);
    if (threadIdx.x == 0){
        double var = q / (double)ATTN_PER_B_;
        musig[b] = make_float2((float)MU[b], (float)(1.0 / sqrt(var + 1e-5)));
    }
}

// ---------------- attn normalize: S in place + padded bf16 split-3 A operand ----------------

__global__ __launch_bounds__(256)
void attnnorm_pad(float* __restrict__ S, const float* __restrict__ wv,
                  const float* __restrict__ bv, const float2* __restrict__ musig,
                  u16* __restrict__ AS0, u16* __restrict__ AS1, u16* __restrict__ AS2){
    int gid = blockIdx.x * 256 + threadIdx.x;
    int jg = gid % 56;
    int rem = gid / 56;
    int i = rem % NP_;
    int bh = rem / NP_;
    int b = bh / H_, h = bh % H_;
    float2 ms = musig[b];
    u16x4 p0, p1, p2;
#pragma unroll
    for (int t = 0; t < 4; ++t){
        int j = jg * 4 + t;
        float val = 0.f;
        if (i < N_ && j < N_){
            size_t si = ((size_t)bh * N_ + i) * N_ + j;
            size_t wi = ((size_t)h * N_ + i) * N_ + j;
            float s = S[si];
            val = (s - ms.x) * ms.y * wv[wi] + bv[wi];
            S[si] = val;
        }
        u16 a, bb, c;
        split3(val, a, bb, c);
        p0[t] = a; p1[t] = bb; p2[t] = c;
    }
    size_t oo = (size_t)bh * (NP_ * NP_) + (size_t)i * NP_ + jg * 4;
    *(u16x4*)&AS0[oo] = p0;
    *(u16x4*)&AS1[oo] = p1;
    *(u16x4*)&AS2[oo] = p2;
}

// ---------------- PV via bf16 split-3 MFMA: Y = attn @ V, epilogue -> fp16 split-2 ----------------

__global__ __launch_bounds__(256)
void pv_mfma3(const u16* __restrict__ AS0, const u16* __restrict__ AS1,
              const u16* __restrict__ AS2,
              const u16* __restrict__ VT0, const u16* __restrict__ VT1,
              const u16* __restrict__ VT2,
              u16* __restrict__ PA0, u16* __restrict__ PA1){
    __shared__ u16 Al[3][32][40];
    __shared__ u16 Vl[3][64][40];
    int i0 = blockIdx.x * 32;
    int bh = blockIdx.y;
    int b = bh / H_, h = bh % H_;
    int tid = threadIdx.x;
    size_t abase = (size_t)bh * (NP_ * NP_) + (size_t)i0 * NP_;
    size_t vbase = (size_t)bh * (HD_ * NP_);
    const int w = tid >> 6, l = tid & 63;
    const int arow = l & 15, kg0 = (l >> 4) * 8;
    const int r4 = (l >> 4) * 4, c16 = l & 15;
    f32x4 acc[2] = {};
    for (int k0 = 0; k0 < NP_; k0 += 32){
        __syncthreads();
        for (int c = tid; c < 384; c += 256){
            int s = c >> 7, rem = c & 127;
            int r = rem >> 2, q = rem & 3;
            const u16* src = (s == 0 ? AS0 : (s == 1 ? AS1 : AS2));
            *(u16x8*)&Al[s][r][q * 8] = *(const u16x8*)(src + abase + (size_t)r * NP_ + k0 + q * 8);
        }
        for (int c = tid; c < 768; c += 256){
            int s = c >> 8, rem = c & 255;
            int r = rem >> 2, q = rem & 3;
            const u16* src = (s == 0 ? VT0 : (s == 1 ? VT1 : VT2));
            *(u16x8*)&Vl[s][r][q * 8] = *(const u16x8*)(src + vbase + (size_t)r * NP_ + k0 + q * 8);
        }
        __syncthreads();
        bf16x8 a0[2], a1[2], a2[2];
#pragma unroll
        for (int m = 0; m < 2; ++m){
            a0[m] = __builtin_bit_cast(bf16x8, *(const u16x8*)&Al[0][m*16 + arow][kg0]);
            a1[m] = __builtin_bit_cast(bf16x8, *(const u16x8*)&Al[1][m*16 + arow][kg0]);
            a2[m] = __builtin_bit_cast(bf16x8, *(const u16x8*)&Al[2][m*16 + arow][kg0]);
        }
        bf16x8 b0 = __builtin_bit_cast(bf16x8, *(const u16x8*)&Vl[0][w*16 + arow][kg0]);
        bf16x8 b1 = __builtin_bit_cast(bf16x8, *(const u16x8*)&Vl[1][w*16 + arow][kg0]);
        bf16x8 b2 = __builtin_bit_cast(bf16x8, *(const u16x8*)&Vl[2][w*16 + arow][kg0]);
#pragma unroll
        for (int m = 0; m < 2; ++m){
            acc[m] = __builtin_amdgcn_mfma_f32_16x16x32_bf16(a2[m], b0, acc[m], 0, 0, 0);
            acc[m] = __builtin_amdgcn_mfma_f32_16x16x32_bf16(a1[m], b1, acc[m], 0, 0, 0);
            acc[m] = __builtin_amdgcn_mfma_f32_16x16x32_bf16(a0[m], b2, acc[m], 0, 0, 0);
            acc[m] = __builtin_amdgcn_mfma_f32_16x16x32_bf16(a1[m], b0, acc[m], 0, 0, 0);
            acc[m] = __builtin_amdgcn_mfma_f32_16x16x32_bf16(a0[m], b1, acc[m], 0, 0, 0);
            acc[m] = __builtin_amdgcn_mfma_f32_16x16x32_bf16(a0[m], b0, acc[m], 0, 0, 0);
        }
    }
#pragma unroll
    for (int m = 0; m < 2; ++m)
#pragma unroll
        for (int r = 0; r < 4; ++r){
            int i = i0 + m * 16 + r4 + r;
            if (i < N_){
                size_t oi = ((size_t)b * N_ + i) * D_ + h * HD_ + w * 16 + c16;
                u16 s0, s1;
                split2h(acc[m][r], s0, s1);
                PA0[oi] = s0; PA1[oi] = s1;
            }
        }
}

// ---------------- final pooling ----------------

__global__ __launch_bounds__(256)
void rowdot_kernel(const float* __restrict__ xf, const float* __restrict__ pw,
                   const float* __restrict__ pb, float* __restrict__ sraw){
    int row = blockIdx.x, tid = threadIdx.x;
    const float* base = xf + (size_t)row * D_;
    float s = base[tid] * pw[tid] + base[tid + 256] * pw[tid + 256] + base[tid + 512] * pw[tid + 512];
    __shared__ float red[4];
    for (int o = 32; o > 0; o >>= 1) s += __shfl_xor(s, o);
    if ((tid & 63) == 0) red[tid >> 6] = s;
    __syncthreads();
    if (tid == 0) sraw[row] = red[0] + red[1] + red[2] + red[3] + pb[0];
}

__global__ __launch_bounds__(256)
void softmax196_kernel(const float* __restrict__ sraw, float* __restrict__ aw){
    int b = blockIdx.x, tid = threadIdx.x;
    __shared__ float red[8];
    float v = (tid < N_) ? sraw[b * N_ + tid] : -3.0e38f;
    float m = v;
    for (int o = 32; o > 0; o >>= 1) m = fmaxf(m, __shfl_xor(m, o));
    if ((tid & 63) == 0) red[tid >> 6] = m;
    __syncthreads();
    float M = fmaxf(fmaxf(red[0], red[1]), fmaxf(red[2], red[3]));
    float e = (tid < N_) ? expf(v - M) : 0.f;
    float s = e;
    for (int o = 32; o > 0; o >>= 1) s += __shfl_xor(s, o);
    if ((tid & 63) == 0) red[4 + (tid >> 6)] = s;
    __syncthreads();
    float S = red[4] + red[5] + red[6] + red[7];
    if (tid < N_) aw[b * N_ + tid] = e / S;
}

__global__ __launch_bounds__(256)
void poolmat_kernel(const float* __restrict__ aw, const float* __restrict__ xf,
                    float* __restrict__ pooled){
    int b = blockIdx.y;
    int d = blockIdx.x * 256 + threadIdx.x;
    float acc = 0.f;
    for (int n = 0; n < N_; ++n)
        acc += aw[b * N_ + n] * xf[((size_t)b * N_ + n) * D_ + d];
    pooled[b * D_ + d] = acc;
}

__global__ __launch_bounds__(256)
void fc_kernel(const float* __restrict__ pooled, const float* __restrict__ fw,
               const float* __restrict__ fb, float* __restrict__ out){
    int b = blockIdx.y;
    int c = blockIdx.x * 256 + threadIdx.x;
    if (c >= CLS_) return;
    float acc = fb[c];
    for (int d = 0; d < D_; ++d)
        acc += pooled[b * D_ + d] * fw[(size_t)d * CLS_ + c];
    out[b * CLS_ + c] = acc;
}

__global__ __launch_bounds__(256)
void zero_logits(float* __restrict__ out){
    out[blockIdx.x * 256 + threadIdx.x] = 0.f;
}

// ---------------- launcher ----------------

extern "C" void kernel_launch(void* const* d_in, const int* in_sizes, int n_in,
                              void* d_out, int out_size, void* d_ws, size_t ws_size,
                              hipStream_t stream){
    const float* x        = (const float*)d_in[0];
    const float* pos_emb  = (const float*)d_in[1];
    const float* qkv_w    = (const float*)d_in[2];
    const float* qkv_b    = (const float*)d_in[3];
    const float* proj_w   = (const float*)d_in[4];
    const float* proj_b   = (const float*)d_in[5];
    const float* lin1_w   = (const float*)d_in[6];
    const float* lin1_b   = (const float*)d_in[7];
    const float* lin2_w   = (const float*)d_in[8];
    const float* lin2_b   = (const float*)d_in[9];
    const float* pre_ln_w = (const float*)d_in[10];
    const float* pre_ln_b = (const float*)d_in[11];
    const float* norm1_w  = (const float*)d_in[12];
    const float* norm1_b  = (const float*)d_in[13];
    const float* attn_ln_w= (const float*)d_in[14];
    const float* attn_ln_b= (const float*)d_in[15];
    const float* fln_w    = (const float*)d_in[16];
    const float* fln_b    = (const float*)d_in[17];
    const float* pool_w   = (const float*)d_in[18];
    const float* pool_b   = (const float*)d_in[19];
    const float* fc_w     = (const float*)d_in[20];
    const float* fc_b     = (const float*)d_in[21];

    float* dout = (float*)d_out;
    float* S = dout + (size_t)B_ * CLS_;   // attn region (B,H,196,196) f32

    char* ws = (char*)d_ws;
    size_t off = 0;
    auto alloc = [&](size_t bytes)->char*{
        char* p = ws + off;
        off += (bytes + 255) & ~(size_t)255;
        return p;
    };
    float* SRC   = (float*)alloc((size_t)NTOK_ * D_ * 4);
    float* Yb    = (float*)alloc((size_t)NTOK_ * D_ * 4);
    float* TMP   = (float*)alloc((size_t)NTOK_ * D_ * 4);
    float* QKV   = (float*)alloc((size_t)NTOK_ * 3 * D_ * 4);
    u16*   A0    = (u16*)  alloc((size_t)NTOK_ * D_ * 2);
    u16*   A1    = (u16*)  alloc((size_t)NTOK_ * D_ * 2);
    u16*   W0    = (u16*)  alloc((size_t)FF_ * D_ * 2);
    u16*   W1    = (u16*)  alloc((size_t)FF_ * D_ * 2);
    u16*   F0    = (u16*)  alloc((size_t)NTOK_ * FF_ * 2);   // aliases attn AS0
    u16*   F1    = (u16*)  alloc((size_t)NTOK_ * FF_ * 2);   // aliases attn AS1
    u16*   F2    = (u16*)  alloc((size_t)NTOK_ * FF_ * 2);   // attn AS2 only
    u16*   Q0b   = (u16*)  alloc((size_t)BH_ * NP_ * HD_ * 2);
    u16*   Q1b   = (u16*)  alloc((size_t)BH_ * NP_ * HD_ * 2);
    u16*   Q2b   = (u16*)  alloc((size_t)BH_ * NP_ * HD_ * 2);
    u16*   K0b   = (u16*)  alloc((size_t)BH_ * NP_ * HD_ * 2);
    u16*   K1b   = (u16*)  alloc((size_t)BH_ * NP_ * HD_ * 2);
    u16*   K2b   = (u16*)  alloc((size_t)BH_ * NP_ * HD_ * 2);
    u16*   VT0   = (u16*)  alloc((size_t)BH_ * HD_ * NP_ * 2);
    u16*   VT1   = (u16*)  alloc((size_t)BH_ * HD_ * NP_ * 2);
    u16*   VT2   = (u16*)  alloc((size_t)BH_ * HD_ * NP_ * 2);
    double* P1   = (double*)alloc((size_t)B_ * 64 * 8);
    double* P2   = (double*)alloc((size_t)B_ * 64 * 8);
    double* MU   = (double*)alloc((size_t)B_ * 8);
    float2* MUSIG= (float2*)alloc((size_t)B_ * 8);
    float* SRAW  = (float*)alloc((size_t)NTOK_ * 4);
    float* AW    = (float*)alloc((size_t)NTOK_ * 4);
    float* POOLED= (float*)alloc((size_t)B_ * D_ * 4);
    u16* AS0 = F0, *AS1 = F1, *AS2 = F2;   // NTOK*FF == BH*NP*NP exactly

    if (ws_size < off){
        zero_logits<<<(B_ * CLS_) / 256, 256, 0, stream>>>(dout);
        return;
    }

    const int cvt_blocks = NTOK_ * D_ / (256 * 4);  // 4704
    const int an_blocks = (int)((size_t)BH_ * NP_ * NP_ / (256 * 4));  // 18816

    addpos_kernel<<<cvt_blocks, 256, 0, stream>>>(x, pos_emb, SRC);

    for (int l = 0; l < L_; ++l){
        const float* qw  = qkv_w  + (size_t)l * D_ * 3 * D_;
        const float* qb  = qkv_b  + (size_t)l * 3 * D_;
        const float* pw  = proj_w + (size_t)l * D_ * D_;
        const float* pb  = proj_b + (size_t)l * D_;
        const float* l1w = lin1_w + (size_t)l * D_ * FF_;
        const float* l1b = lin1_b + (size_t)l * FF_;
        const float* l2w = lin2_w + (size_t)l * FF_ * D_;
        const float* l2b = lin2_b + (size_t)l * D_;
        const float* prw = pre_ln_w + (size_t)l * D_;
        const float* prb = pre_ln_b + (size_t)l * D_;
        const float* n1w = norm1_w + (size_t)l * D_;
        const float* n1b = norm1_b + (size_t)l * D_;
        const float* awl = attn_ln_w + (size_t)l * H_ * N_ * N_;
        const float* abl = attn_ln_b + (size_t)l * H_ * N_ * N_;

        // pre-LN -> fp16 split-2 A operand
        ln_row<<<NTOK_, 256, 0, stream>>>(SRC, prw, prb, nullptr, A0, A1);
        // qkv
        wtrans_kernel<<<dim3(3 * D_ / 32, D_ / 32), 256, 0, stream>>>(qw, W0, W1, D_, 3 * D_);
        gemm_f16s2<0><<<(3 * D_ / 128) * (NTOK_ / 128), 256, 0, stream>>>(
            A0, A1, W0, W1, qb, nullptr, QKV, nullptr, nullptr, NTOK_, 3 * D_, D_);
        // q/k normalize+square -> bf16 split3 (padded), V^T split3
        qkprep_kernel<<<BH_, 256, 0, stream>>>(QKV, Q0b, Q1b, Q2b, K0b, K1b, K2b,
                                               VT0, VT1, VT2);
        // scores via split-3 MFMA (6-term)
        score_mfma3<<<dim3(7, BH_), 256, 0, stream>>>(Q0b, Q1b, Q2b, K0b, K1b, K2b, S);
        // batch LN over (H,N,N): two-pass double stats
        statsA_kernel<<<dim3(64, B_), 256, 0, stream>>>(S, P1);
        reduceMu_kernel<<<B_, 64, 0, stream>>>(P1, MU);
        statsB_kernel<<<dim3(64, B_), 256, 0, stream>>>(S, MU, P2);
        reduceR_kernel<<<B_, 64, 0, stream>>>(P2, MU, MUSIG);
        attnnorm_pad<<<an_blocks, 256, 0, stream>>>(S, awl, abl, MUSIG, AS0, AS1, AS2);
        // attn @ V via split-3 MFMA -> fp16 split-2 A operand (fused cvt)
        pv_mfma3<<<dim3(7, BH_), 256, 0, stream>>>(AS0, AS1, AS2, VT0, VT1, VT2, A0, A1);
        // proj + residual
        wtrans_kernel<<<dim3(D_ / 32, D_ / 32), 256, 0, stream>>>(pw, W0, W1, D_, D_);
        gemm_f16s2<2><<<(D_ / 128) * (NTOK_ / 128), 256, 0, stream>>>(
            A0, A1, W0, W1, pb, SRC, TMP, nullptr, nullptr, NTOK_, D_, D_);
        // norm1 -> SRC f32 + fp16 split2
        ln_row<<<NTOK_, 256, 0, stream>>>(TMP, n1w, n1b, SRC, A0, A1);
        // MLP
        wtrans_kernel<<<dim3(FF_ / 32, D_ / 32), 256, 0, stream>>>(l1w, W0, W1, D_, FF_);
        gemm_f16s2<1><<<(FF_ / 128) * (NTOK_ / 128), 256, 0, stream>>>(
            A0, A1, W0, W1, l1b, nullptr, nullptr, F0, F1, NTOK_, FF_, D_);
        wtrans_kernel<<<dim3(D_ / 32, FF_ / 32), 256, 0, stream>>>(l2w, W0, W1, FF_, D_);
        gemm_f16s2<2><<<(D_ / 128) * (NTOK_ / 128), 256, 0, stream>>>(
            F0, F1, W0, W1, l2b, SRC, SRC, nullptr, nullptr, NTOK_, D_, FF_);
    }

    // final LN -> Yb (xf)
    ln_row<<<NTOK_, 256, 0, stream>>>(SRC, fln_w, fln_b, Yb, nullptr, nullptr);
    // sequence pooling
    rowdot_kernel<<<NTOK_, 256, 0, stream>>>(Yb, pool_w, pool_b, SRAW);
    softmax196_kernel<<<B_, 256, 0, stream>>>(SRAW, AW);
    poolmat_kernel<<<dim3(D_ / 256, B_), 256, 0, stream>>>(AW, Yb, POOLED);
    fc_kernel<<<dim3((CLS_ + 255) / 256, B_), 256, 0, stream>>>(POOLED, fc_w, fc_b, dout);
}

// Round 14
// 7305.661 us; speedup vs baseline: 3.0002x; 1.1396x over previous
//
#include <hip/hip_runtime.h>
#include <hip/hip_bf16.h>

typedef unsigned short u16;
typedef __bf16 bf16x8 __attribute__((ext_vector_type(8)));
typedef _Float16 f16x8 __attribute__((ext_vector_type(8)));
typedef float f32x4 __attribute__((ext_vector_type(4)));
typedef u16 u16x8 __attribute__((ext_vector_type(8)));
typedef u16 u16x4 __attribute__((ext_vector_type(4)));

#define B_ 32
#define N_ 196
#define D_ 768
#define H_ 12
#define L_ 12
#define FF_ 3072
#define CLS_ 1000
#define HD_ 64
#define BH_ 384
#define NTOK_ 6272
#define NP_ 224
#define ATTN_PER_B_ 460992   /* H*N*N */
#define NN_ 38416            /* N*N */

__device__ inline u16 f2bf(float f){
    __bf16 h = (__bf16)f;
    return __builtin_bit_cast(u16, h);
}
__device__ inline float bf2f(u16 u){
    __bf16 h = __builtin_bit_cast(__bf16, u);
    return (float)h;
}
// bf16 3-way split: v ~= s0+s1+s2, rep error ~2^-27
__device__ inline void split3(float v, u16& s0, u16& s1, u16& s2){
    s0 = f2bf(v);
    float r = v - bf2f(s0);
    s1 = f2bf(r);
    r = r - bf2f(s1);
    s2 = f2bf(r);
}
__device__ inline u16 f2h(float f){
    _Float16 h = (_Float16)f;
    return __builtin_bit_cast(u16, h);
}
__device__ inline float h2f(u16 u){
    _Float16 h = __builtin_bit_cast(_Float16, u);
    return (float)h;
}
// fp16 2-way split: v ~= h0+h1, rep error ~2^-23
__device__ inline void split2h(float v, u16& h0, u16& h1){
    h0 = f2h(v);
    h1 = f2h(v - h2f(h0));
}

// ---------------- elementwise / conversion ----------------

__global__ __launch_bounds__(256)
void addpos_kernel(const float* __restrict__ x, const float* __restrict__ pos,
                   float* __restrict__ src){
    size_t gid = (size_t)blockIdx.x * 256 + threadIdx.x;
    size_t e = gid * 4;
    size_t tok = e / D_;
    size_t d = e % D_;
    size_t pe = (tok % N_) * D_ + d;
    float4 a = *(const float4*)(x + e);
    float4 p = *(const float4*)(pos + pe);
    float4 o = make_float4(a.x + p.x, a.y + p.y, a.z + p.z, a.w + p.w);
    *(float4*)(src + e) = o;
}

// weight transpose + fp16 split-2: in (K, Nn) f32 -> out (Nn, K)
__global__ __launch_bounds__(256)
void wtrans_kernel(const float* __restrict__ in, u16* __restrict__ o0,
                   u16* __restrict__ o1, int K, int Nn){
    __shared__ float t[32][33];
    int n0 = blockIdx.x * 32, k0 = blockIdx.y * 32;
    int tx = threadIdx.x & 31, ty = threadIdx.x >> 5;   // ty in [0,8)
#pragma unroll
    for (int r = 0; r < 4; ++r)
        t[ty + 8*r][tx] = in[(size_t)(k0 + ty + 8*r) * Nn + n0 + tx];
    __syncthreads();
#pragma unroll
    for (int r = 0; r < 4; ++r){
        float v = t[tx][ty + 8*r];
        size_t oi = (size_t)(n0 + ty + 8*r) * K + k0 + tx;
        u16 a, b;
        split2h(v, a, b);
        o0[oi] = a; o1[oi] = b;
    }
}

// ---------------- row LayerNorm (768 cols), optional fp16 split-2 out ----------------

__global__ __launch_bounds__(256)
void ln_row(const float* __restrict__ in, const float* __restrict__ w,
            const float* __restrict__ bb, float* __restrict__ outF,
            u16* __restrict__ o0, u16* __restrict__ o1){
    int row = blockIdx.x, tid = threadIdx.x;
    const float* base = in + (size_t)row * D_;
    float x0 = base[tid], x1 = base[tid + 256], x2 = base[tid + 512];
    float s = x0 + x1 + x2;
    float q = x0*x0 + x1*x1 + x2*x2;
    __shared__ float red[8];
    for (int o = 32; o > 0; o >>= 1){ s += __shfl_down(s, o); q += __shfl_down(q, o); }
    if ((tid & 63) == 0){ red[tid >> 6] = s; red[4 + (tid >> 6)] = q; }
    __syncthreads();
    s = red[0] + red[1] + red[2] + red[3];
    q = red[4] + red[5] + red[6] + red[7];
    float mu = s * (1.f / D_);
    float rv = rsqrtf(q * (1.f / D_) - mu * mu + 1e-5f);
#pragma unroll
    for (int t = 0; t < 3; ++t){
        int c = tid + t * 256;
        float x = (t == 0 ? x0 : (t == 1 ? x1 : x2));
        float val = (x - mu) * rv * w[c] + bb[c];
        size_t oi = (size_t)row * D_ + c;
        if (outF) outF[oi] = val;
        if (o0){
            u16 a, b;
            split2h(val, a, b);
            o0[oi] = a; o1[oi] = b;
        }
    }
}

// ---------------- fp16 split-2 GEMM, 3-term, double-buffered global_load_lds ----------------
// (unchanged from round 13)

template<int EPI>
__global__ __launch_bounds__(256)
void gemm_f16s2(const u16* __restrict__ A0, const u16* __restrict__ A1,
                const u16* __restrict__ B0, const u16* __restrict__ B1,
                const float* __restrict__ bias, const float* __restrict__ res,
                float* __restrict__ outF, u16* __restrict__ oH,
                u16* __restrict__ oL, int M, int Nn, int K){
    __shared__ u16 Lds[2][4][128 * 32];   // [buf][operand][row*32+col]
    const int tid = threadIdx.x;
    const int w = tid >> 6, l = tid & 63;
    const int wr = w >> 1, wc = w & 1;
    const int nwg = gridDim.x;
    const int nbx = Nn >> 7;
    const int orig = blockIdx.x;
    const int qq = nwg >> 3, rr = nwg & 7;
    const int xcd = orig & 7, local = orig >> 3;
    const int wg = (xcd < rr ? xcd * (qq + 1) : rr * (qq + 1) + (xcd - rr) * qq) + local;
    const int m0 = (wg / nbx) * 128, n0 = (wg % nbx) * 128;
    const u16* gsrc = (w == 0 ? A0 : w == 1 ? A1 : w == 2 ? B0 : B1);
    const int rowbase = (w < 2 ? m0 : n0);
    const int lq = (l & 3) ^ ((l >> 3) & 3);
    const u16* gp = gsrc + (size_t)(rowbase + (l >> 2)) * K + lq * 8;
    const size_t gstep = (size_t)16 * K;
    f32x4 acc[4][4] = {};
    const int arow = l & 15;
    const int qsel = l >> 4;
    const int nsteps = K >> 5;

    auto stage = [&](int buf, int k0){
        u16* lbuf = &Lds[buf][w][0];
        const u16* gpk = gp + k0;
#pragma unroll
        for (int i = 0; i < 8; ++i){
            __builtin_amdgcn_global_load_lds(
                (const __attribute__((address_space(1))) unsigned int*)gpk,
                (__attribute__((address_space(3))) unsigned int*)(lbuf + i * 512),
                16, 0, 0);
            gpk += gstep;
        }
    };

    stage(0, 0);
    for (int step = 0; step < nsteps; ++step){
        const int cur = step & 1;
        __syncthreads();
        if (step + 1 < nsteps) stage(1 - cur, (step + 1) << 5);
        f16x8 a0[4], a1[4], b0[4], b1[4];
#pragma unroll
        for (int m = 0; m < 4; ++m){
            int row = wr * 64 + m * 16 + arow;
            int off = row * 32 + ((qsel ^ ((row >> 1) & 3)) * 8);
            a0[m] = __builtin_bit_cast(f16x8, *(const u16x8*)&Lds[cur][0][off]);
            a1[m] = __builtin_bit_cast(f16x8, *(const u16x8*)&Lds[cur][1][off]);
        }
#pragma unroll
        for (int n = 0; n < 4; ++n){
            int row = wc * 64 + n * 16 + arow;
            int off = row * 32 + ((qsel ^ ((row >> 1) & 3)) * 8);
            b0[n] = __builtin_bit_cast(f16x8, *(const u16x8*)&Lds[cur][2][off]);
            b1[n] = __builtin_bit_cast(f16x8, *(const u16x8*)&Lds[cur][3][off]);
        }
#pragma unroll
        for (int m = 0; m < 4; ++m)
#pragma unroll
            for (int n = 0; n < 4; ++n){
                acc[m][n] = __builtin_amdgcn_mfma_f32_16x16x32_f16(a1[m], b0[n], acc[m][n], 0, 0, 0);
                acc[m][n] = __builtin_amdgcn_mfma_f32_16x16x32_f16(a0[m], b1[n], acc[m][n], 0, 0, 0);
                acc[m][n] = __builtin_amdgcn_mfma_f32_16x16x32_f16(a0[m], b0[n], acc[m][n], 0, 0, 0);
            }
    }
    const int r4 = (l >> 4) * 4, c16 = l & 15;
#pragma unroll
    for (int m = 0; m < 4; ++m){
#pragma unroll
        for (int n = 0; n < 4; ++n){
            int colg = n0 + wc*64 + n*16 + c16;
            float bv = bias[colg];
#pragma unroll
            for (int r = 0; r < 4; ++r){
                int rowg = m0 + wr*64 + m*16 + r4 + r;
                size_t oi = (size_t)rowg * Nn + colg;
                float v = acc[m][n][r] + bv;
                if (EPI == 0){
                    outF[oi] = v;
                } else if (EPI == 1){
                    v = 0.5f * v * (1.0f + erff(v * 0.70710678118654752f));
                    u16 a, b;
                    split2h(v, a, b);
                    oH[oi] = a; oL[oi] = b;
                } else {
                    outF[oi] = v + res[oi];
                }
            }
        }
    }
}

// ---------------- q/k normalize+square -> bf16 split-3 (padded), V^T fp16 split-2 ----------------

__global__ __launch_bounds__(256)
void qkprep_kernel(const float* __restrict__ QKV,
                   u16* __restrict__ Q0, u16* __restrict__ Q1, u16* __restrict__ Q2,
                   u16* __restrict__ K0, u16* __restrict__ K1, u16* __restrict__ K2,
                   u16* __restrict__ VT0, u16* __restrict__ VT1){
    __shared__ float vbuf[NP_][65];
    int bh = blockIdx.x;
    int b = bh / H_, h = bh % H_;
    int w = threadIdx.x >> 6, l = threadIdx.x & 63;
    size_t base = (size_t)bh * (NP_ * HD_);
    for (int n = w; n < NP_; n += 4){
        size_t oi = base + (size_t)n * HD_ + l;
        if (n < N_){
            const float* row = QKV + (size_t)(b * N_ + n) * (3 * D_) + h * HD_;
            float qv = row[l], kv = row[D_ + l], vv = row[2 * D_ + l];
            double qs = (double)qv * (double)qv, ks = (double)kv * (double)kv;
            double qr = qs, kr = ks;
            for (int o = 32; o > 0; o >>= 1){ qr += __shfl_xor(qr, o); kr += __shfl_xor(kr, o); }
            float q2 = (float)(qs / qr), k2 = (float)(ks / kr);
            u16 a, bb, c;
            split3(q2, a, bb, c);
            Q0[oi] = a; Q1[oi] = bb; Q2[oi] = c;
            split3(k2, a, bb, c);
            K0[oi] = a; K1[oi] = bb; K2[oi] = c;
            vbuf[n][l] = vv;
        } else {
            Q0[oi] = 0; Q1[oi] = 0; Q2[oi] = 0;
            K0[oi] = 0; K1[oi] = 0; K2[oi] = 0;
            vbuf[n][l] = 0.f;
        }
    }
    __syncthreads();
    size_t vtb = (size_t)bh * (HD_ * NP_);
    for (int idx = threadIdx.x; idx < HD_ * NP_; idx += 256){
        int d = idx / NP_, n = idx % NP_;
        u16 a, bb;
        split2h(vbuf[n][d], a, bb);
        VT0[vtb + idx] = a; VT1[vtb + idx] = bb;
    }
}

// ---------------- score via bf16 split-3 MFMA (6-term) + fused batch-LN stats ----------------
// Each block accumulates (sum, sumsq) in double over its valid S outputs ->
// PART[b*84 + (bh%H)*7 + i-tile].

#define SPAD 72

__global__ __launch_bounds__(256)
void score_mfma3(const u16* __restrict__ Q0, const u16* __restrict__ Q1,
                 const u16* __restrict__ Q2,
                 const u16* __restrict__ K0, const u16* __restrict__ K1,
                 const u16* __restrict__ K2,
                 float* __restrict__ S, double2* __restrict__ part){
    __shared__ u16 Ql[3][32][SPAD];
    __shared__ u16 Kl[3][32][SPAD];
    __shared__ double red2[8];
    int i0 = blockIdx.x * 32;
    int bh = blockIdx.y;
    int tid = threadIdx.x;
    size_t base = (size_t)bh * (NP_ * HD_);
    {
        int r = tid >> 3, q = tid & 7;
        size_t src = base + (size_t)(i0 + r) * HD_ + q * 8;
        *(u16x8*)&Ql[0][r][q * 8] = *(const u16x8*)(Q0 + src);
        *(u16x8*)&Ql[1][r][q * 8] = *(const u16x8*)(Q1 + src);
        *(u16x8*)&Ql[2][r][q * 8] = *(const u16x8*)(Q2 + src);
    }
    const int w = tid >> 6, l = tid & 63;
    const int wm = w >> 1, wn = w & 1;
    const int arow = l & 15, kg0 = (l >> 4) * 8;
    const int r4 = (l >> 4) * 4, c16 = l & 15;
    double dsum = 0.0, dsq = 0.0;
    for (int jt = 0; jt < 7; ++jt){
        __syncthreads();
        {
            int r = tid >> 3, q = tid & 7;
            size_t src = base + (size_t)(jt * 32 + r) * HD_ + q * 8;
            *(u16x8*)&Kl[0][r][q * 8] = *(const u16x8*)(K0 + src);
            *(u16x8*)&Kl[1][r][q * 8] = *(const u16x8*)(K1 + src);
            *(u16x8*)&Kl[2][r][q * 8] = *(const u16x8*)(K2 + src);
        }
        __syncthreads();
        f32x4 acc = {};
#pragma unroll
        for (int kk = 0; kk < 2; ++kk){
            int kg = kk * 32 + kg0;
            bf16x8 a0 = __builtin_bit_cast(bf16x8, *(const u16x8*)&Ql[0][wm*16 + arow][kg]);
            bf16x8 a1 = __builtin_bit_cast(bf16x8, *(const u16x8*)&Ql[1][wm*16 + arow][kg]);
            bf16x8 a2 = __builtin_bit_cast(bf16x8, *(const u16x8*)&Ql[2][wm*16 + arow][kg]);
            bf16x8 b0 = __builtin_bit_cast(bf16x8, *(const u16x8*)&Kl[0][wn*16 + arow][kg]);
            bf16x8 b1 = __builtin_bit_cast(bf16x8, *(const u16x8*)&Kl[1][wn*16 + arow][kg]);
            bf16x8 b2 = __builtin_bit_cast(bf16x8, *(const u16x8*)&Kl[2][wn*16 + arow][kg]);
            acc = __builtin_amdgcn_mfma_f32_16x16x32_bf16(a2, b0, acc, 0, 0, 0);
            acc = __builtin_amdgcn_mfma_f32_16x16x32_bf16(a1, b1, acc, 0, 0, 0);
            acc = __builtin_amdgcn_mfma_f32_16x16x32_bf16(a0, b2, acc, 0, 0, 0);
            acc = __builtin_amdgcn_mfma_f32_16x16x32_bf16(a1, b0, acc, 0, 0, 0);
            acc = __builtin_amdgcn_mfma_f32_16x16x32_bf16(a0, b1, acc, 0, 0, 0);
            acc = __builtin_amdgcn_mfma_f32_16x16x32_bf16(a0, b0, acc, 0, 0, 0);
        }
#pragma unroll
        for (int r = 0; r < 4; ++r){
            int i = i0 + wm * 16 + r4 + r;
            int j = jt * 32 + wn * 16 + c16;
            if (i < N_ && j < N_){
                float v = acc[r];
                S[((size_t)bh * N_ + i) * N_ + j] = v;
                dsum += (double)v;
                dsq += (double)v * (double)v;
            }
        }
    }
    // block-level stats reduction
    for (int o = 32; o > 0; o >>= 1){
        dsum += __shfl_down(dsum, o);
        dsq  += __shfl_down(dsq, o);
    }
    __syncthreads();
    if ((tid & 63) == 0){ red2[tid >> 6] = dsum; red2[4 + (tid >> 6)] = dsq; }
    __syncthreads();
    if (tid == 0){
        int b = bh / H_, h = bh % H_;
        part[(size_t)b * 84 + h * 7 + blockIdx.x] =
            make_double2(red2[0] + red2[1] + red2[2] + red2[3],
                         red2[4] + red2[5] + red2[6] + red2[7]);
    }
}

__global__ __launch_bounds__(64)
void reduceMS_kernel(const double2* __restrict__ part, float2* __restrict__ musig){
    int b = blockIdx.x, tid = threadIdx.x;
    double s = 0.0, q = 0.0;
    for (int i = tid; i < 84; i += 64){
        double2 p = part[(size_t)b * 84 + i];
        s += p.x; q += p.y;
    }
    for (int o = 32; o > 0; o >>= 1){ s += __shfl_down(s, o); q += __shfl_down(q, o); }
    if (tid == 0){
        double mu = s / (double)ATTN_PER_B_;
        double var = q / (double)ATTN_PER_B_ - mu * mu;
        musig[b] = make_float2((float)mu, (float)(1.0 / sqrt(var + 1e-5)));
    }
}

// ---------------- attn normalize: optional S writeback + padded fp16 split-2 A ----------------

__global__ __launch_bounds__(256)
void attnnorm_f16(float* __restrict__ S, const float* __restrict__ wv,
                  const float* __restrict__ bv, const float2* __restrict__ musig,
                  u16* __restrict__ AS0, u16* __restrict__ AS1, int writeS){
    int gid = blockIdx.x * 256 + threadIdx.x;
    int jg = gid % 56;
    int rem = gid / 56;
    int i = rem % NP_;
    int bh = rem / NP_;
    int b = bh / H_, h = bh % H_;
    float2 ms = musig[b];
    u16x4 p0, p1;
#pragma unroll
    for (int t = 0; t < 4; ++t){
        int j = jg * 4 + t;
        float val = 0.f;
        if (i < N_ && j < N_){
            size_t si = ((size_t)bh * N_ + i) * N_ + j;
            size_t wi = ((size_t)h * N_ + i) * N_ + j;
            float s = S[si];
            val = (s - ms.x) * ms.y * wv[wi] + bv[wi];
            if (writeS) S[si] = val;
        }
        u16 a, bb;
        split2h(val, a, bb);
        p0[t] = a; p1[t] = bb;
    }
    size_t oo = (size_t)bh * (NP_ * NP_) + (size_t)i * NP_ + jg * 4;
    *(u16x4*)&AS0[oo] = p0;
    *(u16x4*)&AS1[oo] = p1;
}

// ---------------- PV via fp16 split-2 MFMA (4-term exact): Y = attn @ V -> fp16 split-2 ----------------

__global__ __launch_bounds__(256)
void pv_f16s2(const u16* __restrict__ AS0, const u16* __restrict__ AS1,
              const u16* __restrict__ VT0, const u16* __restrict__ VT1,
              u16* __restrict__ PA0, u16* __restrict__ PA1){
    __shared__ u16 Al[2][32][40];
    __shared__ u16 Vl[2][64][40];
    int i0 = blockIdx.x * 32;
    int bh = blockIdx.y;
    int b = bh / H_, h = bh % H_;
    int tid = threadIdx.x;
    size_t abase = (size_t)bh * (NP_ * NP_) + (size_t)i0 * NP_;
    size_t vbase = (size_t)bh * (HD_ * NP_);
    const int w = tid >> 6, l = tid & 63;
    const int arow = l & 15, kg0 = (l >> 4) * 8;
    const int r4 = (l >> 4) * 4, c16 = l & 15;
    f32x4 acc[2] = {};
    for (int k0 = 0; k0 < NP_; k0 += 32){
        __syncthreads();
        // stage A: 2 splits x 32 rows x 32 cols / 8 = 256 chunks
        {
            int s = tid >> 7, rem = tid & 127;
            int r = rem >> 2, q = rem & 3;
            const u16* src = (s == 0 ? AS0 : AS1);
            *(u16x8*)&Al[s][r][q * 8] = *(const u16x8*)(src + abase + (size_t)r * NP_ + k0 + q * 8);
        }
        // stage VT: 2 splits x 64 rows x 32 cols / 8 = 512 chunks
#pragma unroll
        for (int it = 0; it < 2; ++it){
            int c = tid + it * 256;
            int s = c >> 8, rem = c & 255;
            int r = rem >> 2, q = rem & 3;
            const u16* src = (s == 0 ? VT0 : VT1);
            *(u16x8*)&Vl[s][r][q * 8] = *(const u16x8*)(src + vbase + (size_t)r * NP_ + k0 + q * 8);
        }
        __syncthreads();
        f16x8 a0[2], a1[2];
#pragma unroll
        for (int m = 0; m < 2; ++m){
            a0[m] = __builtin_bit_cast(f16x8, *(const u16x8*)&Al[0][m*16 + arow][kg0]);
            a1[m] = __builtin_bit_cast(f16x8, *(const u16x8*)&Al[1][m*16 + arow][kg0]);
        }
        f16x8 b0 = __builtin_bit_cast(f16x8, *(const u16x8*)&Vl[0][w*16 + arow][kg0]);
        f16x8 b1 = __builtin_bit_cast(f16x8, *(const u16x8*)&Vl[1][w*16 + arow][kg0]);
#pragma unroll
        for (int m = 0; m < 2; ++m){
            acc[m] = __builtin_amdgcn_mfma_f32_16x16x32_f16(a1[m], b1, acc[m], 0, 0, 0);
            acc[m] = __builtin_amdgcn_mfma_f32_16x16x32_f16(a1[m], b0, acc[m], 0, 0, 0);
            acc[m] = __builtin_amdgcn_mfma_f32_16x16x32_f16(a0[m], b1, acc[m], 0, 0, 0);
            acc[m] = __builtin_amdgcn_mfma_f32_16x16x32_f16(a0[m], b0, acc[m], 0, 0, 0);
        }
    }
#pragma unroll
    for (int m = 0; m < 2; ++m)
#pragma unroll
        for (int r = 0; r < 4; ++r){
            int i = i0 + m * 16 + r4 + r;
            if (i < N_){
                size_t oi = ((size_t)b * N_ + i) * D_ + h * HD_ + w * 16 + c16;
                u16 s0, s1;
                split2h(acc[m][r], s0, s1);
                PA0[oi] = s0; PA1[oi] = s1;
            }
        }
}

// ---------------- final pooling ----------------

__global__ __launch_bounds__(256)
void rowdot_kernel(const float* __restrict__ xf, const float* __restrict__ pw,
                   const float* __restrict__ pb, float* __restrict__ sraw){
    int row = blockIdx.x, tid = threadIdx.x;
    const float* base = xf + (size_t)row * D_;
    float s = base[tid] * pw[tid] + base[tid + 256] * pw[tid + 256] + base[tid + 512] * pw[tid + 512];
    __shared__ float red[4];
    for (int o = 32; o > 0; o >>= 1) s += __shfl_xor(s, o);
    if ((tid & 63) == 0) red[tid >> 6] = s;
    __syncthreads();
    if (tid == 0) sraw[row] = red[0] + red[1] + red[2] + red[3] + pb[0];
}

__global__ __launch_bounds__(256)
void softmax196_kernel(const float* __restrict__ sraw, float* __restrict__ aw){
    int b = blockIdx.x, tid = threadIdx.x;
    __shared__ float red[8];
    float v = (tid < N_) ? sraw[b * N_ + tid] : -3.0e38f;
    float m = v;
    for (int o = 32; o > 0; o >>= 1) m = fmaxf(m, __shfl_xor(m, o));
    if ((tid & 63) == 0) red[tid >> 6] = m;
    __syncthreads();
    float M = fmaxf(fmaxf(red[0], red[1]), fmaxf(red[2], red[3]));
    float e = (tid < N_) ? expf(v - M) : 0.f;
    float s = e;
    for (int o = 32; o > 0; o >>= 1) s += __shfl_xor(s, o);
    if ((tid & 63) == 0) red[4 + (tid >> 6)] = s;
    __syncthreads();
    float S = red[4] + red[5] + red[6] + red[7];
    if (tid < N_) aw[b * N_ + tid] = e / S;
}

__global__ __launch_bounds__(256)
void poolmat_kernel(const float* __restrict__ aw, const float* __restrict__ xf,
                    float* __restrict__ pooled){
    int b = blockIdx.y;
    int d = blockIdx.x * 256 + threadIdx.x;
    float acc = 0.f;
    for (int n = 0; n < N_; ++n)
        acc += aw[b * N_ + n] * xf[((size_t)b * N_ + n) * D_ + d];
    pooled[b * D_ + d] = acc;
}

__global__ __launch_bounds__(256)
void fc_kernel(const float* __restrict__ pooled, const float* __restrict__ fw,
               const float* __restrict__ fb, float* __restrict__ out){
    int b = blockIdx.y;
    int c = blockIdx.x * 256 + threadIdx.x;
    if (c >= CLS_) return;
    float acc = fb[c];
    for (int d = 0; d < D_; ++d)
        acc += pooled[b * D_ + d] * fw[(size_t)d * CLS_ + c];
    out[b * CLS_ + c] = acc;
}

__global__ __launch_bounds__(256)
void zero_logits(float* __restrict__ out){
    out[blockIdx.x * 256 + threadIdx.x] = 0.f;
}

// ---------------- launcher ----------------

extern "C" void kernel_launch(void* const* d_in, const int* in_sizes, int n_in,
                              void* d_out, int out_size, void* d_ws, size_t ws_size,
                              hipStream_t stream){
    const float* x        = (const float*)d_in[0];
    const float* pos_emb  = (const float*)d_in[1];
    const float* qkv_w    = (const float*)d_in[2];
    const float* qkv_b    = (const float*)d_in[3];
    const float* proj_w   = (const float*)d_in[4];
    const float* proj_b   = (const float*)d_in[5];
    const float* lin1_w   = (const float*)d_in[6];
    const float* lin1_b   = (const float*)d_in[7];
    const float* lin2_w   = (const float*)d_in[8];
    const float* lin2_b   = (const float*)d_in[9];
    const float* pre_ln_w = (const float*)d_in[10];
    const float* pre_ln_b = (const float*)d_in[11];
    const float* norm1_w  = (const float*)d_in[12];
    const float* norm1_b  = (const float*)d_in[13];
    const float* attn_ln_w= (const float*)d_in[14];
    const float* attn_ln_b= (const float*)d_in[15];
    const float* fln_w    = (const float*)d_in[16];
    const float* fln_b    = (const float*)d_in[17];
    const float* pool_w   = (const float*)d_in[18];
    const float* pool_b   = (const float*)d_in[19];
    const float* fc_w     = (const float*)d_in[20];
    const float* fc_b     = (const float*)d_in[21];

    float* dout = (float*)d_out;
    float* S = dout + (size_t)B_ * CLS_;   // attn region (B,H,196,196) f32

    char* ws = (char*)d_ws;
    size_t off = 0;
    auto alloc = [&](size_t bytes)->char*{
        char* p = ws + off;
        off += (bytes + 255) & ~(size_t)255;
        return p;
    };
    float* SRC   = (float*)alloc((size_t)NTOK_ * D_ * 4);
    float* Yb    = (float*)alloc((size_t)NTOK_ * D_ * 4);
    float* TMP   = (float*)alloc((size_t)NTOK_ * D_ * 4);
    float* QKV   = (float*)alloc((size_t)NTOK_ * 3 * D_ * 4);
    u16*   A0    = (u16*)  alloc((size_t)NTOK_ * D_ * 2);
    u16*   A1    = (u16*)  alloc((size_t)NTOK_ * D_ * 2);
    u16*   W0    = (u16*)  alloc((size_t)FF_ * D_ * 2);
    u16*   W1    = (u16*)  alloc((size_t)FF_ * D_ * 2);
    u16*   F0    = (u16*)  alloc((size_t)NTOK_ * FF_ * 2);   // aliases attn AS0
    u16*   F1    = (u16*)  alloc((size_t)NTOK_ * FF_ * 2);   // aliases attn AS1
    u16*   Q0b   = (u16*)  alloc((size_t)BH_ * NP_ * HD_ * 2);
    u16*   Q1b   = (u16*)  alloc((size_t)BH_ * NP_ * HD_ * 2);
    u16*   Q2b   = (u16*)  alloc((size_t)BH_ * NP_ * HD_ * 2);
    u16*   K0b   = (u16*)  alloc((size_t)BH_ * NP_ * HD_ * 2);
    u16*   K1b   = (u16*)  alloc((size_t)BH_ * NP_ * HD_ * 2);
    u16*   K2b   = (u16*)  alloc((size_t)BH_ * NP_ * HD_ * 2);
    u16*   VT0   = (u16*)  alloc((size_t)BH_ * HD_ * NP_ * 2);
    u16*   VT1   = (u16*)  alloc((size_t)BH_ * HD_ * NP_ * 2);
    double2* PART= (double2*)alloc((size_t)B_ * 84 * 16);
    float2* MUSIG= (float2*)alloc((size_t)B_ * 8);
    float* SRAW  = (float*)alloc((size_t)NTOK_ * 4);
    float* AW    = (float*)alloc((size_t)NTOK_ * 4);
    float* POOLED= (float*)alloc((size_t)B_ * D_ * 4);
    u16* AS0 = F0, *AS1 = F1;   // NTOK*FF == BH*NP*NP exactly

    if (ws_size < off){
        zero_logits<<<(B_ * CLS_) / 256, 256, 0, stream>>>(dout);
        return;
    }

    const int cvt_blocks = NTOK_ * D_ / (256 * 4);  // 4704
    const int an_blocks = (int)((size_t)BH_ * NP_ * NP_ / (256 * 4));  // 18816

    addpos_kernel<<<cvt_blocks, 256, 0, stream>>>(x, pos_emb, SRC);

    for (int l = 0; l < L_; ++l){
        const float* qw  = qkv_w  + (size_t)l * D_ * 3 * D_;
        const float* qb  = qkv_b  + (size_t)l * 3 * D_;
        const float* pw  = proj_w + (size_t)l * D_ * D_;
        const float* pb  = proj_b + (size_t)l * D_;
        const float* l1w = lin1_w + (size_t)l * D_ * FF_;
        const float* l1b = lin1_b + (size_t)l * FF_;
        const float* l2w = lin2_w + (size_t)l * FF_ * D_;
        const float* l2b = lin2_b + (size_t)l * D_;
        const float* prw = pre_ln_w + (size_t)l * D_;
        const float* prb = pre_ln_b + (size_t)l * D_;
        const float* n1w = norm1_w + (size_t)l * D_;
        const float* n1b = norm1_b + (size_t)l * D_;
        const float* awl = attn_ln_w + (size_t)l * H_ * N_ * N_;
        const float* abl = attn_ln_b + (size_t)l * H_ * N_ * N_;

        // pre-LN -> fp16 split-2 A operand
        ln_row<<<NTOK_, 256, 0, stream>>>(SRC, prw, prb, nullptr, A0, A1);
        // qkv
        wtrans_kernel<<<dim3(3 * D_ / 32, D_ / 32), 256, 0, stream>>>(qw, W0, W1, D_, 3 * D_);
        gemm_f16s2<0><<<(3 * D_ / 128) * (NTOK_ / 128), 256, 0, stream>>>(
            A0, A1, W0, W1, qb, nullptr, QKV, nullptr, nullptr, NTOK_, 3 * D_, D_);
        // q/k normalize+square -> bf16 split3 (padded), V^T fp16 split2
        qkprep_kernel<<<BH_, 256, 0, stream>>>(QKV, Q0b, Q1b, Q2b, K0b, K1b, K2b,
                                               VT0, VT1);
        // scores via split-3 MFMA (6-term) + fused stats
        score_mfma3<<<dim3(7, BH_), 256, 0, stream>>>(Q0b, Q1b, Q2b, K0b, K1b, K2b,
                                                      S, PART);
        reduceMS_kernel<<<B_, 64, 0, stream>>>(PART, MUSIG);
        attnnorm_f16<<<an_blocks, 256, 0, stream>>>(S, awl, abl, MUSIG, AS0, AS1,
                                                    l == L_ - 1 ? 1 : 0);
        // attn @ V via fp16 split-2 MFMA (4-term) -> fp16 split-2 A operand
        pv_f16s2<<<dim3(7, BH_), 256, 0, stream>>>(AS0, AS1, VT0, VT1, A0, A1);
        // proj + residual
        wtrans_kernel<<<dim3(D_ / 32, D_ / 32), 256, 0, stream>>>(pw, W0, W1, D_, D_);
        gemm_f16s2<2><<<(D_ / 128) * (NTOK_ / 128), 256, 0, stream>>>(
            A0, A1, W0, W1, pb, SRC, TMP, nullptr, nullptr, NTOK_, D_, D_);
        // norm1 -> SRC f32 + fp16 split2
        ln_row<<<NTOK_, 256, 0, stream>>>(TMP, n1w, n1b, SRC, A0, A1);
        // MLP
        wtrans_kernel<<<dim3(FF_ / 32, D_ / 32), 256, 0, stream>>>(l1w, W0, W1, D_, FF_);
        gemm_f16s2<1><<<(FF_ / 128) * (NTOK_ / 128), 256, 0, stream>>>(
            A0, A1, W0, W1, l1b, nullptr, nullptr, F0, F1, NTOK_, FF_, D_);
        wtrans_kernel<<<dim3(D_ / 32, FF_ / 32), 256, 0, stream>>>(l2w, W0, W1, FF_, D_);
        gemm_f16s2<2><<<(D_ / 128) * (NTOK_ / 128), 256, 0, stream>>>(
            F0, F1, W0, W1, l2b, SRC, SRC, nullptr, nullptr, NTOK_, D_, FF_);
    }

    // final LN -> Yb (xf)
    ln_row<<<NTOK_, 256, 0, stream>>>(SRC, fln_w, fln_b, Yb, nullptr, nullptr);
    // sequence pooling
    rowdot_kernel<<<NTOK_, 256, 0, stream>>>(Yb, pool_w, pool_b, SRAW);
    softmax196_kernel<<<B_, 256, 0, stream>>>(SRAW, AW);
    poolmat_kernel<<<dim3(D_ / 256, B_), 256, 0, stream>>>(AW, Yb, POOLED);
    fc_kernel<<<dim3((CLS_ + 255) / 256, B_), 256, 0, stream>>>(POOLED, fc_w, fc_b, dout);
}

// Round 16
// 6753.590 us; speedup vs baseline: 3.2454x; 1.0817x over previous
//
#include <hip/hip_runtime.h>
#include <hip/hip_bf16.h>

typedef unsigned short u16;
typedef _Float16 f16x8 __attribute__((ext_vector_type(8)));
typedef float f32x4 __attribute__((ext_vector_type(4)));
typedef u16 u16x8 __attribute__((ext_vector_type(8)));
typedef u16 u16x4 __attribute__((ext_vector_type(4)));

#define B_ 32
#define N_ 196
#define D_ 768
#define H_ 12
#define L_ 12
#define FF_ 3072
#define CLS_ 1000
#define HD_ 64
#define BH_ 384
#define NTOK_ 6272
#define NP_ 224
#define ATTN_PER_B_ 460992   /* H*N*N */
#define NN_ 38416            /* N*N */

__device__ inline u16 f2h(float f){
    _Float16 h = (_Float16)f;
    return __builtin_bit_cast(u16, h);
}
__device__ inline float h2f(u16 u){
    _Float16 h = __builtin_bit_cast(_Float16, u);
    return (float)h;
}
// fp16 2-way split: v ~= h0+h1, rep error ~2^-22 rel
__device__ inline void split2h(float v, u16& h0, u16& h1){
    h0 = f2h(v);
    h1 = f2h(v - h2f(h0));
}

// ---------------- elementwise / conversion ----------------

__global__ __launch_bounds__(256)
void addpos_kernel(const float* __restrict__ x, const float* __restrict__ pos,
                   float* __restrict__ src){
    size_t gid = (size_t)blockIdx.x * 256 + threadIdx.x;
    size_t e = gid * 4;
    size_t tok = e / D_;
    size_t d = e % D_;
    size_t pe = (tok % N_) * D_ + d;
    float4 a = *(const float4*)(x + e);
    float4 p = *(const float4*)(pos + pe);
    float4 o = make_float4(a.x + p.x, a.y + p.y, a.z + p.z, a.w + p.w);
    *(float4*)(src + e) = o;
}

// weight transpose + fp16 split-2: in (K, Nn) f32 -> out (Nn, K)
__global__ __launch_bounds__(256)
void wtrans_kernel(const float* __restrict__ in, u16* __restrict__ o0,
                   u16* __restrict__ o1, int K, int Nn){
    __shared__ float t[32][33];
    int n0 = blockIdx.x * 32, k0 = blockIdx.y * 32;
    int tx = threadIdx.x & 31, ty = threadIdx.x >> 5;   // ty in [0,8)
#pragma unroll
    for (int r = 0; r < 4; ++r)
        t[ty + 8*r][tx] = in[(size_t)(k0 + ty + 8*r) * Nn + n0 + tx];
    __syncthreads();
#pragma unroll
    for (int r = 0; r < 4; ++r){
        float v = t[tx][ty + 8*r];
        size_t oi = (size_t)(n0 + ty + 8*r) * K + k0 + tx;
        u16 a, b;
        split2h(v, a, b);
        o0[oi] = a; o1[oi] = b;
    }
}

// ---------------- row LayerNorm (768 cols), optional fp16 split-2 out ----------------

__global__ __launch_bounds__(256)
void ln_row(const float* __restrict__ in, const float* __restrict__ w,
            const float* __restrict__ bb, float* __restrict__ outF,
            u16* __restrict__ o0, u16* __restrict__ o1){
    int row = blockIdx.x, tid = threadIdx.x;
    const float* base = in + (size_t)row * D_;
    float x0 = base[tid], x1 = base[tid + 256], x2 = base[tid + 512];
    float s = x0 + x1 + x2;
    float q = x0*x0 + x1*x1 + x2*x2;
    __shared__ float red[8];
    for (int o = 32; o > 0; o >>= 1){ s += __shfl_down(s, o); q += __shfl_down(q, o); }
    if ((tid & 63) == 0){ red[tid >> 6] = s; red[4 + (tid >> 6)] = q; }
    __syncthreads();
    s = red[0] + red[1] + red[2] + red[3];
    q = red[4] + red[5] + red[6] + red[7];
    float mu = s * (1.f / D_);
    float rv = rsqrtf(q * (1.f / D_) - mu * mu + 1e-5f);
#pragma unroll
    for (int t = 0; t < 3; ++t){
        int c = tid + t * 256;
        float x = (t == 0 ? x0 : (t == 1 ? x1 : x2));
        float val = (x - mu) * rv * w[c] + bb[c];
        size_t oi = (size_t)row * D_ + c;
        if (outF) outF[oi] = val;
        if (o0){
            u16 a, b;
            split2h(val, a, b);
            o0[oi] = a; o1[oi] = b;
        }
    }
}

// ---------------- fp16 split-2 GEMM, 3-term, double-buffered global_load_lds ----------------
// (frozen from round 13)

template<int EPI>
__global__ __launch_bounds__(256)
void gemm_f16s2(const u16* __restrict__ A0, const u16* __restrict__ A1,
                const u16* __restrict__ B0, const u16* __restrict__ B1,
                const float* __restrict__ bias, const float* __restrict__ res,
                float* __restrict__ outF, u16* __restrict__ oH,
                u16* __restrict__ oL, int M, int Nn, int K){
    __shared__ u16 Lds[2][4][128 * 32];   // [buf][operand][row*32+col]
    const int tid = threadIdx.x;
    const int w = tid >> 6, l = tid & 63;
    const int wr = w >> 1, wc = w & 1;
    const int nwg = gridDim.x;
    const int nbx = Nn >> 7;
    const int orig = blockIdx.x;
    const int qq = nwg >> 3, rr = nwg & 7;
    const int xcd = orig & 7, local = orig >> 3;
    const int wg = (xcd < rr ? xcd * (qq + 1) : rr * (qq + 1) + (xcd - rr) * qq) + local;
    const int m0 = (wg / nbx) * 128, n0 = (wg % nbx) * 128;
    const u16* gsrc = (w == 0 ? A0 : w == 1 ? A1 : w == 2 ? B0 : B1);
    const int rowbase = (w < 2 ? m0 : n0);
    const int lq = (l & 3) ^ ((l >> 3) & 3);
    const u16* gp = gsrc + (size_t)(rowbase + (l >> 2)) * K + lq * 8;
    const size_t gstep = (size_t)16 * K;
    f32x4 acc[4][4] = {};
    const int arow = l & 15;
    const int qsel = l >> 4;
    const int nsteps = K >> 5;

    auto stage = [&](int buf, int k0){
        u16* lbuf = &Lds[buf][w][0];
        const u16* gpk = gp + k0;
#pragma unroll
        for (int i = 0; i < 8; ++i){
            __builtin_amdgcn_global_load_lds(
                (const __attribute__((address_space(1))) unsigned int*)gpk,
                (__attribute__((address_space(3))) unsigned int*)(lbuf + i * 512),
                16, 0, 0);
            gpk += gstep;
        }
    };

    stage(0, 0);
    for (int step = 0; step < nsteps; ++step){
        const int cur = step & 1;
        __syncthreads();
        if (step + 1 < nsteps) stage(1 - cur, (step + 1) << 5);
        f16x8 a0[4], a1[4], b0[4], b1[4];
#pragma unroll
        for (int m = 0; m < 4; ++m){
            int row = wr * 64 + m * 16 + arow;
            int off = row * 32 + ((qsel ^ ((row >> 1) & 3)) * 8);
            a0[m] = __builtin_bit_cast(f16x8, *(const u16x8*)&Lds[cur][0][off]);
            a1[m] = __builtin_bit_cast(f16x8, *(const u16x8*)&Lds[cur][1][off]);
        }
#pragma unroll
        for (int n = 0; n < 4; ++n){
            int row = wc * 64 + n * 16 + arow;
            int off = row * 32 + ((qsel ^ ((row >> 1) & 3)) * 8);
            b0[n] = __builtin_bit_cast(f16x8, *(const u16x8*)&Lds[cur][2][off]);
            b1[n] = __builtin_bit_cast(f16x8, *(const u16x8*)&Lds[cur][3][off]);
        }
#pragma unroll
        for (int m = 0; m < 4; ++m)
#pragma unroll
            for (int n = 0; n < 4; ++n){
                acc[m][n] = __builtin_amdgcn_mfma_f32_16x16x32_f16(a1[m], b0[n], acc[m][n], 0, 0, 0);
                acc[m][n] = __builtin_amdgcn_mfma_f32_16x16x32_f16(a0[m], b1[n], acc[m][n], 0, 0, 0);
                acc[m][n] = __builtin_amdgcn_mfma_f32_16x16x32_f16(a0[m], b0[n], acc[m][n], 0, 0, 0);
            }
    }
    const int r4 = (l >> 4) * 4, c16 = l & 15;
#pragma unroll
    for (int m = 0; m < 4; ++m){
#pragma unroll
        for (int n = 0; n < 4; ++n){
            int colg = n0 + wc*64 + n*16 + c16;
            float bv = bias[colg];
#pragma unroll
            for (int r = 0; r < 4; ++r){
                int rowg = m0 + wr*64 + m*16 + r4 + r;
                size_t oi = (size_t)rowg * Nn + colg;
                float v = acc[m][n][r] + bv;
                if (EPI == 0){
                    outF[oi] = v;
                } else if (EPI == 1){
                    v = 0.5f * v * (1.0f + erff(v * 0.70710678118654752f));
                    u16 a, b;
                    split2h(v, a, b);
                    oH[oi] = a; oL[oi] = b;
                } else {
                    outF[oi] = v + res[oi];
                }
            }
        }
    }
}

// ---------------- q/k normalize+square -> fp16 split-2 (padded), V^T fp16 split-2 ----------------

__global__ __launch_bounds__(256)
void qkprep_kernel(const float* __restrict__ QKV,
                   u16* __restrict__ Q0, u16* __restrict__ Q1,
                   u16* __restrict__ K0, u16* __restrict__ K1,
                   u16* __restrict__ VT0, u16* __restrict__ VT1){
    __shared__ float vbuf[NP_][65];
    int bh = blockIdx.x;
    int b = bh / H_, h = bh % H_;
    int w = threadIdx.x >> 6, l = threadIdx.x & 63;
    size_t base = (size_t)bh * (NP_ * HD_);
    for (int n = w; n < NP_; n += 4){
        size_t oi = base + (size_t)n * HD_ + l;
        if (n < N_){
            const float* row = QKV + (size_t)(b * N_ + n) * (3 * D_) + h * HD_;
            float qv = row[l], kv = row[D_ + l], vv = row[2 * D_ + l];
            double qs = (double)qv * (double)qv, ks = (double)kv * (double)kv;
            double qr = qs, kr = ks;
            for (int o = 32; o > 0; o >>= 1){ qr += __shfl_xor(qr, o); kr += __shfl_xor(kr, o); }
            float q2 = (float)(qs / qr), k2 = (float)(ks / kr);
            u16 a, bb;
            split2h(q2, a, bb);
            Q0[oi] = a; Q1[oi] = bb;
            split2h(k2, a, bb);
            K0[oi] = a; K1[oi] = bb;
            vbuf[n][l] = vv;
        } else {
            Q0[oi] = 0; Q1[oi] = 0;
            K0[oi] = 0; K1[oi] = 0;
            vbuf[n][l] = 0.f;
        }
    }
    __syncthreads();
    size_t vtb = (size_t)bh * (HD_ * NP_);
    for (int idx = threadIdx.x; idx < HD_ * NP_; idx += 256){
        int d = idx / NP_, n = idx % NP_;
        u16 a, bb;
        split2h(vbuf[n][d], a, bb);
        VT0[vtb + idx] = a; VT1[vtb + idx] = bb;
    }
}

// ---------------- score via fp16 split-2 MFMA (4-term exact) + fused batch-LN stats ----------------

#define SPAD 72

__global__ __launch_bounds__(256)
void score_f16s2(const u16* __restrict__ Q0, const u16* __restrict__ Q1,
                 const u16* __restrict__ K0, const u16* __restrict__ K1,
                 float* __restrict__ S, double2* __restrict__ part){
    __shared__ u16 Ql[2][32][SPAD];
    __shared__ u16 Kl[2][32][SPAD];
    __shared__ double red2[8];
    int i0 = blockIdx.x * 32;
    int bh = blockIdx.y;
    int tid = threadIdx.x;
    size_t base = (size_t)bh * (NP_ * HD_);
    {
        int r = tid >> 3, q = tid & 7;
        size_t src = base + (size_t)(i0 + r) * HD_ + q * 8;
        *(u16x8*)&Ql[0][r][q * 8] = *(const u16x8*)(Q0 + src);
        *(u16x8*)&Ql[1][r][q * 8] = *(const u16x8*)(Q1 + src);
    }
    const int w = tid >> 6, l = tid & 63;
    const int wm = w >> 1, wn = w & 1;
    const int arow = l & 15, kg0 = (l >> 4) * 8;
    const int r4 = (l >> 4) * 4, c16 = l & 15;
    double dsum = 0.0, dsq = 0.0;
    for (int jt = 0; jt < 7; ++jt){
        __syncthreads();
        {
            int r = tid >> 3, q = tid & 7;
            size_t src = base + (size_t)(jt * 32 + r) * HD_ + q * 8;
            *(u16x8*)&Kl[0][r][q * 8] = *(const u16x8*)(K0 + src);
            *(u16x8*)&Kl[1][r][q * 8] = *(const u16x8*)(K1 + src);
        }
        __syncthreads();
        f32x4 acc = {};
#pragma unroll
        for (int kk = 0; kk < 2; ++kk){
            int kg = kk * 32 + kg0;
            f16x8 a0 = __builtin_bit_cast(f16x8, *(const u16x8*)&Ql[0][wm*16 + arow][kg]);
            f16x8 a1 = __builtin_bit_cast(f16x8, *(const u16x8*)&Ql[1][wm*16 + arow][kg]);
            f16x8 b0 = __builtin_bit_cast(f16x8, *(const u16x8*)&Kl[0][wn*16 + arow][kg]);
            f16x8 b1 = __builtin_bit_cast(f16x8, *(const u16x8*)&Kl[1][wn*16 + arow][kg]);
            acc = __builtin_amdgcn_mfma_f32_16x16x32_f16(a1, b1, acc, 0, 0, 0);
            acc = __builtin_amdgcn_mfma_f32_16x16x32_f16(a1, b0, acc, 0, 0, 0);
            acc = __builtin_amdgcn_mfma_f32_16x16x32_f16(a0, b1, acc, 0, 0, 0);
            acc = __builtin_amdgcn_mfma_f32_16x16x32_f16(a0, b0, acc, 0, 0, 0);
        }
#pragma unroll
        for (int r = 0; r < 4; ++r){
            int i = i0 + wm * 16 + r4 + r;
            int j = jt * 32 + wn * 16 + c16;
            if (i < N_ && j < N_){
                float v = acc[r];
                S[((size_t)bh * N_ + i) * N_ + j] = v;
                dsum += (double)v;
                dsq += (double)v * (double)v;
            }
        }
    }
    for (int o = 32; o > 0; o >>= 1){
        dsum += __shfl_down(dsum, o);
        dsq  += __shfl_down(dsq, o);
    }
    __syncthreads();
    if ((tid & 63) == 0){ red2[tid >> 6] = dsum; red2[4 + (tid >> 6)] = dsq; }
    __syncthreads();
    if (tid == 0){
        int b = bh / H_, h = bh % H_;
        part[(size_t)b * 84 + h * 7 + blockIdx.x] =
            make_double2(red2[0] + red2[1] + red2[2] + red2[3],
                         red2[4] + red2[5] + red2[6] + red2[7]);
    }
}

__global__ __launch_bounds__(64)
void reduceMS_kernel(const double2* __restrict__ part, float2* __restrict__ musig){
    int b = blockIdx.x, tid = threadIdx.x;
    double s = 0.0, q = 0.0;
    for (int i = tid; i < 84; i += 64){
        double2 p = part[(size_t)b * 84 + i];
        s += p.x; q += p.y;
    }
    for (int o = 32; o > 0; o >>= 1){ s += __shfl_down(s, o); q += __shfl_down(q, o); }
    if (tid == 0){
        double mu = s / (double)ATTN_PER_B_;
        double var = q / (double)ATTN_PER_B_ - mu * mu;
        musig[b] = make_float2((float)mu, (float)(1.0 / sqrt(var + 1e-5)));
    }
}

// ---------------- final-layer attn normalize (S in place, output only) ----------------

__global__ __launch_bounds__(256)
void attnnorm_final(float* __restrict__ S, const float* __restrict__ wv,
                    const float* __restrict__ bv, const float2* __restrict__ musig){
    size_t idx = ((size_t)blockIdx.x * 256 + threadIdx.x) * 4;
    int b = (int)(idx / ATTN_PER_B_);
    int wi = (int)(idx % ATTN_PER_B_);
    float2 ms = musig[b];
    float4 s = *(const float4*)(S + idx);
    float4 w = *(const float4*)(wv + wi);
    float4 bb = *(const float4*)(bv + wi);
    s.x = (s.x - ms.x) * ms.y * w.x + bb.x;
    s.y = (s.y - ms.x) * ms.y * w.y + bb.y;
    s.z = (s.z - ms.x) * ms.y * w.z + bb.z;
    s.w = (s.w - ms.x) * ms.y * w.w + bb.w;
    *(float4*)(S + idx) = s;
}

// ---------------- PV with fused attn-LN: Y = norm(S) @ V -> fp16 split-2 ----------------
// Stages A by reading raw S + wv/bv tiles, normalizing + split2h in registers.
// N_=196 is a multiple of 4 => every float4 in a row is fully valid or fully out.

__global__ __launch_bounds__(256)
void pv_norm(const float* __restrict__ S, const float* __restrict__ wv,
             const float* __restrict__ bv, const float2* __restrict__ musig,
             const u16* __restrict__ VT0, const u16* __restrict__ VT1,
             u16* __restrict__ PA0, u16* __restrict__ PA1){
    __shared__ u16 Al[2][32][40];
    __shared__ u16 Vl[2][64][40];
    int i0 = blockIdx.x * 32;
    int bh = blockIdx.y;
    int b = bh / H_, h = bh % H_;
    int tid = threadIdx.x;
    float2 ms = musig[b];
    size_t vbase = (size_t)bh * (HD_ * NP_);
    const int w = tid >> 6, l = tid & 63;
    const int arow = l & 15, kg0 = (l >> 4) * 8;
    const int r4 = (l >> 4) * 4, c16 = l & 15;
    const int sr = tid >> 3, sc4 = (tid & 7) * 4;   // staging row/col4
    f32x4 acc[2] = {};
    for (int k0 = 0; k0 < NP_; k0 += 32){
        __syncthreads();
        // stage A = normalized S tile (32 rows x 32 cols), fp16 split-2
        {
            int i = i0 + sr, j = k0 + sc4;
            u16x4 p0, p1;
            if (i < N_ && j + 3 < N_){
                size_t si = ((size_t)bh * N_ + i) * N_ + j;
                size_t wi = ((size_t)h * N_ + i) * N_ + j;
                float4 sv = *(const float4*)(S + si);
                float4 wvv = *(const float4*)(wv + wi);
                float4 bvv = *(const float4*)(bv + wi);
                float v0 = (sv.x - ms.x) * ms.y * wvv.x + bvv.x;
                float v1 = (sv.y - ms.x) * ms.y * wvv.y + bvv.y;
                float v2 = (sv.z - ms.x) * ms.y * wvv.z + bvv.z;
                float v3 = (sv.w - ms.x) * ms.y * wvv.w + bvv.w;
                u16 t0, t1;
                split2h(v0, t0, t1); p0[0] = t0; p1[0] = t1;
                split2h(v1, t0, t1); p0[1] = t0; p1[1] = t1;
                split2h(v2, t0, t1); p0[2] = t0; p1[2] = t1;
                split2h(v3, t0, t1); p0[3] = t0; p1[3] = t1;
            } else {
                p0[0]=p0[1]=p0[2]=p0[3]=0;
                p1[0]=p1[1]=p1[2]=p1[3]=0;
            }
            *(u16x4*)&Al[0][sr][sc4] = p0;
            *(u16x4*)&Al[1][sr][sc4] = p1;
        }
        // stage VT: 2 splits x 64 rows x 32 cols / 8 = 512 chunks
#pragma unroll
        for (int it = 0; it < 2; ++it){
            int c = tid + it * 256;
            int s = c >> 8, rem = c & 255;
            int r = rem >> 2, q = rem & 3;
            const u16* src = (s == 0 ? VT0 : VT1);
            *(u16x8*)&Vl[s][r][q * 8] = *(const u16x8*)(src + vbase + (size_t)r * NP_ + k0 + q * 8);
        }
        __syncthreads();
        f16x8 a0[2], a1[2];
#pragma unroll
        for (int m = 0; m < 2; ++m){
            a0[m] = __builtin_bit_cast(f16x8, *(const u16x8*)&Al[0][m*16 + arow][kg0]);
            a1[m] = __builtin_bit_cast(f16x8, *(const u16x8*)&Al[1][m*16 + arow][kg0]);
        }
        f16x8 b0 = __builtin_bit_cast(f16x8, *(const u16x8*)&Vl[0][w*16 + arow][kg0]);
        f16x8 b1 = __builtin_bit_cast(f16x8, *(const u16x8*)&Vl[1][w*16 + arow][kg0]);
#pragma unroll
        for (int m = 0; m < 2; ++m){
            acc[m] = __builtin_amdgcn_mfma_f32_16x16x32_f16(a1[m], b1, acc[m], 0, 0, 0);
            acc[m] = __builtin_amdgcn_mfma_f32_16x16x32_f16(a1[m], b0, acc[m], 0, 0, 0);
            acc[m] = __builtin_amdgcn_mfma_f32_16x16x32_f16(a0[m], b1, acc[m], 0, 0, 0);
            acc[m] = __builtin_amdgcn_mfma_f32_16x16x32_f16(a0[m], b0, acc[m], 0, 0, 0);
        }
    }
#pragma unroll
    for (int m = 0; m < 2; ++m)
#pragma unroll
        for (int r = 0; r < 4; ++r){
            int i = i0 + m * 16 + r4 + r;
            if (i < N_){
                size_t oi = ((size_t)b * N_ + i) * D_ + h * HD_ + w * 16 + c16;
                u16 s0, s1;
                split2h(acc[m][r], s0, s1);
                PA0[oi] = s0; PA1[oi] = s1;
            }
        }
}

// ---------------- final pooling ----------------

__global__ __launch_bounds__(256)
void rowdot_kernel(const float* __restrict__ xf, const float* __restrict__ pw,
                   const float* __restrict__ pb, float* __restrict__ sraw){
    int row = blockIdx.x, tid = threadIdx.x;
    const float* base = xf + (size_t)row * D_;
    float s = base[tid] * pw[tid] + base[tid + 256] * pw[tid + 256] + base[tid + 512] * pw[tid + 512];
    __shared__ float red[4];
    for (int o = 32; o > 0; o >>= 1) s += __shfl_xor(s, o);
    if ((tid & 63) == 0) red[tid >> 6] = s;
    __syncthreads();
    if (tid == 0) sraw[row] = red[0] + red[1] + red[2] + red[3] + pb[0];
}

__global__ __launch_bounds__(256)
void softmax196_kernel(const float* __restrict__ sraw, float* __restrict__ aw){
    int b = blockIdx.x, tid = threadIdx.x;
    __shared__ float red[8];
    float v = (tid < N_) ? sraw[b * N_ + tid] : -3.0e38f;
    float m = v;
    for (int o = 32; o > 0; o >>= 1) m = fmaxf(m, __shfl_xor(m, o));
    if ((tid & 63) == 0) red[tid >> 6] = m;
    __syncthreads();
    float M = fmaxf(fmaxf(red[0], red[1]), fmaxf(red[2], red[3]));
    float e = (tid < N_) ? expf(v - M) : 0.f;
    float s = e;
    for (int o = 32; o > 0; o >>= 1) s += __shfl_xor(s, o);
    if ((tid & 63) == 0) red[4 + (tid >> 6)] = s;
    __syncthreads();
    float S = red[4] + red[5] + red[6] + red[7];
    if (tid < N_) aw[b * N_ + tid] = e / S;
}

__global__ __launch_bounds__(256)
void poolmat_kernel(const float* __restrict__ aw, const float* __restrict__ xf,
                    float* __restrict__ pooled){
    int b = blockIdx.y;
    int d = blockIdx.x * 256 + threadIdx.x;
    float acc = 0.f;
    for (int n = 0; n < N_; ++n)
        acc += aw[b * N_ + n] * xf[((size_t)b * N_ + n) * D_ + d];
    pooled[b * D_ + d] = acc;
}

__global__ __launch_bounds__(256)
void fc_kernel(const float* __restrict__ pooled, const float* __restrict__ fw,
               const float* __restrict__ fb, float* __restrict__ out){
    int b = blockIdx.y;
    int c = blockIdx.x * 256 + threadIdx.x;
    if (c >= CLS_) return;
    float acc = fb[c];
    for (int d = 0; d < D_; ++d)
        acc += pooled[b * D_ + d] * fw[(size_t)d * CLS_ + c];
    out[b * CLS_ + c] = acc;
}

__global__ __launch_bounds__(256)
void zero_logits(float* __restrict__ out){
    out[blockIdx.x * 256 + threadIdx.x] = 0.f;
}

// ---------------- launcher ----------------

extern "C" void kernel_launch(void* const* d_in, const int* in_sizes, int n_in,
                              void* d_out, int out_size, void* d_ws, size_t ws_size,
                              hipStream_t stream){
    const float* x        = (const float*)d_in[0];
    const float* pos_emb  = (const float*)d_in[1];
    const float* qkv_w    = (const float*)d_in[2];
    const float* qkv_b    = (const float*)d_in[3];
    const float* proj_w   = (const float*)d_in[4];
    const float* proj_b   = (const float*)d_in[5];
    const float* lin1_w   = (const float*)d_in[6];
    const float* lin1_b   = (const float*)d_in[7];
    const float* lin2_w   = (const float*)d_in[8];
    const float* lin2_b   = (const float*)d_in[9];
    const float* pre_ln_w = (const float*)d_in[10];
    const float* pre_ln_b = (const float*)d_in[11];
    const float* norm1_w  = (const float*)d_in[12];
    const float* norm1_b  = (const float*)d_in[13];
    const float* attn_ln_w= (const float*)d_in[14];
    const float* attn_ln_b= (const float*)d_in[15];
    const float* fln_w    = (const float*)d_in[16];
    const float* fln_b    = (const float*)d_in[17];
    const float* pool_w   = (const float*)d_in[18];
    const float* pool_b   = (const float*)d_in[19];
    const float* fc_w     = (const float*)d_in[20];
    const float* fc_b     = (const float*)d_in[21];

    float* dout = (float*)d_out;
    float* S = dout + (size_t)B_ * CLS_;   // attn region (B,H,196,196) f32

    char* ws = (char*)d_ws;
    size_t off = 0;
    auto alloc = [&](size_t bytes)->char*{
        char* p = ws + off;
        off += (bytes + 255) & ~(size_t)255;
        return p;
    };
    float* SRC   = (float*)alloc((size_t)NTOK_ * D_ * 4);
    float* Yb    = (float*)alloc((size_t)NTOK_ * D_ * 4);
    float* TMP   = (float*)alloc((size_t)NTOK_ * D_ * 4);
    float* QKV   = (float*)alloc((size_t)NTOK_ * 3 * D_ * 4);
    u16*   A0    = (u16*)  alloc((size_t)NTOK_ * D_ * 2);
    u16*   A1    = (u16*)  alloc((size_t)NTOK_ * D_ * 2);
    u16*   W0    = (u16*)  alloc((size_t)FF_ * D_ * 2);
    u16*   W1    = (u16*)  alloc((size_t)FF_ * D_ * 2);
    u16*   F0    = (u16*)  alloc((size_t)NTOK_ * FF_ * 2);
    u16*   F1    = (u16*)  alloc((size_t)NTOK_ * FF_ * 2);
    u16*   Q0b   = (u16*)  alloc((size_t)BH_ * NP_ * HD_ * 2);
    u16*   Q1b   = (u16*)  alloc((size_t)BH_ * NP_ * HD_ * 2);
    u16*   K0b   = (u16*)  alloc((size_t)BH_ * NP_ * HD_ * 2);
    u16*   K1b   = (u16*)  alloc((size_t)BH_ * NP_ * HD_ * 2);
    u16*   VT0   = (u16*)  alloc((size_t)BH_ * HD_ * NP_ * 2);
    u16*   VT1   = (u16*)  alloc((size_t)BH_ * HD_ * NP_ * 2);
    double2* PART= (double2*)alloc((size_t)B_ * 84 * 16);
    float2* MUSIG= (float2*)alloc((size_t)B_ * 8);
    float* SRAW  = (float*)alloc((size_t)NTOK_ * 4);
    float* AW    = (float*)alloc((size_t)NTOK_ * 4);
    float* POOLED= (float*)alloc((size_t)B_ * D_ * 4);

    if (ws_size < off){
        zero_logits<<<(B_ * CLS_) / 256, 256, 0, stream>>>(dout);
        return;
    }

    const int cvt_blocks = NTOK_ * D_ / (256 * 4);  // 4704
    const int anf_blocks = (int)((size_t)B_ * ATTN_PER_B_ / (256 * 4));  // 14406

    addpos_kernel<<<cvt_blocks, 256, 0, stream>>>(x, pos_emb, SRC);

    for (int l = 0; l < L_; ++l){
        const float* qw  = qkv_w  + (size_t)l * D_ * 3 * D_;
        const float* qb  = qkv_b  + (size_t)l * 3 * D_;
        const float* pw  = proj_w + (size_t)l * D_ * D_;
        const float* pb  = proj_b + (size_t)l * D_;
        const float* l1w = lin1_w + (size_t)l * D_ * FF_;
        const float* l1b = lin1_b + (size_t)l * FF_;
        const float* l2w = lin2_w + (size_t)l * FF_ * D_;
        const float* l2b = lin2_b + (size_t)l * D_;
        const float* prw = pre_ln_w + (size_t)l * D_;
        const float* prb = pre_ln_b + (size_t)l * D_;
        const float* n1w = norm1_w + (size_t)l * D_;
        const float* n1b = norm1_b + (size_t)l * D_;
        const float* awl = attn_ln_w + (size_t)l * H_ * N_ * N_;
        const float* abl = attn_ln_b + (size_t)l * H_ * N_ * N_;

        // pre-LN -> fp16 split-2 A operand
        ln_row<<<NTOK_, 256, 0, stream>>>(SRC, prw, prb, nullptr, A0, A1);
        // qkv
        wtrans_kernel<<<dim3(3 * D_ / 32, D_ / 32), 256, 0, stream>>>(qw, W0, W1, D_, 3 * D_);
        gemm_f16s2<0><<<(3 * D_ / 128) * (NTOK_ / 128), 256, 0, stream>>>(
            A0, A1, W0, W1, qb, nullptr, QKV, nullptr, nullptr, NTOK_, 3 * D_, D_);
        // q/k normalize+square -> fp16 split2 (padded), V^T fp16 split2
        qkprep_kernel<<<BH_, 256, 0, stream>>>(QKV, Q0b, Q1b, K0b, K1b, VT0, VT1);
        // scores via fp16 split-2 MFMA (4-term exact) + fused stats
        score_f16s2<<<dim3(7, BH_), 256, 0, stream>>>(Q0b, Q1b, K0b, K1b, S, PART);
        reduceMS_kernel<<<B_, 64, 0, stream>>>(PART, MUSIG);
        // attn @ V with fused normalization -> fp16 split-2 A operand
        pv_norm<<<dim3(7, BH_), 256, 0, stream>>>(S, awl, abl, MUSIG, VT0, VT1, A0, A1);
        // final layer: write normalized S (output 1) after pv consumed raw S
        if (l == L_ - 1)
            attnnorm_final<<<anf_blocks, 256, 0, stream>>>(S, awl, abl, MUSIG);
        // proj + residual
        wtrans_kernel<<<dim3(D_ / 32, D_ / 32), 256, 0, stream>>>(pw, W0, W1, D_, D_);
        gemm_f16s2<2><<<(D_ / 128) * (NTOK_ / 128), 256, 0, stream>>>(
            A0, A1, W0, W1, pb, SRC, TMP, nullptr, nullptr, NTOK_, D_, D_);
        // norm1 -> SRC f32 + fp16 split2
        ln_row<<<NTOK_, 256, 0, stream>>>(TMP, n1w, n1b, SRC, A0, A1);
        // MLP
        wtrans_kernel<<<dim3(FF_ / 32, D_ / 32), 256, 0, stream>>>(l1w, W0, W1, D_, FF_);
        gemm_f16s2<1><<<(FF_ / 128) * (NTOK_ / 128), 256, 0, stream>>>(
            A0, A1, W0, W1, l1b, nullptr, nullptr, F0, F1, NTOK_, FF_, D_);
        wtrans_kernel<<<dim3(D_ / 32, FF_ / 32), 256, 0, stream>>>(l2w, W0, W1, FF_, D_);
        gemm_f16s2<2><<<(D_ / 128) * (NTOK_ / 128), 256, 0, stream>>>(
            F0, F1, W0, W1, l2b, SRC, SRC, nullptr, nullptr, NTOK_, D_, FF_);
    }

    // final LN -> Yb (xf)
    ln_row<<<NTOK_, 256, 0, stream>>>(SRC, fln_w, fln_b, Yb, nullptr, nullptr);
    // sequence pooling
    rowdot_kernel<<<NTOK_, 256, 0, stream>>>(Yb, pool_w, pool_b, SRAW);
    softmax196_kernel<<<B_, 256, 0, stream>>>(SRAW, AW);
    poolmat_kernel<<<dim3(D_ / 256, B_), 256, 0, stream>>>(AW, Yb, POOLED);
    fc_kernel<<<dim3((CLS_ + 255) / 256, B_), 256, 0, stream>>>(POOLED, fc_w, fc_b, dout);
}